// Round 1
// 152.941 us; speedup vs baseline: 1.1238x; 1.1238x over previous
//
#include <hip/hip_runtime.h>
#include <cfloat>
#include <cmath>

#define NB 64
#define NQ 900
#define NM 64
#define NC 4
#define THREADS 256
#define NS 15   // ceil(NQ / 64) columns per lane

// ws layout (bytes):
// [16]              float class_sum[NB]
// [16 + 4*NB]       float box_sum[NB]
// [16 + 8*NB]       int   count[NB]

__global__ __launch_bounds__(THREADS) void match_kernel(
    const float* __restrict__ pred_boxes,    // [NB,NQ,6]
    const float* __restrict__ pred_classes,  // [NB,NQ,NC]
    const float* __restrict__ gt_boxes,      // [NB,NM,6]
    const unsigned int* __restrict__ labels_w,
    const unsigned int* __restrict__ mask_w,
    const unsigned char* __restrict__ mask_b,
    float* __restrict__ cls_part, float* __restrict__ box_part,
    int* __restrict__ cnt_part)
{
    __shared__ float4 pbx4[NQ];          // pred box dims 0..3
    __shared__ float2 pbx2[NQ];          // pred box dims 4..5
    __shared__ float  probT[NC][NQ];     // transposed softmax probs
    __shared__ int    pcol[NQ + 1];      // col -> matched row (1-based), 0=free
    __shared__ float  upot[NM + 1];      // row potentials (1-based)
    __shared__ int    tree_i[NM + 2];    // rows in the alternating tree
    __shared__ float4 gb4[NM];
    __shared__ float2 gb2[NM];
    __shared__ int    lab[NM];
    __shared__ int    vpos_s[NM];
    __shared__ int    row2col[NM];
    __shared__ int    m_sh;
    __shared__ int    f_lab_odd, f_m_not01, f_m_odd;
    __shared__ float  redc[4], redb[4];

    const int b = blockIdx.x;
    const int tid = threadIdx.x;
    const int lane = tid & 63;

    if (tid == 0) { f_lab_odd = 0; f_m_not01 = 0; f_m_odd = 0; }
    __syncthreads();

    // ---- Phase 1a: dtype detection (first 4KB of each buffer) + staging ----
    for (int w = tid; w < 1024; w += THREADS) {
        unsigned int lw = labels_w[w];
        if ((w & 1) && lw != 0u) f_lab_odd = 1;   // benign race: all write 1
        unsigned int mw = mask_w[w];
        if (mw > 1u) f_m_not01 = 1;
        if ((w & 1) && mw != 0u) f_m_odd = 1;
    }
    for (int q = tid; q < NQ; q += THREADS) {
        const float4 lg = *reinterpret_cast<const float4*>(
            pred_classes + ((size_t)b * NQ + q) * NC);
        float mx = fmaxf(fmaxf(lg.x, lg.y), fmaxf(lg.z, lg.w));
        float e0 = expf(lg.x - mx), e1 = expf(lg.y - mx);
        float e2 = expf(lg.z - mx), e3 = expf(lg.w - mx);
        float inv = 1.0f / (e0 + e1 + e2 + e3);
        probT[0][q] = e0 * inv; probT[1][q] = e1 * inv;
        probT[2][q] = e2 * inv; probT[3][q] = e3 * inv;
        const float* bp = pred_boxes + ((size_t)b * NQ + q) * 6;
        float2 b0 = *reinterpret_cast<const float2*>(bp);
        float2 b1 = *reinterpret_cast<const float2*>(bp + 2);
        float2 b2 = *reinterpret_cast<const float2*>(bp + 4);
        pbx4[q] = make_float4(b0.x, b0.y, b1.x, b1.y);
        pbx2[q] = make_float2(b2.x, b2.y);
    }
    for (int j = tid; j <= NQ; j += THREADS) pcol[j] = 0;
    for (int i2 = tid; i2 <= NM; i2 += THREADS) upot[i2] = 0.f;
    __syncthreads();

    const int lmode = f_lab_odd ? 0 : 1;                 // 0=int32, 1=int64
    const int mmode = f_m_not01 ? 2 : (f_m_odd ? 0 : 1); // 2=bytes,0=i32,1=i64

    // ---- Phase 1b: mask compaction + gt staging (wave 0 only) ----
    if (tid < 64) {
        int vv;
        if (mmode == 2)      vv = (mask_b[b * NM + lane] != 0);
        else if (mmode == 1) vv = (mask_w[(b * NM + lane) * 2] != 0u);
        else                 vv = (mask_w[b * NM + lane] != 0u);
        unsigned long long bal = __ballot(vv);
        if (vv) {
            int pos = (int)__popcll(bal & ((1ull << lane) - 1ull));
            vpos_s[pos] = lane;
        }
        if (lane == 0) m_sh = (int)__popcll(bal);
        __builtin_amdgcn_wave_barrier();
        int nw = (int)__popcll(bal);
        if (lane < nw) {
            int g = vpos_s[lane];
            lab[lane] = (int)(lmode ? labels_w[(size_t)(b * NM + g) * 2]
                                    : labels_w[b * NM + g]);
            const float* gp = gt_boxes + ((size_t)b * NM + g) * 6;
            gb4[lane] = make_float4(gp[0], gp[1], gp[2], gp[3]);
            gb2[lane] = make_float2(gp[4], gp[5]);
        }
    }
    __syncthreads();
    const int n = m_sh;

    // ---- Phase 2: Jonker-Volgenant, wave-synchronous on wave 0 ----
    // Per-lane register state for its 15 columns q = s*64 + lane.
    if (tid < 64) {
        float minv[NS], vpot[NS];
        int way[NS];
        #pragma unroll
        for (int s = 0; s < NS; ++s) { vpot[s] = 0.f; way[s] = 0; }

        for (int i = 1; i <= n; ++i) {
            #pragma unroll
            for (int s = 0; s < NS; ++s) minv[s] = FLT_MAX;
            unsigned int usedm = 0;
            if (lane == 0) pcol[0] = i;
            int j0 = 0, i0 = i, T = 0, bj = 0;
            while (true) {
                // step 1: mark used[j0], append row i0 to the tree
                if (j0 > 0 && ((j0 - 1) & 63) == lane)
                    usedm |= 1u << ((j0 - 1) >> 6);
                if (lane == 0) tree_i[T] = i0;
                T++;
                __builtin_amdgcn_wave_barrier();
                // step 2: scan row i0 over this lane's unused columns
                const float base = upot[i0];
                const float4 g4 = gb4[i0 - 1];
                const float2 g2 = gb2[i0 - 1];
                const int lb = lab[i0 - 1];
                const float* probrow = probT[lb];
                float lmin = FLT_MAX; int lj = NQ + 2;
                #pragma unroll
                for (int s = 0; s < NS; ++s) {
                    const int q = s * 64 + lane;
                    const bool valid = ((s + 1) * 64 <= NQ) || (q < NQ);
                    const int qc = valid ? q : 0;
                    const float4 p4 = pbx4[qc];
                    const float2 p2 = pbx2[qc];
                    const float pr = probrow[qc];
                    float l1 = fabsf(p4.x - g4.x) + fabsf(p4.y - g4.y)
                             + fabsf(p4.z - g4.z) + fabsf(p4.w - g4.w)
                             + fabsf(p2.x - g2.x) + fabsf(p2.y - g2.y);
                    float cost = 5.0f * l1 - pr;
                    float cur = cost - base - vpot[s];
                    const bool isused = (usedm >> s) & 1u;
                    if (valid && !isused) {
                        if (cur < minv[s]) { minv[s] = cur; way[s] = j0; }
                        if (minv[s] < lmin) { lmin = minv[s]; lj = q + 1; }
                    }
                }
                // step 3: wave argmin, lowest-index tie-break (np.argmin)
                float rv = lmin; int rj = lj;
                #pragma unroll
                for (int off = 32; off > 0; off >>= 1) {
                    float ov = __shfl_xor(rv, off);
                    int   oj = __shfl_xor(rj, off);
                    if (ov < rv || (ov == rv && oj < rj)) { rv = ov; rj = oj; }
                }
                const float delta = rv;
                bj = rj;
                const int nr = pcol[bj];
                // step 4: u[row in tree] += delta (distinct rows, parallel)
                for (int t = lane; t < T; t += 64)
                    upot[tree_i[t]] += delta;
                // step 4/5: v[used] -= delta ; minv[unused] -= delta
                #pragma unroll
                for (int s = 0; s < NS; ++s) {
                    if ((usedm >> s) & 1u) vpot[s] -= delta;
                    else                   minv[s] -= delta;
                }
                __builtin_amdgcn_wave_barrier();
                if (nr == 0) break;     // bj is a free column
                j0 = bj; i0 = nr;
            }
            // augment along the alternating path (uniform across the wave)
            int jcur = bj;
            while (jcur != 0) {
                const int q = jcur - 1;
                const int sl = q >> 6, ln = q & 63;
                int wsel = 0;
                #pragma unroll
                for (int s = 0; s < NS; ++s) if (s == sl) wsel = way[s];
                const int jp = __shfl(wsel, ln);
                const int pv = pcol[jp];
                if (lane == 0) pcol[jcur] = pv;
                __builtin_amdgcn_wave_barrier();
                jcur = jp;
            }
        }
    }
    __syncthreads();

    // ---- Phase 3: losses over matched pairs (all 256 threads) ----
    for (int j = 1 + tid; j <= NQ; j += THREADS) {
        int r = pcol[j];
        if (r > 0) row2col[r - 1] = j - 1;
    }
    __syncthreads();
    float cs = 0.f, bs = 0.f;
    for (int k = tid; k < n; k += THREADS) {
        int q = row2col[k];
        int lb = lab[k];
        cs += -logf(probT[lb][q]);
        float4 p4 = pbx4[q]; float2 p2 = pbx2[q];
        float4 g4 = gb4[k];  float2 g2 = gb2[k];
        bs += fabsf(p4.x - g4.x) + fabsf(p4.y - g4.y) + fabsf(p4.z - g4.z)
            + fabsf(p4.w - g4.w) + fabsf(p2.x - g2.x) + fabsf(p2.y - g2.y);
    }
    for (int off = 32; off > 0; off >>= 1) {
        cs += __shfl_down(cs, off);
        bs += __shfl_down(bs, off);
    }
    {
        int wave = tid >> 6;
        if ((tid & 63) == 0) { redc[wave] = cs; redb[wave] = bs; }
    }
    __syncthreads();
    if (tid == 0) {
        cls_part[b] = redc[0] + redc[1] + redc[2] + redc[3];
        box_part[b] = redb[0] + redb[1] + redb[2] + redb[3];
        cnt_part[b] = n;
    }
}

__global__ void finalize_kernel(const float* __restrict__ cls_part,
                                const float* __restrict__ box_part,
                                const int* __restrict__ cnt_part,
                                float* __restrict__ out) {
    if (threadIdx.x == 0 && blockIdx.x == 0) {
        float c = 0.f, bx = 0.f;
        int nn = 0;
        for (int b = 0; b < NB; ++b) {
            c += cls_part[b]; bx += box_part[b]; nn += cnt_part[b];
        }
        float denom = (nn > 0) ? (float)nn : 1.0f;
        float cl = c / denom;
        float bl = bx / (6.0f * denom);
        out[0] = cl;
        out[1] = bl;
        out[2] = cl + 5.0f * bl;
    }
}

extern "C" void kernel_launch(void* const* d_in, const int* in_sizes, int n_in,
                              void* d_out, int out_size, void* d_ws, size_t ws_size,
                              hipStream_t stream) {
    const float* pred_boxes   = (const float*)d_in[0];
    const float* pred_classes = (const float*)d_in[1];
    const float* gt_boxes     = (const float*)d_in[2];
    const unsigned int*  labels_w = (const unsigned int*)d_in[3];
    const unsigned int*  mask_w   = (const unsigned int*)d_in[4];
    const unsigned char* mask_b   = (const unsigned char*)d_in[4];

    char* ws = (char*)d_ws;
    float* cls_part = (float*)(ws + 16);
    float* box_part = (float*)(ws + 16 + 4 * NB);
    int*   cnt_part = (int*)(ws + 16 + 8 * NB);
    float* out = (float*)d_out;

    match_kernel<<<NB, THREADS, 0, stream>>>(pred_boxes, pred_classes, gt_boxes,
                                             labels_w, mask_w, mask_b,
                                             cls_part, box_part, cnt_part);
    finalize_kernel<<<1, 64, 0, stream>>>(cls_part, box_part, cnt_part, out);
}

// Round 2
// 87.550 us; speedup vs baseline: 1.9631x; 1.7469x over previous
//
#include <hip/hip_runtime.h>
#include <cfloat>
#include <cmath>

#define NB 64
#define NQ 900
#define NM 64
#define NC 4
#define THREADS 256
#define NS 15   // ceil(NQ / 64) columns per lane

__global__ __launch_bounds__(THREADS, 1) void match_kernel(
    const float* __restrict__ pred_boxes,    // [NB,NQ,6]
    const float* __restrict__ pred_classes,  // [NB,NQ,NC]
    const float* __restrict__ gt_boxes,      // [NB,NM,6]
    const unsigned int* __restrict__ labels_w,
    const unsigned int* __restrict__ mask_w,
    const unsigned char* __restrict__ mask_b,
    float* __restrict__ cls_part, float* __restrict__ box_part,
    int* __restrict__ cnt_part)
{
    __shared__ float4 pbx4[NQ];          // pred box dims 0..3
    __shared__ float2 pbx2[NQ];          // pred box dims 4..5
    __shared__ float  probT[NC][NQ];     // transposed softmax probs
    __shared__ int    pcol[NQ + 1];      // col -> matched row (1-based), 0=free
    __shared__ int    claim[NQ];         // greedy contention: min row claiming col
    __shared__ float  upot[NM + 1];      // row potentials (1-based)
    __shared__ int    tree_i[NM + 2];    // rows in the alternating tree
    __shared__ float4 gb4[NM];
    __shared__ float2 gb2[NM];
    __shared__ int    lab[NM];
    __shared__ int    vpos_s[NM];
    __shared__ int    row2col[NM];
    __shared__ float  rowmin_s[NM];
    __shared__ int    rowarg_s[NM];
    __shared__ int    ua_s[NM];          // unassigned rows after greedy
    __shared__ int    nua_s;
    __shared__ int    m_sh;
    __shared__ int    f_lab_odd, f_m_not01, f_m_odd;
    __shared__ float  redc[4], redb[4];

    const int b = blockIdx.x;
    const int tid = threadIdx.x;
    const int lane = tid & 63;
    const int wv = tid >> 6;

    if (tid == 0) { f_lab_odd = 0; f_m_not01 = 0; f_m_odd = 0; }
    __syncthreads();

    // ---- Phase 1a: dtype detection (first 4KB of each buffer) + staging ----
    for (int w = tid; w < 1024; w += THREADS) {
        unsigned int lw = labels_w[w];
        if ((w & 1) && lw != 0u) f_lab_odd = 1;   // benign race: all write 1
        unsigned int mw = mask_w[w];
        if (mw > 1u) f_m_not01 = 1;
        if ((w & 1) && mw != 0u) f_m_odd = 1;
    }
    for (int q = tid; q < NQ; q += THREADS) {
        const float4 lg = *reinterpret_cast<const float4*>(
            pred_classes + ((size_t)b * NQ + q) * NC);
        float mx = fmaxf(fmaxf(lg.x, lg.y), fmaxf(lg.z, lg.w));
        float e0 = expf(lg.x - mx), e1 = expf(lg.y - mx);
        float e2 = expf(lg.z - mx), e3 = expf(lg.w - mx);
        float inv = 1.0f / (e0 + e1 + e2 + e3);
        probT[0][q] = e0 * inv; probT[1][q] = e1 * inv;
        probT[2][q] = e2 * inv; probT[3][q] = e3 * inv;
        const float* bp = pred_boxes + ((size_t)b * NQ + q) * 6;
        float2 b0 = *reinterpret_cast<const float2*>(bp);
        float2 b1 = *reinterpret_cast<const float2*>(bp + 2);
        float2 b2 = *reinterpret_cast<const float2*>(bp + 4);
        pbx4[q] = make_float4(b0.x, b0.y, b1.x, b1.y);
        pbx2[q] = make_float2(b2.x, b2.y);
    }
    for (int j = tid; j <= NQ; j += THREADS) pcol[j] = 0;
    for (int j = tid; j < NQ; j += THREADS) claim[j] = 0x7FFFFFFF;
    for (int i2 = tid; i2 <= NM; i2 += THREADS) upot[i2] = 0.f;
    __syncthreads();

    const int lmode = f_lab_odd ? 0 : 1;                 // 0=int32, 1=int64
    const int mmode = f_m_not01 ? 2 : (f_m_odd ? 0 : 1); // 2=bytes,0=i32,1=i64

    // ---- Phase 1b: mask compaction + gt staging (wave 0 only) ----
    if (tid < 64) {
        int vv;
        if (mmode == 2)      vv = (mask_b[b * NM + lane] != 0);
        else if (mmode == 1) vv = (mask_w[(b * NM + lane) * 2] != 0u);
        else                 vv = (mask_w[b * NM + lane] != 0u);
        unsigned long long bal = __ballot(vv);
        if (vv) {
            int pos = (int)__popcll(bal & ((1ull << lane) - 1ull));
            vpos_s[pos] = lane;
        }
        if (lane == 0) m_sh = (int)__popcll(bal);
        __builtin_amdgcn_wave_barrier();
        int nw = (int)__popcll(bal);
        if (lane < nw) {
            int g = vpos_s[lane];
            lab[lane] = (int)(lmode ? labels_w[(size_t)(b * NM + g) * 2]
                                    : labels_w[b * NM + g]);
            const float* gp = gt_boxes + ((size_t)b * NM + g) * 6;
            gb4[lane] = make_float4(gp[0], gp[1], gp[2], gp[3]);
            gb2[lane] = make_float2(gp[4], gp[5]);
        }
    }
    __syncthreads();
    const int n = m_sh;

    // ---- Phase 1c: hoist this lane's 15 columns into registers ----
    // (per-wave copy; used by row reduction in all waves and SAP in wave 0)
    float cb0[NS], cb1[NS], cb2[NS], cb3[NS], cb4[NS], cb5[NS];
    float cp0[NS], cp1[NS], cp2[NS], cp3[NS];
    #pragma unroll
    for (int s = 0; s < NS; ++s) {
        const int q = s * 64 + lane;
        const int qc = (q < NQ) ? q : 0;
        const float4 p4 = pbx4[qc];
        const float2 p2 = pbx2[qc];
        cb0[s] = p4.x; cb1[s] = p4.y; cb2[s] = p4.z; cb3[s] = p4.w;
        cb4[s] = p2.x; cb5[s] = p2.y;
        cp0[s] = probT[0][qc]; cp1[s] = probT[1][qc];
        cp2[s] = probT[2][qc]; cp3[s] = probT[3][qc];
    }

    // ---- Phase 2a: row reduction — u[i] = min_j cost(i,j), argmin ----
    // rows strided across the 4 waves; cols across lanes (register-resident)
    for (int k = wv; k < n; k += 4) {
        const float4 g4 = gb4[k];
        const float2 g2 = gb2[k];
        const int lb = lab[k];
        float lmin = FLT_MAX; int lj = NQ + 2;
        #pragma unroll
        for (int s = 0; s < NS; ++s) {
            const int q = s * 64 + lane;
            float l1 = fabsf(cb0[s] - g4.x) + fabsf(cb1[s] - g4.y)
                     + fabsf(cb2[s] - g4.z) + fabsf(cb3[s] - g4.w)
                     + fabsf(cb4[s] - g2.x) + fabsf(cb5[s] - g2.y);
            float pr = (lb == 0) ? cp0[s] : ((lb == 1) ? cp1[s]
                     : ((lb == 2) ? cp2[s] : cp3[s]));
            float c = 5.0f * l1 - pr;
            if (q < NQ && c < lmin) { lmin = c; lj = q; }
        }
        float rv = lmin; int rj = lj;
        #pragma unroll
        for (int off = 32; off > 0; off >>= 1) {
            float ov = __shfl_xor(rv, off);
            int   oj = __shfl_xor(rj, off);
            if (ov < rv || (ov == rv && oj < rj)) { rv = ov; rj = oj; }
        }
        if (lane == 0) { rowmin_s[k] = rv; rowarg_s[k] = rj; }
    }
    __syncthreads();

    // ---- Phase 2b: greedy claim (dual-feasible partial assignment) ----
    if (tid < n) atomicMin(&claim[rowarg_s[tid]], tid);
    for (int k = tid; k < n; k += THREADS) upot[k + 1] = rowmin_s[k];
    if (tid == 0) upot[0] = 0.f;
    __syncthreads();
    if (tid < n) {
        int a = rowarg_s[tid];
        if (claim[a] == tid) pcol[a + 1] = tid + 1;   // unique winner
    }
    if (tid < 64) {
        int un = (lane < n) && (claim[rowarg_s[lane]] != lane);
        unsigned long long bal = __ballot(un);
        if (un) ua_s[(int)__popcll(bal & ((1ull << lane) - 1ull))] = lane;
        if (lane == 0) nua_s = (int)__popcll(bal);
    }
    __syncthreads();

    // ---- Phase 2c: shortest augmenting path for contested rows (wave 0) ----
    if (tid < 64) {
        float minv[NS], vpot[NS];
        int way[NS];
        #pragma unroll
        for (int s = 0; s < NS; ++s) vpot[s] = 0.f;
        const int nua = nua_s;

        for (int t = 0; t < nua; ++t) {
            const int i = ua_s[t] + 1;
            #pragma unroll
            for (int s = 0; s < NS; ++s) { minv[s] = FLT_MAX; way[s] = 0; }
            unsigned int usedm = 0;
            if (lane == 0) pcol[0] = i;
            int j0 = 0, i0 = i, T = 0, bj = 0;
            while (true) {
                // mark used[j0], append row i0 to the alternating tree
                if (j0 > 0 && ((j0 - 1) & 63) == lane)
                    usedm |= 1u << ((j0 - 1) >> 6);
                if (lane == 0) tree_i[T] = i0;
                T++;
                __builtin_amdgcn_wave_barrier();
                // scan row i0 over this lane's unused columns (registers only)
                const float base = upot[i0];
                const float4 g4 = gb4[i0 - 1];
                const float2 g2 = gb2[i0 - 1];
                const int lb = lab[i0 - 1];
                float lmin = FLT_MAX; int lj = NQ + 2;
                #pragma unroll
                for (int s = 0; s < NS; ++s) {
                    const int q = s * 64 + lane;
                    float l1 = fabsf(cb0[s] - g4.x) + fabsf(cb1[s] - g4.y)
                             + fabsf(cb2[s] - g4.z) + fabsf(cb3[s] - g4.w)
                             + fabsf(cb4[s] - g2.x) + fabsf(cb5[s] - g2.y);
                    float pr = (lb == 0) ? cp0[s] : ((lb == 1) ? cp1[s]
                             : ((lb == 2) ? cp2[s] : cp3[s]));
                    float cost = 5.0f * l1 - pr;
                    float cur = cost - base - vpot[s];
                    const bool isused = (usedm >> s) & 1u;
                    if ((q < NQ) && !isused) {
                        if (cur < minv[s]) { minv[s] = cur; way[s] = j0; }
                        if (minv[s] < lmin) { lmin = minv[s]; lj = q + 1; }
                    }
                }
                // wave argmin, lowest-index tie-break
                float rv = lmin; int rj = lj;
                #pragma unroll
                for (int off = 32; off > 0; off >>= 1) {
                    float ov = __shfl_xor(rv, off);
                    int   oj = __shfl_xor(rj, off);
                    if (ov < rv || (ov == rv && oj < rj)) { rv = ov; rj = oj; }
                }
                const float delta = rv;
                bj = rj;
                const int nr = pcol[bj];
                // u[rows in tree] += delta (distinct rows, lane-parallel)
                for (int tt = lane; tt < T; tt += 64)
                    upot[tree_i[tt]] += delta;
                // v[used] -= delta ; minv[unused] -= delta
                #pragma unroll
                for (int s = 0; s < NS; ++s) {
                    if ((usedm >> s) & 1u) vpot[s] -= delta;
                    else                   minv[s] -= delta;
                }
                __builtin_amdgcn_wave_barrier();
                if (nr == 0) break;     // bj is a free column
                j0 = bj; i0 = nr;
            }
            // augment along the alternating path (uniform across the wave)
            int jcur = bj;
            while (jcur != 0) {
                const int q = jcur - 1;
                const int sl = q >> 6, ln = q & 63;
                int wsel = 0;
                #pragma unroll
                for (int s = 0; s < NS; ++s) if (s == sl) wsel = way[s];
                const int jp = __shfl(wsel, ln);
                const int pv = pcol[jp];
                if (lane == 0) pcol[jcur] = pv;
                __builtin_amdgcn_wave_barrier();
                jcur = jp;
            }
        }
    }
    __syncthreads();

    // ---- Phase 3: losses over matched pairs (all 256 threads) ----
    for (int j = 1 + tid; j <= NQ; j += THREADS) {
        int r = pcol[j];
        if (r > 0) row2col[r - 1] = j - 1;
    }
    __syncthreads();
    float cs = 0.f, bs = 0.f;
    for (int k = tid; k < n; k += THREADS) {
        int q = row2col[k];
        int lb = lab[k];
        cs += -logf(probT[lb][q]);
        float4 p4 = pbx4[q]; float2 p2 = pbx2[q];
        float4 g4 = gb4[k];  float2 g2 = gb2[k];
        bs += fabsf(p4.x - g4.x) + fabsf(p4.y - g4.y) + fabsf(p4.z - g4.z)
            + fabsf(p4.w - g4.w) + fabsf(p2.x - g2.x) + fabsf(p2.y - g2.y);
    }
    for (int off = 32; off > 0; off >>= 1) {
        cs += __shfl_down(cs, off);
        bs += __shfl_down(bs, off);
    }
    {
        int wave = tid >> 6;
        if ((tid & 63) == 0) { redc[wave] = cs; redb[wave] = bs; }
    }
    __syncthreads();
    if (tid == 0) {
        cls_part[b] = redc[0] + redc[1] + redc[2] + redc[3];
        box_part[b] = redb[0] + redb[1] + redb[2] + redb[3];
        cnt_part[b] = n;
    }
}

__global__ void finalize_kernel(const float* __restrict__ cls_part,
                                const float* __restrict__ box_part,
                                const int* __restrict__ cnt_part,
                                float* __restrict__ out) {
    if (threadIdx.x == 0 && blockIdx.x == 0) {
        float c = 0.f, bx = 0.f;
        int nn = 0;
        for (int b = 0; b < NB; ++b) {
            c += cls_part[b]; bx += box_part[b]; nn += cnt_part[b];
        }
        float denom = (nn > 0) ? (float)nn : 1.0f;
        float cl = c / denom;
        float bl = bx / (6.0f * denom);
        out[0] = cl;
        out[1] = bl;
        out[2] = cl + 5.0f * bl;
    }
}

extern "C" void kernel_launch(void* const* d_in, const int* in_sizes, int n_in,
                              void* d_out, int out_size, void* d_ws, size_t ws_size,
                              hipStream_t stream) {
    const float* pred_boxes   = (const float*)d_in[0];
    const float* pred_classes = (const float*)d_in[1];
    const float* gt_boxes     = (const float*)d_in[2];
    const unsigned int*  labels_w = (const unsigned int*)d_in[3];
    const unsigned int*  mask_w   = (const unsigned int*)d_in[4];
    const unsigned char* mask_b   = (const unsigned char*)d_in[4];

    char* ws = (char*)d_ws;
    float* cls_part = (float*)(ws + 16);
    float* box_part = (float*)(ws + 16 + 4 * NB);
    int*   cnt_part = (int*)(ws + 16 + 8 * NB);
    float* out = (float*)d_out;

    match_kernel<<<NB, THREADS, 0, stream>>>(pred_boxes, pred_classes, gt_boxes,
                                             labels_w, mask_w, mask_b,
                                             cls_part, box_part, cnt_part);
    finalize_kernel<<<1, 64, 0, stream>>>(cls_part, box_part, cnt_part, out);
}

// Round 3
// 51.324 us; speedup vs baseline: 3.3487x; 1.7058x over previous
//
#include <hip/hip_runtime.h>
#include <cfloat>
#include <cmath>

#define NB 64
#define NQ 900
#define NM 64
#define NC 4
#define THREADS 256
#define NS 15   // ceil(NQ / 64) columns per lane

// Apply X to every subtile index (compile-time fanout -> named registers)
#define S_LIST(X) X(0) X(1) X(2) X(3) X(4) X(5) X(6) X(7) X(8) X(9) \
                  X(10) X(11) X(12) X(13) X(14)

__global__ __launch_bounds__(THREADS, 1) void match_kernel(
    const float* __restrict__ pred_boxes,    // [NB,NQ,6]
    const float* __restrict__ pred_classes,  // [NB,NQ,NC]
    const float* __restrict__ gt_boxes,      // [NB,NM,6]
    const unsigned int* __restrict__ labels_w,
    const unsigned int* __restrict__ mask_w,
    const unsigned char* __restrict__ mask_b,
    float* __restrict__ cls_part, float* __restrict__ box_part,
    int* __restrict__ cnt_part)
{
    __shared__ float4 pbx4[NQ];          // pred box dims 0..3
    __shared__ float2 pbx2[NQ];          // pred box dims 4..5
    __shared__ float  probT[NC][NQ];     // transposed softmax probs
    __shared__ int    pcol[NQ + 1];      // col -> matched row (1-based), 0=free
    __shared__ int    claim[NQ];         // greedy contention: min row claiming col
    __shared__ float  upot[NM + 1];      // row potentials (1-based)
    __shared__ int    tree_i[NM + 2];    // rows in the alternating tree
    __shared__ float4 gb4[NM];
    __shared__ float2 gb2[NM];
    __shared__ int    lab[NM];
    __shared__ int    vpos_s[NM];
    __shared__ int    row2col[NM];
    __shared__ float  rowmin_s[NM];
    __shared__ int    rowarg_s[NM];
    __shared__ int    ua_s[NM];          // unassigned rows after greedy
    __shared__ int    nua_s;
    __shared__ int    m_sh;
    __shared__ int    f_lab_odd, f_m_not01, f_m_odd;
    __shared__ float  redc[4], redb[4];

    const int b = blockIdx.x;
    const int tid = threadIdx.x;
    const int lane = tid & 63;
    const int wv = tid >> 6;

    if (tid == 0) { f_lab_odd = 0; f_m_not01 = 0; f_m_odd = 0; }
    __syncthreads();

    // ---- Phase 1a: dtype detection (first 4KB of each buffer) + staging ----
    for (int w = tid; w < 1024; w += THREADS) {
        unsigned int lw = labels_w[w];
        if ((w & 1) && lw != 0u) f_lab_odd = 1;   // benign race: all write 1
        unsigned int mw = mask_w[w];
        if (mw > 1u) f_m_not01 = 1;
        if ((w & 1) && mw != 0u) f_m_odd = 1;
    }
    for (int q = tid; q < NQ; q += THREADS) {
        const float4 lg = *reinterpret_cast<const float4*>(
            pred_classes + ((size_t)b * NQ + q) * NC);
        float mx = fmaxf(fmaxf(lg.x, lg.y), fmaxf(lg.z, lg.w));
        float e0 = expf(lg.x - mx), e1 = expf(lg.y - mx);
        float e2 = expf(lg.z - mx), e3 = expf(lg.w - mx);
        float inv = 1.0f / (e0 + e1 + e2 + e3);
        probT[0][q] = e0 * inv; probT[1][q] = e1 * inv;
        probT[2][q] = e2 * inv; probT[3][q] = e3 * inv;
        const float* bp = pred_boxes + ((size_t)b * NQ + q) * 6;
        float2 b0 = *reinterpret_cast<const float2*>(bp);
        float2 b1 = *reinterpret_cast<const float2*>(bp + 2);
        float2 b2 = *reinterpret_cast<const float2*>(bp + 4);
        pbx4[q] = make_float4(b0.x, b0.y, b1.x, b1.y);
        pbx2[q] = make_float2(b2.x, b2.y);
    }
    for (int j = tid; j <= NQ; j += THREADS) pcol[j] = 0;
    for (int j = tid; j < NQ; j += THREADS) claim[j] = 0x7FFFFFFF;
    for (int i2 = tid; i2 <= NM; i2 += THREADS) upot[i2] = 0.f;
    __syncthreads();

    const int lmode = f_lab_odd ? 0 : 1;                 // 0=int32, 1=int64
    const int mmode = f_m_not01 ? 2 : (f_m_odd ? 0 : 1); // 2=bytes,0=i32,1=i64

    // ---- Phase 1b: mask compaction + gt staging (wave 0 only) ----
    if (tid < 64) {
        int vv;
        if (mmode == 2)      vv = (mask_b[b * NM + lane] != 0);
        else if (mmode == 1) vv = (mask_w[(b * NM + lane) * 2] != 0u);
        else                 vv = (mask_w[b * NM + lane] != 0u);
        unsigned long long bal = __ballot(vv);
        if (vv) {
            int pos = (int)__popcll(bal & ((1ull << lane) - 1ull));
            vpos_s[pos] = lane;
        }
        if (lane == 0) m_sh = (int)__popcll(bal);
        __builtin_amdgcn_wave_barrier();
        int nw = (int)__popcll(bal);
        if (lane < nw) {
            int g = vpos_s[lane];
            lab[lane] = (int)(lmode ? labels_w[(size_t)(b * NM + g) * 2]
                                    : labels_w[b * NM + g]);
            const float* gp = gt_boxes + ((size_t)b * NM + g) * 6;
            gb4[lane] = make_float4(gp[0], gp[1], gp[2], gp[3]);
            gb2[lane] = make_float2(gp[4], gp[5]);
        }
    }
    __syncthreads();
    const int n = m_sh;

    // ---- Phase 1c: hoist this lane's 15 columns into NAMED registers ----
    // (arrays went to scratch in the previous version: VGPR=92 + 2MB extra
    //  FETCH. Named scalars leave the allocator no scratch option.)
#define DECL_COL(s) float cb0_##s, cb1_##s, cb2_##s, cb3_##s, cb4_##s, \
                          cb5_##s, cq0_##s, cq1_##s, cq2_##s, cq3_##s;
    S_LIST(DECL_COL)
#define HOIST(s) { const int q = (s) * 64 + lane; \
        const int qc = (q < NQ) ? q : 0; \
        const float4 h4 = pbx4[qc]; const float2 h2 = pbx2[qc]; \
        cb0_##s = h4.x; cb1_##s = h4.y; cb2_##s = h4.z; cb3_##s = h4.w; \
        cb4_##s = h2.x; cb5_##s = h2.y; \
        cq0_##s = probT[0][qc]; cq1_##s = probT[1][qc]; \
        cq2_##s = probT[2][qc]; cq3_##s = probT[3][qc]; }
    S_LIST(HOIST)

    // ---- Phase 2a: row reduction — u[i] = min_j cost(i,j), argmin ----
    // rows strided across the 4 waves; cols across lanes (register-resident)
    for (int k = wv; k < n; k += 4) {
        const float4 g4 = gb4[k];
        const float2 g2 = gb2[k];
        const int lb = lab[k];
        float lmin = FLT_MAX; int lj = NQ + 2;
#define RSCAN(s) { const int q = (s) * 64 + lane; \
        float l1 = fabsf(cb0_##s - g4.x) + fabsf(cb1_##s - g4.y) \
                 + fabsf(cb2_##s - g4.z) + fabsf(cb3_##s - g4.w) \
                 + fabsf(cb4_##s - g2.x) + fabsf(cb5_##s - g2.y); \
        float pr = (lb == 0) ? cq0_##s : ((lb == 1) ? cq1_##s \
                 : ((lb == 2) ? cq2_##s : cq3_##s)); \
        float c = 5.0f * l1 - pr; \
        if (q < NQ && c < lmin) { lmin = c; lj = q; } }
        S_LIST(RSCAN)
        float rv = lmin; int rj = lj;
        #pragma unroll
        for (int off = 32; off > 0; off >>= 1) {
            float ov = __shfl_xor(rv, off);
            int   oj = __shfl_xor(rj, off);
            if (ov < rv || (ov == rv && oj < rj)) { rv = ov; rj = oj; }
        }
        if (lane == 0) { rowmin_s[k] = rv; rowarg_s[k] = rj; }
    }
    __syncthreads();

    // ---- Phase 2b: greedy claim (dual-feasible partial assignment) ----
    if (tid < n) atomicMin(&claim[rowarg_s[tid]], tid);
    for (int k = tid; k < n; k += THREADS) upot[k + 1] = rowmin_s[k];
    if (tid == 0) upot[0] = 0.f;
    __syncthreads();
    if (tid < n) {
        int a = rowarg_s[tid];
        if (claim[a] == tid) pcol[a + 1] = tid + 1;   // unique winner
    }
    if (tid < 64) {
        int un = (lane < n) && (claim[rowarg_s[lane]] != lane);
        unsigned long long bal = __ballot(un);
        if (un) ua_s[(int)__popcll(bal & ((1ull << lane) - 1ull))] = lane;
        if (lane == 0) nua_s = (int)__popcll(bal);
    }
    __syncthreads();

    // ---- Phase 2c: shortest augmenting path for contested rows (wave 0) ----
    if (tid < 64) {
#define DECL_SAP(s) float minv_##s, vpot_##s; int way_##s;
        S_LIST(DECL_SAP)
#define INIT_VPOT(s) vpot_##s = 0.f;
        S_LIST(INIT_VPOT)
        const int nua = nua_s;

        for (int t = 0; t < nua; ++t) {
            const int i = ua_s[t] + 1;
#define INIT_MINV(s) { minv_##s = FLT_MAX; way_##s = 0; }
            S_LIST(INIT_MINV)
            unsigned int usedm = 0;
            if (lane == 0) pcol[0] = i;
            int j0 = 0, i0 = i, T = 0, bj = 0;
            while (true) {
                // mark used[j0], append row i0 to the alternating tree
                if (j0 > 0 && ((j0 - 1) & 63) == lane)
                    usedm |= 1u << ((j0 - 1) >> 6);
                if (lane == 0) tree_i[T] = i0;
                T++;
                __builtin_amdgcn_wave_barrier();
                // scan row i0 over this lane's unused columns (registers only)
                const float base = upot[i0];
                const float4 g4 = gb4[i0 - 1];
                const float2 g2 = gb2[i0 - 1];
                const int lb = lab[i0 - 1];
                float lmin = FLT_MAX; int lj = NQ + 2;
#define SSCAN(s) { const int q = (s) * 64 + lane; \
                float l1 = fabsf(cb0_##s - g4.x) + fabsf(cb1_##s - g4.y) \
                         + fabsf(cb2_##s - g4.z) + fabsf(cb3_##s - g4.w) \
                         + fabsf(cb4_##s - g2.x) + fabsf(cb5_##s - g2.y); \
                float pr = (lb == 0) ? cq0_##s : ((lb == 1) ? cq1_##s \
                         : ((lb == 2) ? cq2_##s : cq3_##s)); \
                float cur = 5.0f * l1 - pr - base - vpot_##s; \
                if ((q < NQ) && !((usedm >> (s)) & 1u)) { \
                    if (cur < minv_##s) { minv_##s = cur; way_##s = j0; } \
                    if (minv_##s < lmin) { lmin = minv_##s; lj = q + 1; } } }
                S_LIST(SSCAN)
                // wave argmin, lowest-index tie-break
                float rv = lmin; int rj = lj;
                #pragma unroll
                for (int off = 32; off > 0; off >>= 1) {
                    float ov = __shfl_xor(rv, off);
                    int   oj = __shfl_xor(rj, off);
                    if (ov < rv || (ov == rv && oj < rj)) { rv = ov; rj = oj; }
                }
                const float delta = rv;
                bj = rj;
                const int nr = pcol[bj];
                // u[rows in tree] += delta (distinct rows, lane-parallel)
                for (int tt = lane; tt < T; tt += 64)
                    upot[tree_i[tt]] += delta;
                // v[used] -= delta ; minv[unused] -= delta
#define UPDATE(s) { if ((usedm >> (s)) & 1u) vpot_##s -= delta; \
                    else                     minv_##s -= delta; }
                S_LIST(UPDATE)
                __builtin_amdgcn_wave_barrier();
                if (nr == 0) break;     // bj is a free column
                j0 = bj; i0 = nr;
            }
            // augment along the alternating path (uniform across the wave)
            int jcur = bj;
            while (jcur != 0) {
                const int q = jcur - 1;
                const int sl = q >> 6, ln = q & 63;
                int wsel = 0;
#define WSEL(s) if (sl == (s)) wsel = way_##s;
                S_LIST(WSEL)
                const int jp = __shfl(wsel, ln);
                const int pv = pcol[jp];
                if (lane == 0) pcol[jcur] = pv;
                __builtin_amdgcn_wave_barrier();
                jcur = jp;
            }
        }
    }
    __syncthreads();

    // ---- Phase 3: losses over matched pairs (all 256 threads) ----
    for (int j = 1 + tid; j <= NQ; j += THREADS) {
        int r = pcol[j];
        if (r > 0) row2col[r - 1] = j - 1;
    }
    __syncthreads();
    float cs = 0.f, bs = 0.f;
    for (int k = tid; k < n; k += THREADS) {
        int q = row2col[k];
        int lb = lab[k];
        cs += -logf(probT[lb][q]);
        float4 p4 = pbx4[q]; float2 p2 = pbx2[q];
        float4 g4 = gb4[k];  float2 g2 = gb2[k];
        bs += fabsf(p4.x - g4.x) + fabsf(p4.y - g4.y) + fabsf(p4.z - g4.z)
            + fabsf(p4.w - g4.w) + fabsf(p2.x - g2.x) + fabsf(p2.y - g2.y);
    }
    for (int off = 32; off > 0; off >>= 1) {
        cs += __shfl_down(cs, off);
        bs += __shfl_down(bs, off);
    }
    {
        int wave = tid >> 6;
        if ((tid & 63) == 0) { redc[wave] = cs; redb[wave] = bs; }
    }
    __syncthreads();
    if (tid == 0) {
        cls_part[b] = redc[0] + redc[1] + redc[2] + redc[3];
        box_part[b] = redb[0] + redb[1] + redb[2] + redb[3];
        cnt_part[b] = n;
    }
}

__global__ void finalize_kernel(const float* __restrict__ cls_part,
                                const float* __restrict__ box_part,
                                const int* __restrict__ cnt_part,
                                float* __restrict__ out) {
    if (threadIdx.x == 0 && blockIdx.x == 0) {
        float c = 0.f, bx = 0.f;
        int nn = 0;
        for (int b = 0; b < NB; ++b) {
            c += cls_part[b]; bx += box_part[b]; nn += cnt_part[b];
        }
        float denom = (nn > 0) ? (float)nn : 1.0f;
        float cl = c / denom;
        float bl = bx / (6.0f * denom);
        out[0] = cl;
        out[1] = bl;
        out[2] = cl + 5.0f * bl;
    }
}

extern "C" void kernel_launch(void* const* d_in, const int* in_sizes, int n_in,
                              void* d_out, int out_size, void* d_ws, size_t ws_size,
                              hipStream_t stream) {
    const float* pred_boxes   = (const float*)d_in[0];
    const float* pred_classes = (const float*)d_in[1];
    const float* gt_boxes     = (const float*)d_in[2];
    const unsigned int*  labels_w = (const unsigned int*)d_in[3];
    const unsigned int*  mask_w   = (const unsigned int*)d_in[4];
    const unsigned char* mask_b   = (const unsigned char*)d_in[4];

    char* ws = (char*)d_ws;
    float* cls_part = (float*)(ws + 16);
    float* box_part = (float*)(ws + 16 + 4 * NB);
    int*   cnt_part = (int*)(ws + 16 + 8 * NB);
    float* out = (float*)d_out;

    match_kernel<<<NB, THREADS, 0, stream>>>(pred_boxes, pred_classes, gt_boxes,
                                             labels_w, mask_w, mask_b,
                                             cls_part, box_part, cnt_part);
    finalize_kernel<<<1, 64, 0, stream>>>(cls_part, box_part, cnt_part, out);
}

// Round 4
// 42.234 us; speedup vs baseline: 4.0695x; 1.2152x over previous
//
#include <hip/hip_runtime.h>
#include <cfloat>
#include <cmath>

#define NB 64
#define NQ 900
#define NM 64
#define NC 4
#define THREADS 256
#define NS 15   // ceil(NQ / 64) columns per lane

// Apply X to every subtile index (compile-time fanout -> named registers)
#define S_LIST(X) X(0) X(1) X(2) X(3) X(4) X(5) X(6) X(7) X(8) X(9) \
                  X(10) X(11) X(12) X(13) X(14)

__device__ __forceinline__ unsigned int uminu(unsigned int a, unsigned int b) {
    return a < b ? a : b;
}

// Wave-64 min reduction on the VALU pipe: 4x DPP row_shr + readlane of the
// 4 row minima + scalar mins. Result is wave-uniform. (Replaces the 6-step
// __shfl_xor butterfly = 12 dependent ds_bpermute ~600cy with ~100cy.)
__device__ __forceinline__ unsigned int wave_redmin_u32(unsigned int x) {
    int t;
    t = __builtin_amdgcn_update_dpp(-1, (int)x, 0x111, 0xF, 0xF, false); // shr:1
    x = uminu(x, (unsigned)t);
    t = __builtin_amdgcn_update_dpp(-1, (int)x, 0x112, 0xF, 0xF, false); // shr:2
    x = uminu(x, (unsigned)t);
    t = __builtin_amdgcn_update_dpp(-1, (int)x, 0x114, 0xF, 0xF, false); // shr:4
    x = uminu(x, (unsigned)t);
    t = __builtin_amdgcn_update_dpp(-1, (int)x, 0x118, 0xF, 0xF, false); // shr:8
    x = uminu(x, (unsigned)t);
    unsigned a = (unsigned)__builtin_amdgcn_readlane((int)x, 15);
    unsigned b = (unsigned)__builtin_amdgcn_readlane((int)x, 31);
    unsigned c = (unsigned)__builtin_amdgcn_readlane((int)x, 47);
    unsigned d = (unsigned)__builtin_amdgcn_readlane((int)x, 63);
    return uminu(uminu(a, b), uminu(c, d));
}

// Wave argmin with exact np.argmin (lowest index on ties) semantics.
// Monotonic float->u32 key; min key; then min index among key-equal lanes.
// Each lane's lj is its FIRST in-lane attainer, so the global first-min
// index is always in the candidate set and is its minimum.
__device__ __forceinline__ void wave_argmin_f(float lmin, int lj,
                                              float& mv, int& mj) {
    unsigned u = __float_as_uint(lmin);
    unsigned key = (u & 0x80000000u) ? ~u : (u | 0x80000000u);
    unsigned mk = wave_redmin_u32(key);
    unsigned cand = (key == mk) ? (unsigned)lj : 0x7FFFFFFFu;
    mj = (int)wave_redmin_u32(cand);
    unsigned mu = (mk & 0x80000000u) ? (mk & 0x7FFFFFFFu) : ~mk;
    mv = __uint_as_float(mu);
}

__global__ __launch_bounds__(THREADS, 1) void match_kernel(
    const float* __restrict__ pred_boxes,    // [NB,NQ,6]
    const float* __restrict__ pred_classes,  // [NB,NQ,NC]
    const float* __restrict__ gt_boxes,      // [NB,NM,6]
    const unsigned int* __restrict__ labels_w,
    const unsigned int* __restrict__ mask_w,
    const unsigned char* __restrict__ mask_b,
    float* __restrict__ cls_part, float* __restrict__ box_part,
    int* __restrict__ cnt_part)
{
    __shared__ float4 pbx4[NQ];          // pred box dims 0..3
    __shared__ float2 pbx2[NQ];          // pred box dims 4..5
    __shared__ float  probT[NC][NQ];     // transposed softmax probs
    __shared__ int    pcol[NQ + 1];      // col -> matched row (1-based), 0=free
    __shared__ int    claim[NQ];         // greedy contention: min row claiming col
    __shared__ float  upot[NM + 1];      // row potentials (1-based)
    __shared__ int    tree_i[NM + 2];    // rows in the alternating tree
    __shared__ float4 gb4[NM];
    __shared__ float2 gb2[NM];
    __shared__ int    lab[NM];
    __shared__ int    vpos_s[NM];
    __shared__ int    row2col[NM];
    __shared__ float  rowmin_s[NM];
    __shared__ int    rowarg_s[NM];
    __shared__ int    ua_s[NM];          // unassigned rows after greedy
    __shared__ int    nua_s;
    __shared__ int    m_sh;
    __shared__ int    f_lab_odd, f_m_not01, f_m_odd;
    __shared__ float  redc[4], redb[4];

    const int b = blockIdx.x;
    const int tid = threadIdx.x;
    const int lane = tid & 63;
    const int wv = tid >> 6;

    if (tid == 0) { f_lab_odd = 0; f_m_not01 = 0; f_m_odd = 0; }
    __syncthreads();

    // ---- Phase 1a: dtype detection (first 4KB of each buffer) + staging ----
    for (int w = tid; w < 1024; w += THREADS) {
        unsigned int lw = labels_w[w];
        if ((w & 1) && lw != 0u) f_lab_odd = 1;   // benign race: all write 1
        unsigned int mw = mask_w[w];
        if (mw > 1u) f_m_not01 = 1;
        if ((w & 1) && mw != 0u) f_m_odd = 1;
    }
    for (int q = tid; q < NQ; q += THREADS) {
        const float4 lg = *reinterpret_cast<const float4*>(
            pred_classes + ((size_t)b * NQ + q) * NC);
        float mx = fmaxf(fmaxf(lg.x, lg.y), fmaxf(lg.z, lg.w));
        float e0 = expf(lg.x - mx), e1 = expf(lg.y - mx);
        float e2 = expf(lg.z - mx), e3 = expf(lg.w - mx);
        float inv = 1.0f / (e0 + e1 + e2 + e3);
        probT[0][q] = e0 * inv; probT[1][q] = e1 * inv;
        probT[2][q] = e2 * inv; probT[3][q] = e3 * inv;
        const float* bp = pred_boxes + ((size_t)b * NQ + q) * 6;
        float2 b0 = *reinterpret_cast<const float2*>(bp);
        float2 b1 = *reinterpret_cast<const float2*>(bp + 2);
        float2 b2 = *reinterpret_cast<const float2*>(bp + 4);
        pbx4[q] = make_float4(b0.x, b0.y, b1.x, b1.y);
        pbx2[q] = make_float2(b2.x, b2.y);
    }
    for (int j = tid; j <= NQ; j += THREADS) pcol[j] = 0;
    for (int j = tid; j < NQ; j += THREADS) claim[j] = 0x7FFFFFFF;
    for (int i2 = tid; i2 <= NM; i2 += THREADS) upot[i2] = 0.f;
    __syncthreads();

    const int lmode = f_lab_odd ? 0 : 1;                 // 0=int32, 1=int64
    const int mmode = f_m_not01 ? 2 : (f_m_odd ? 0 : 1); // 2=bytes,0=i32,1=i64

    // ---- Phase 1b: mask compaction + gt staging (wave 0 only) ----
    if (tid < 64) {
        int vv;
        if (mmode == 2)      vv = (mask_b[b * NM + lane] != 0);
        else if (mmode == 1) vv = (mask_w[(b * NM + lane) * 2] != 0u);
        else                 vv = (mask_w[b * NM + lane] != 0u);
        unsigned long long bal = __ballot(vv);
        if (vv) {
            int pos = (int)__popcll(bal & ((1ull << lane) - 1ull));
            vpos_s[pos] = lane;
        }
        if (lane == 0) m_sh = (int)__popcll(bal);
        __builtin_amdgcn_wave_barrier();
        int nw = (int)__popcll(bal);
        if (lane < nw) {
            int g = vpos_s[lane];
            lab[lane] = (int)(lmode ? labels_w[(size_t)(b * NM + g) * 2]
                                    : labels_w[b * NM + g]);
            const float* gp = gt_boxes + ((size_t)b * NM + g) * 6;
            gb4[lane] = make_float4(gp[0], gp[1], gp[2], gp[3]);
            gb2[lane] = make_float2(gp[4], gp[5]);
        }
    }
    __syncthreads();
    const int n = m_sh;

    // ---- Phase 1c: hoist this lane's 15 column boxes into NAMED registers.
    // Probs stay in LDS (probT[lb][q] read in-scan: 1 conflict-free ds_read
    // per subtile on the LDS pipe instead of 3 v_cndmask on the VALU path).
#define DECL_COL(s) float cb0_##s, cb1_##s, cb2_##s, cb3_##s, cb4_##s, cb5_##s;
    S_LIST(DECL_COL)
#define HOIST(s) { const int q = (s) * 64 + lane; \
        const int qc = (q < NQ) ? q : 0; \
        const float4 h4 = pbx4[qc]; const float2 h2 = pbx2[qc]; \
        cb0_##s = h4.x; cb1_##s = h4.y; cb2_##s = h4.z; cb3_##s = h4.w; \
        cb4_##s = h2.x; cb5_##s = h2.y; }
    S_LIST(HOIST)

    // ---- Phase 2a: row reduction — u[i] = min_j cost(i,j), argmin ----
    // rows strided across the 4 waves; cols across lanes (register-resident)
    for (int k = wv; k < n; k += 4) {
        const float4 g4 = gb4[k];
        const float2 g2 = gb2[k];
        const float* prow = probT[lab[k]];
        float lmin = FLT_MAX; int lj = NQ + 2;
#define RSCAN(s) { const int q = (s) * 64 + lane; \
        const int qc = (q < NQ) ? q : 0; \
        float l1 = fabsf(cb0_##s - g4.x) + fabsf(cb1_##s - g4.y) \
                 + fabsf(cb2_##s - g4.z) + fabsf(cb3_##s - g4.w) \
                 + fabsf(cb4_##s - g2.x) + fabsf(cb5_##s - g2.y); \
        float c = 5.0f * l1 - prow[qc]; \
        if (q < NQ && c < lmin) { lmin = c; lj = q; } }
        S_LIST(RSCAN)
        float mv; int mj;
        wave_argmin_f(lmin, lj, mv, mj);
        if (lane == 0) { rowmin_s[k] = mv; rowarg_s[k] = mj; }
    }
    __syncthreads();

    // ---- Phase 2b: greedy claim (dual-feasible partial assignment) ----
    if (tid < n) atomicMin(&claim[rowarg_s[tid]], tid);
    for (int k = tid; k < n; k += THREADS) upot[k + 1] = rowmin_s[k];
    if (tid == 0) upot[0] = 0.f;
    __syncthreads();
    if (tid < n) {
        int a = rowarg_s[tid];
        if (claim[a] == tid) pcol[a + 1] = tid + 1;   // unique winner
    }
    if (tid < 64) {
        int un = (lane < n) && (claim[rowarg_s[lane]] != lane);
        unsigned long long bal = __ballot(un);
        if (un) ua_s[(int)__popcll(bal & ((1ull << lane) - 1ull))] = lane;
        if (lane == 0) nua_s = (int)__popcll(bal);
    }
    __syncthreads();

    // ---- Phase 2c: shortest augmenting path for contested rows (wave 0) ----
    if (tid < 64) {
#define DECL_SAP(s) float minv_##s, vpot_##s; int way_##s;
        S_LIST(DECL_SAP)
#define INIT_VPOT(s) vpot_##s = 0.f;
        S_LIST(INIT_VPOT)
        const int nua = nua_s;

        for (int t = 0; t < nua; ++t) {
            const int i = ua_s[t] + 1;
#define INIT_MINV(s) { minv_##s = FLT_MAX; way_##s = 0; }
            S_LIST(INIT_MINV)
            unsigned int usedm = 0;
            if (lane == 0) pcol[0] = i;
            int j0 = 0, i0 = i, T = 0, bj = 0;
            while (true) {
                // mark used[j0], append row i0 to the alternating tree
                if (j0 > 0 && ((j0 - 1) & 63) == lane)
                    usedm |= 1u << ((j0 - 1) >> 6);
                if (lane == 0) tree_i[T] = i0;
                T++;
                __builtin_amdgcn_wave_barrier();
                // scan row i0 over this lane's unused columns
                const float base = upot[i0];
                const float4 g4 = gb4[i0 - 1];
                const float2 g2 = gb2[i0 - 1];
                const float* prow = probT[lab[i0 - 1]];
                float lmin = FLT_MAX; int lj = NQ + 2;
#define SSCAN(s) { const int q = (s) * 64 + lane; \
                const int qc = (q < NQ) ? q : 0; \
                float l1 = fabsf(cb0_##s - g4.x) + fabsf(cb1_##s - g4.y) \
                         + fabsf(cb2_##s - g4.z) + fabsf(cb3_##s - g4.w) \
                         + fabsf(cb4_##s - g2.x) + fabsf(cb5_##s - g2.y); \
                float cost = 5.0f * l1 - prow[qc]; \
                float cur = cost - base - vpot_##s; \
                if ((q < NQ) && !((usedm >> (s)) & 1u)) { \
                    if (cur < minv_##s) { minv_##s = cur; way_##s = j0; } \
                    if (minv_##s < lmin) { lmin = minv_##s; lj = q + 1; } } }
                S_LIST(SSCAN)
                float delta; int rbj;
                wave_argmin_f(lmin, lj, delta, rbj);
                bj = rbj;
                const int nr = pcol[bj];
                // u[rows in tree] += delta (distinct rows, lane-parallel)
                for (int tt = lane; tt < T; tt += 64)
                    upot[tree_i[tt]] += delta;
                // v[used] -= delta ; minv[unused] -= delta
#define UPDATE(s) { if ((usedm >> (s)) & 1u) vpot_##s -= delta; \
                    else                     minv_##s -= delta; }
                S_LIST(UPDATE)
                __builtin_amdgcn_wave_barrier();
                if (nr == 0) break;     // bj is a free column
                j0 = bj; i0 = nr;
            }
            // augment along the alternating path (uniform across the wave)
            int jcur = bj;
            while (jcur != 0) {
                const int q = jcur - 1;
                const int sl = q >> 6, ln = q & 63;
                int wsel = 0;
#define WSEL(s) if (sl == (s)) wsel = way_##s;
                S_LIST(WSEL)
                const int jp = __builtin_amdgcn_readlane(wsel, ln); // ln uniform
                const int pv = pcol[jp];
                if (lane == 0) pcol[jcur] = pv;
                __builtin_amdgcn_wave_barrier();
                jcur = jp;
            }
        }
    }
    __syncthreads();

    // ---- Phase 3: losses over matched pairs (all 256 threads) ----
    // (summation structure unchanged from the verified kernel)
    for (int j = 1 + tid; j <= NQ; j += THREADS) {
        int r = pcol[j];
        if (r > 0) row2col[r - 1] = j - 1;
    }
    __syncthreads();
    float cs = 0.f, bs = 0.f;
    for (int k = tid; k < n; k += THREADS) {
        int q = row2col[k];
        int lb = lab[k];
        cs += -logf(probT[lb][q]);
        float4 p4 = pbx4[q]; float2 p2 = pbx2[q];
        float4 g4 = gb4[k];  float2 g2 = gb2[k];
        bs += fabsf(p4.x - g4.x) + fabsf(p4.y - g4.y) + fabsf(p4.z - g4.z)
            + fabsf(p4.w - g4.w) + fabsf(p2.x - g2.x) + fabsf(p2.y - g2.y);
    }
    for (int off = 32; off > 0; off >>= 1) {
        cs += __shfl_down(cs, off);
        bs += __shfl_down(bs, off);
    }
    {
        int wave = tid >> 6;
        if ((tid & 63) == 0) { redc[wave] = cs; redb[wave] = bs; }
    }
    __syncthreads();
    if (tid == 0) {
        cls_part[b] = redc[0] + redc[1] + redc[2] + redc[3];
        box_part[b] = redb[0] + redb[1] + redb[2] + redb[3];
        cnt_part[b] = n;
    }
}

__global__ void finalize_kernel(const float* __restrict__ cls_part,
                                const float* __restrict__ box_part,
                                const int* __restrict__ cnt_part,
                                float* __restrict__ out) {
    if (threadIdx.x == 0 && blockIdx.x == 0) {
        float c = 0.f, bx = 0.f;
        int nn = 0;
        for (int b = 0; b < NB; ++b) {
            c += cls_part[b]; bx += box_part[b]; nn += cnt_part[b];
        }
        float denom = (nn > 0) ? (float)nn : 1.0f;
        float cl = c / denom;
        float bl = bx / (6.0f * denom);
        out[0] = cl;
        out[1] = bl;
        out[2] = cl + 5.0f * bl;
    }
}

extern "C" void kernel_launch(void* const* d_in, const int* in_sizes, int n_in,
                              void* d_out, int out_size, void* d_ws, size_t ws_size,
                              hipStream_t stream) {
    const float* pred_boxes   = (const float*)d_in[0];
    const float* pred_classes = (const float*)d_in[1];
    const float* gt_boxes     = (const float*)d_in[2];
    const unsigned int*  labels_w = (const unsigned int*)d_in[3];
    const unsigned int*  mask_w   = (const unsigned int*)d_in[4];
    const unsigned char* mask_b   = (const unsigned char*)d_in[4];

    char* ws = (char*)d_ws;
    float* cls_part = (float*)(ws + 16);
    float* box_part = (float*)(ws + 16 + 4 * NB);
    int*   cnt_part = (int*)(ws + 16 + 8 * NB);
    float* out = (float*)d_out;

    match_kernel<<<NB, THREADS, 0, stream>>>(pred_boxes, pred_classes, gt_boxes,
                                             labels_w, mask_w, mask_b,
                                             cls_part, box_part, cnt_part);
    finalize_kernel<<<1, 64, 0, stream>>>(cls_part, box_part, cnt_part, out);
}

// Round 5
// 42.158 us; speedup vs baseline: 4.0768x; 1.0018x over previous
//
#include <hip/hip_runtime.h>
#include <cfloat>
#include <cmath>

#define NB 64
#define NQ 900
#define NM 64
#define NC 4
#define THREADS 256
#define NS 15   // columns per lane (lane-major: lane l owns [15l, 15l+15), l<60)

// Apply X to every subtile index (compile-time fanout -> named registers)
#define S_LIST(X) X(0) X(1) X(2) X(3) X(4) X(5) X(6) X(7) X(8) X(9) \
                  X(10) X(11) X(12) X(13) X(14)

__device__ __forceinline__ unsigned int uminu(unsigned int a, unsigned int b) {
    return a < b ? a : b;
}

__device__ __forceinline__ float readlane_f(float v, int l) {
    return __uint_as_float(
        (unsigned)__builtin_amdgcn_readlane(__float_as_int(v), l));
}

// Wave-64 min reduction on the VALU pipe: 4x DPP row_shr + readlane of the
// 4 row minima + scalar mins. Result is wave-uniform.
__device__ __forceinline__ unsigned int wave_redmin_u32(unsigned int x) {
    int t;
    t = __builtin_amdgcn_update_dpp(-1, (int)x, 0x111, 0xF, 0xF, false); // shr:1
    x = uminu(x, (unsigned)t);
    t = __builtin_amdgcn_update_dpp(-1, (int)x, 0x112, 0xF, 0xF, false); // shr:2
    x = uminu(x, (unsigned)t);
    t = __builtin_amdgcn_update_dpp(-1, (int)x, 0x114, 0xF, 0xF, false); // shr:4
    x = uminu(x, (unsigned)t);
    t = __builtin_amdgcn_update_dpp(-1, (int)x, 0x118, 0xF, 0xF, false); // shr:8
    x = uminu(x, (unsigned)t);
    unsigned a = (unsigned)__builtin_amdgcn_readlane((int)x, 15);
    unsigned b = (unsigned)__builtin_amdgcn_readlane((int)x, 31);
    unsigned c = (unsigned)__builtin_amdgcn_readlane((int)x, 47);
    unsigned d = (unsigned)__builtin_amdgcn_readlane((int)x, 63);
    return uminu(uminu(a, b), uminu(c, d));
}

// Wave argmin with exact np.argmin (lowest index on ties) semantics.
// Lane-major column ownership makes lane order == column order, so the
// index pass is just ballot + find-first-set + one readlane.
__device__ __forceinline__ void wave_argmin_f(float lmin, int lj,
                                              float& mv, int& mj) {
    unsigned u = __float_as_uint(lmin);
    unsigned key = (u & 0x80000000u) ? ~u : (u | 0x80000000u);
    unsigned mk = wave_redmin_u32(key);
    unsigned long long bal = __ballot(key == mk);
    int fl = (int)__builtin_ctzll(bal);
    mj = __builtin_amdgcn_readlane(lj, fl);
    unsigned mu = (mk & 0x80000000u) ? (mk & 0x7FFFFFFFu) : ~mk;
    mv = __uint_as_float(mu);
}

__global__ __launch_bounds__(THREADS, 1) void match_kernel(
    const float* __restrict__ pred_boxes,    // [NB,NQ,6]
    const float* __restrict__ pred_classes,  // [NB,NQ,NC]
    const float* __restrict__ gt_boxes,      // [NB,NM,6]
    const unsigned int* __restrict__ labels_w,
    const unsigned int* __restrict__ mask_w,
    const unsigned char* __restrict__ mask_b,
    float* __restrict__ cls_part, float* __restrict__ box_part,
    int* __restrict__ cnt_part)
{
    __shared__ float4 pbx4[NQ];          // pred box dims 0..3
    __shared__ float2 pbx2[NQ];          // pred box dims 4..5
    __shared__ float  probT[NC][NQ];     // transposed softmax probs
    __shared__ int    pcol[NQ + 1];      // col -> matched row (1-based), 0=free
    __shared__ int    claim[NQ];         // greedy contention: min row claiming col
    __shared__ float4 gb4[NM];
    __shared__ float2 gb2[NM];
    __shared__ int    lab[NM];
    __shared__ int    vpos_s[NM];
    __shared__ int    row2col[NM];
    __shared__ float  rowmin_s[NM];
    __shared__ int    rowarg_s[NM];
    __shared__ int    ua_s[NM];          // unassigned rows after greedy
    __shared__ int    nua_s;
    __shared__ int    m_sh;
    __shared__ int    f_lab_odd, f_m_not01, f_m_odd;
    __shared__ float  redc[4], redb[4];

    const int b = blockIdx.x;
    const int tid = threadIdx.x;
    const int lane = tid & 63;
    const int wv = tid >> 6;

    if (tid == 0) { f_lab_odd = 0; f_m_not01 = 0; f_m_odd = 0; }
    __syncthreads();

    // ---- Phase 1a: dtype detection (first 4KB of each buffer) + staging ----
    for (int w = tid; w < 1024; w += THREADS) {
        unsigned int lw = labels_w[w];
        if ((w & 1) && lw != 0u) f_lab_odd = 1;   // benign race: all write 1
        unsigned int mw = mask_w[w];
        if (mw > 1u) f_m_not01 = 1;
        if ((w & 1) && mw != 0u) f_m_odd = 1;
    }
    for (int q = tid; q < NQ; q += THREADS) {
        const float4 lg = *reinterpret_cast<const float4*>(
            pred_classes + ((size_t)b * NQ + q) * NC);
        float mx = fmaxf(fmaxf(lg.x, lg.y), fmaxf(lg.z, lg.w));
        float e0 = expf(lg.x - mx), e1 = expf(lg.y - mx);
        float e2 = expf(lg.z - mx), e3 = expf(lg.w - mx);
        float inv = 1.0f / (e0 + e1 + e2 + e3);
        probT[0][q] = e0 * inv; probT[1][q] = e1 * inv;
        probT[2][q] = e2 * inv; probT[3][q] = e3 * inv;
        const float* bp = pred_boxes + ((size_t)b * NQ + q) * 6;
        float2 b0 = *reinterpret_cast<const float2*>(bp);
        float2 b1 = *reinterpret_cast<const float2*>(bp + 2);
        float2 b2 = *reinterpret_cast<const float2*>(bp + 4);
        pbx4[q] = make_float4(b0.x, b0.y, b1.x, b1.y);
        pbx2[q] = make_float2(b2.x, b2.y);
    }
    for (int j = tid; j <= NQ; j += THREADS) pcol[j] = 0;
    for (int j = tid; j < NQ; j += THREADS) claim[j] = 0x7FFFFFFF;
    __syncthreads();

    const int lmode = f_lab_odd ? 0 : 1;                 // 0=int32, 1=int64
    const int mmode = f_m_not01 ? 2 : (f_m_odd ? 0 : 1); // 2=bytes,0=i32,1=i64

    // ---- Phase 1b: mask compaction + gt staging (wave 0 only) ----
    if (tid < 64) {
        int vv;
        if (mmode == 2)      vv = (mask_b[b * NM + lane] != 0);
        else if (mmode == 1) vv = (mask_w[(b * NM + lane) * 2] != 0u);
        else                 vv = (mask_w[b * NM + lane] != 0u);
        unsigned long long bal = __ballot(vv);
        if (vv) {
            int pos = (int)__popcll(bal & ((1ull << lane) - 1ull));
            vpos_s[pos] = lane;
        }
        if (lane == 0) m_sh = (int)__popcll(bal);
        __builtin_amdgcn_wave_barrier();
        int nw = (int)__popcll(bal);
        if (lane < nw) {
            int g = vpos_s[lane];
            lab[lane] = (int)(lmode ? labels_w[(size_t)(b * NM + g) * 2]
                                    : labels_w[b * NM + g]);
            const float* gp = gt_boxes + ((size_t)b * NM + g) * 6;
            gb4[lane] = make_float4(gp[0], gp[1], gp[2], gp[3]);
            gb2[lane] = make_float2(gp[4], gp[5]);
        }
    }
    __syncthreads();
    const int n = m_sh;

    // ---- Phase 1c: hoist this lane's 15 column boxes into NAMED registers.
    // Lane-major: lane l owns q = 15l + s (l < 60). Lanes 60-63 idle (lv=0).
    const bool lv = (lane < 60);
    const int qb = lv ? lane * NS : 0;   // clamped base for safe LDS indexing
#define DECL_COL(s) float cb0_##s, cb1_##s, cb2_##s, cb3_##s, cb4_##s, cb5_##s;
    S_LIST(DECL_COL)
#define HOIST(s) { const float4 h4 = pbx4[qb + (s)]; \
        const float2 h2 = pbx2[qb + (s)]; \
        cb0_##s = h4.x; cb1_##s = h4.y; cb2_##s = h4.z; cb3_##s = h4.w; \
        cb4_##s = h2.x; cb5_##s = h2.y; }
    S_LIST(HOIST)

    // ---- Phase 2a: row reduction — u[i] = min_j cost(i,j), argmin ----
    // rows strided across the 4 waves; cols across lanes (register-resident)
    for (int k = wv; k < n; k += 4) {
        const float4 g4 = gb4[k];
        const float2 g2 = gb2[k];
        const float* prow = probT[lab[k]];
        float lmin = FLT_MAX; int lj = NQ + 2;
#define RSCAN(s) { \
        float l1 = fabsf(cb0_##s - g4.x) + fabsf(cb1_##s - g4.y) \
                 + fabsf(cb2_##s - g4.z) + fabsf(cb3_##s - g4.w) \
                 + fabsf(cb4_##s - g2.x) + fabsf(cb5_##s - g2.y); \
        float c = 5.0f * l1 - prow[qb + (s)]; \
        if (lv && c < lmin) { lmin = c; lj = qb + (s); } }
        S_LIST(RSCAN)
        float mv; int mj;
        wave_argmin_f(lmin, lj, mv, mj);
        if (lane == 0) { rowmin_s[k] = mv; rowarg_s[k] = mj; }
    }
    __syncthreads();

    // ---- Phase 2b: greedy claim (dual-feasible partial assignment) ----
    if (tid < n) atomicMin(&claim[rowarg_s[tid]], tid);
    __syncthreads();
    if (tid < n) {
        int a = rowarg_s[tid];
        if (claim[a] == tid) pcol[a + 1] = tid + 1;   // unique winner
    }
    if (tid < 64) {
        int un = (lane < n) && (claim[rowarg_s[lane]] != lane);
        unsigned long long bal = __ballot(un);
        if (un) ua_s[(int)__popcll(bal & ((1ull << lane) - 1ull))] = lane;
        if (lane == 0) nua_s = (int)__popcll(bal);
    }
    __syncthreads();

    // ---- Phase 2c: shortest augmenting path for contested rows (wave 0) ----
    // Row state lives in lane registers: lane k holds row k+1's dual (ur),
    // gt box (gr0..5) and label (labr); broadcast via readlane (uniform idx).
    if (tid < 64) {
#define DECL_SAP(s) float minv_##s, vpot_##s; int way_##s;
        S_LIST(DECL_SAP)
#define INIT_VPOT(s) vpot_##s = 0.f;
        S_LIST(INIT_VPOT)
        float ur = (lane < n) ? rowmin_s[lane] : 0.f;
        float gr0 = 0.f, gr1 = 0.f, gr2 = 0.f, gr3 = 0.f, gr4 = 0.f, gr5 = 0.f;
        int labr = 0;
        if (lane < n) {
            const float4 h4 = gb4[lane]; const float2 h2 = gb2[lane];
            gr0 = h4.x; gr1 = h4.y; gr2 = h4.z; gr3 = h4.w;
            gr4 = h2.x; gr5 = h2.y; labr = lab[lane];
        }
        const int nua = nua_s;

        for (int t = 0; t < nua; ++t) {
            const int i = ua_s[t] + 1;
#define INIT_MINV(s) { minv_##s = FLT_MAX; way_##s = 0; }
            S_LIST(INIT_MINV)
            unsigned int usedm = 0;
            int intree = 0;
            if (lane == 0) pcol[0] = i;
            int j0 = 0, i0 = i, T_dummy = 0, bj = 0;
            (void)T_dummy;
            while (true) {
                // mark used[j0] (lane-major: col j0-1 -> lane (j0-1)/15),
                // append row i0 to the tree (per-lane flag)
                if (j0 > 0 && ((j0 - 1) / NS) == lane)
                    usedm |= 1u << ((j0 - 1) % NS);
                if (lane == i0 - 1) intree = 1;
                __builtin_amdgcn_wave_barrier();
                // broadcast row i0's data from its owner lane (registers)
                const float base = readlane_f(ur, i0 - 1);
                const float g0 = readlane_f(gr0, i0 - 1);
                const float g1 = readlane_f(gr1, i0 - 1);
                const float g2 = readlane_f(gr2, i0 - 1);
                const float g3 = readlane_f(gr3, i0 - 1);
                const float g4 = readlane_f(gr4, i0 - 1);
                const float g5 = readlane_f(gr5, i0 - 1);
                const int lb = __builtin_amdgcn_readlane(labr, i0 - 1);
                const float* prow = probT[lb];
                float lmin = FLT_MAX; int lj = NQ + 2;
#define SSCAN(s) { \
                float l1 = fabsf(cb0_##s - g0) + fabsf(cb1_##s - g1) \
                         + fabsf(cb2_##s - g2) + fabsf(cb3_##s - g3) \
                         + fabsf(cb4_##s - g4) + fabsf(cb5_##s - g5); \
                float cost = 5.0f * l1 - prow[qb + (s)]; \
                float cur = cost - base - vpot_##s; \
                if (lv && !((usedm >> (s)) & 1u)) { \
                    if (cur < minv_##s) { minv_##s = cur; way_##s = j0; } \
                    if (minv_##s < lmin) { lmin = minv_##s; lj = qb + (s) + 1; } } }
                S_LIST(SSCAN)
                float delta; int rbj;
                wave_argmin_f(lmin, lj, delta, rbj);
                bj = rbj;
                const int nr = pcol[bj];
                // u[rows in tree] += delta (per-lane predicated, no LDS)
                if (intree) ur += delta;
                // v[used] -= delta ; minv[unused] -= delta
#define UPDATE(s) { if ((usedm >> (s)) & 1u) vpot_##s -= delta; \
                    else                     minv_##s -= delta; }
                S_LIST(UPDATE)
                __builtin_amdgcn_wave_barrier();
                if (nr == 0) break;     // bj is a free column
                j0 = bj; i0 = nr;
            }
            // augment along the alternating path (uniform across the wave)
            int jcur = bj;
            while (jcur != 0) {
                const int q = jcur - 1;
                const int li = q / NS, si = q % NS;
                int wsel = 0;
#define WSEL(s) if (si == (s)) wsel = way_##s;
                S_LIST(WSEL)
                const int jp = __builtin_amdgcn_readlane(wsel, li); // li uniform
                const int pv = pcol[jp];
                if (lane == 0) pcol[jcur] = pv;
                __builtin_amdgcn_wave_barrier();
                jcur = jp;
            }
        }
    }
    __syncthreads();

    // ---- Phase 3: losses over matched pairs (all 256 threads) ----
    // (summation structure unchanged from the verified kernel)
    for (int j = 1 + tid; j <= NQ; j += THREADS) {
        int r = pcol[j];
        if (r > 0) row2col[r - 1] = j - 1;
    }
    __syncthreads();
    float cs = 0.f, bs = 0.f;
    for (int k = tid; k < n; k += THREADS) {
        int q = row2col[k];
        int lb = lab[k];
        cs += -logf(probT[lb][q]);
        float4 p4 = pbx4[q]; float2 p2 = pbx2[q];
        float4 g4 = gb4[k];  float2 g2 = gb2[k];
        bs += fabsf(p4.x - g4.x) + fabsf(p4.y - g4.y) + fabsf(p4.z - g4.z)
            + fabsf(p4.w - g4.w) + fabsf(p2.x - g2.x) + fabsf(p2.y - g2.y);
    }
    for (int off = 32; off > 0; off >>= 1) {
        cs += __shfl_down(cs, off);
        bs += __shfl_down(bs, off);
    }
    {
        int wave = tid >> 6;
        if ((tid & 63) == 0) { redc[wave] = cs; redb[wave] = bs; }
    }
    __syncthreads();
    if (tid == 0) {
        cls_part[b] = redc[0] + redc[1] + redc[2] + redc[3];
        box_part[b] = redb[0] + redb[1] + redb[2] + redb[3];
        cnt_part[b] = n;
    }
}

__global__ void finalize_kernel(const float* __restrict__ cls_part,
                                const float* __restrict__ box_part,
                                const int* __restrict__ cnt_part,
                                float* __restrict__ out) {
    if (threadIdx.x == 0 && blockIdx.x == 0) {
        float c = 0.f, bx = 0.f;
        int nn = 0;
        for (int b = 0; b < NB; ++b) {
            c += cls_part[b]; bx += box_part[b]; nn += cnt_part[b];
        }
        float denom = (nn > 0) ? (float)nn : 1.0f;
        float cl = c / denom;
        float bl = bx / (6.0f * denom);
        out[0] = cl;
        out[1] = bl;
        out[2] = cl + 5.0f * bl;
    }
}

extern "C" void kernel_launch(void* const* d_in, const int* in_sizes, int n_in,
                              void* d_out, int out_size, void* d_ws, size_t ws_size,
                              hipStream_t stream) {
    const float* pred_boxes   = (const float*)d_in[0];
    const float* pred_classes = (const float*)d_in[1];
    const float* gt_boxes     = (const float*)d_in[2];
    const unsigned int*  labels_w = (const unsigned int*)d_in[3];
    const unsigned int*  mask_w   = (const unsigned int*)d_in[4];
    const unsigned char* mask_b   = (const unsigned char*)d_in[4];

    char* ws = (char*)d_ws;
    float* cls_part = (float*)(ws + 16);
    float* box_part = (float*)(ws + 16 + 4 * NB);
    int*   cnt_part = (int*)(ws + 16 + 8 * NB);
    float* out = (float*)d_out;

    match_kernel<<<NB, THREADS, 0, stream>>>(pred_boxes, pred_classes, gt_boxes,
                                             labels_w, mask_w, mask_b,
                                             cls_part, box_part, cnt_part);
    finalize_kernel<<<1, 64, 0, stream>>>(cls_part, box_part, cnt_part, out);
}

// Round 6
// 40.458 us; speedup vs baseline: 4.2481x; 1.0420x over previous
//
#include <hip/hip_runtime.h>
#include <cfloat>
#include <cmath>

#define NB 64
#define NQ 900
#define NM 64
#define NC 4
#define THREADS 256
#define NCT 225   // col-threads: thread t (t<225) owns cols [4t, 4t+4)

// Apply X to the 4 per-thread column slots
#define S4_LIST(X) X(0) X(1) X(2) X(3)

__device__ __forceinline__ unsigned int uminu(unsigned int a, unsigned int b) {
    return a < b ? a : b;
}

// Wave-64 min reduction on the VALU pipe: 4x DPP row_shr + readlane of the
// 4 row minima + scalar mins. Result is wave-uniform.
__device__ __forceinline__ unsigned int wave_redmin_u32(unsigned int x) {
    int t;
    t = __builtin_amdgcn_update_dpp(-1, (int)x, 0x111, 0xF, 0xF, false); // shr:1
    x = uminu(x, (unsigned)t);
    t = __builtin_amdgcn_update_dpp(-1, (int)x, 0x112, 0xF, 0xF, false); // shr:2
    x = uminu(x, (unsigned)t);
    t = __builtin_amdgcn_update_dpp(-1, (int)x, 0x114, 0xF, 0xF, false); // shr:4
    x = uminu(x, (unsigned)t);
    t = __builtin_amdgcn_update_dpp(-1, (int)x, 0x118, 0xF, 0xF, false); // shr:8
    x = uminu(x, (unsigned)t);
    unsigned a = (unsigned)__builtin_amdgcn_readlane((int)x, 15);
    unsigned b = (unsigned)__builtin_amdgcn_readlane((int)x, 31);
    unsigned c = (unsigned)__builtin_amdgcn_readlane((int)x, 47);
    unsigned d = (unsigned)__builtin_amdgcn_readlane((int)x, 63);
    return uminu(uminu(a, b), uminu(c, d));
}

// Per-wave argmin with np.argmin (lowest index on ties) semantics.
// Thread-major col ownership: lane order == col order within the wave.
__device__ __forceinline__ void wave_argmin_f(float lmin, int lj,
                                              float& mv, int& mj) {
    unsigned u = __float_as_uint(lmin);
    unsigned key = (u & 0x80000000u) ? ~u : (u | 0x80000000u);
    unsigned mk = wave_redmin_u32(key);
    unsigned long long bal = __ballot(key == mk);
    int fl = (int)__builtin_ctzll(bal);
    mj = __builtin_amdgcn_readlane(lj, fl);
    unsigned mu = (mk & 0x80000000u) ? (mk & 0x7FFFFFFFu) : ~mk;
    mv = __uint_as_float(mu);
}

__global__ __launch_bounds__(THREADS, 1) void match_kernel(
    const float* __restrict__ pred_boxes,    // [NB,NQ,6]
    const float* __restrict__ pred_classes,  // [NB,NQ,NC]
    const float* __restrict__ gt_boxes,      // [NB,NM,6]
    const unsigned int* __restrict__ labels_w,
    const unsigned int* __restrict__ mask_w,
    const unsigned char* __restrict__ mask_b,
    float* __restrict__ cls_part, float* __restrict__ box_part,
    int* __restrict__ cnt_part)
{
    __shared__ float4 pbx4[NQ];          // pred box dims 0..3
    __shared__ float2 pbx2[NQ];          // pred box dims 4..5
    __shared__ float  probT[NC][NQ];     // transposed softmax probs
    __shared__ int    pcol[NQ + 1];      // col -> matched row (1-based), 0=free
    __shared__ int    claim[NQ];         // greedy contention: min row claiming col
    __shared__ int    way_lds[NQ + 1];   // Dijkstra predecessor col
    __shared__ float  upot[NM + 1];      // row potentials (1-based)
    __shared__ float4 gb4[NM];
    __shared__ float2 gb2[NM];
    __shared__ int    lab[NM];
    __shared__ int    vpos_s[NM];
    __shared__ int    row2col[NM];
    __shared__ float  rowmin_s[NM];
    __shared__ int    rowarg_s[NM];
    __shared__ float  rpart_v[4][NM];    // per-wave row-reduction partials
    __shared__ int    rpart_j[4][NM];
    __shared__ int    ua_s[NM];          // unassigned rows after greedy
    __shared__ int    nua_s;
    __shared__ int    m_sh;
    __shared__ int    f_lab_odd, f_m_not01, f_m_odd;
    __shared__ __align__(16) float redv[4];
    __shared__ __align__(16) int   redj[4];
    __shared__ float  redc[4], redb[4];

    const int b = blockIdx.x;
    const int tid = threadIdx.x;
    const int lane = tid & 63;
    const int wv = tid >> 6;

    if (tid == 0) { f_lab_odd = 0; f_m_not01 = 0; f_m_odd = 0; }
    __syncthreads();

    // ---- Phase 1a: dtype detection (first 4KB of each buffer) + staging ----
    for (int w = tid; w < 1024; w += THREADS) {
        unsigned int lw = labels_w[w];
        if ((w & 1) && lw != 0u) f_lab_odd = 1;   // benign race: all write 1
        unsigned int mw = mask_w[w];
        if (mw > 1u) f_m_not01 = 1;
        if ((w & 1) && mw != 0u) f_m_odd = 1;
    }
    for (int q = tid; q < NQ; q += THREADS) {
        const float4 lg = *reinterpret_cast<const float4*>(
            pred_classes + ((size_t)b * NQ + q) * NC);
        float mx = fmaxf(fmaxf(lg.x, lg.y), fmaxf(lg.z, lg.w));
        float e0 = expf(lg.x - mx), e1 = expf(lg.y - mx);
        float e2 = expf(lg.z - mx), e3 = expf(lg.w - mx);
        float inv = 1.0f / (e0 + e1 + e2 + e3);
        probT[0][q] = e0 * inv; probT[1][q] = e1 * inv;
        probT[2][q] = e2 * inv; probT[3][q] = e3 * inv;
        const float* bp = pred_boxes + ((size_t)b * NQ + q) * 6;
        float2 b0 = *reinterpret_cast<const float2*>(bp);
        float2 b1 = *reinterpret_cast<const float2*>(bp + 2);
        float2 b2 = *reinterpret_cast<const float2*>(bp + 4);
        pbx4[q] = make_float4(b0.x, b0.y, b1.x, b1.y);
        pbx2[q] = make_float2(b2.x, b2.y);
    }
    for (int j = tid; j <= NQ; j += THREADS) { pcol[j] = 0; way_lds[j] = 0; }
    for (int j = tid; j < NQ; j += THREADS) claim[j] = 0x7FFFFFFF;
    __syncthreads();

    const int lmode = f_lab_odd ? 0 : 1;                 // 0=int32, 1=int64
    const int mmode = f_m_not01 ? 2 : (f_m_odd ? 0 : 1); // 2=bytes,0=i32,1=i64

    // ---- Phase 1b: mask compaction + gt staging (wave 0 only) ----
    if (tid < 64) {
        int vv;
        if (mmode == 2)      vv = (mask_b[b * NM + lane] != 0);
        else if (mmode == 1) vv = (mask_w[(b * NM + lane) * 2] != 0u);
        else                 vv = (mask_w[b * NM + lane] != 0u);
        unsigned long long bal = __ballot(vv);
        if (vv) {
            int pos = (int)__popcll(bal & ((1ull << lane) - 1ull));
            vpos_s[pos] = lane;
        }
        if (lane == 0) m_sh = (int)__popcll(bal);
        __builtin_amdgcn_wave_barrier();
        int nw = (int)__popcll(bal);
        if (lane < nw) {
            int g = vpos_s[lane];
            lab[lane] = (int)(lmode ? labels_w[(size_t)(b * NM + g) * 2]
                                    : labels_w[b * NM + g]);
            const float* gp = gt_boxes + ((size_t)b * NM + g) * 6;
            gb4[lane] = make_float4(gp[0], gp[1], gp[2], gp[3]);
            gb2[lane] = make_float2(gp[4], gp[5]);
        }
    }
    __syncthreads();
    const int n = m_sh;

    // ---- Phase 1c: hoist this thread's 4 columns into named registers ----
    // 40 floats/thread: fits the VGPR budget, unlike 15-cols/lane (R3-R5
    // kept spilling to LDS re-reads). Scans below read NO LDS column data.
    const bool lv = (tid < NCT);
    const int qb = lv ? (tid << 2) : 0;
#define DECL_COL(s) float cb0_##s, cb1_##s, cb2_##s, cb3_##s, cb4_##s, cb5_##s;
    S4_LIST(DECL_COL)
    float cq0_0, cq0_1, cq0_2, cq0_3;
    float cq1_0, cq1_1, cq1_2, cq1_3;
    float cq2_0, cq2_1, cq2_2, cq2_3;
    float cq3_0, cq3_1, cq3_2, cq3_3;
#define HOIST(s) { const float4 h4 = pbx4[qb + (s)]; \
        const float2 h2 = pbx2[qb + (s)]; \
        cb0_##s = h4.x; cb1_##s = h4.y; cb2_##s = h4.z; cb3_##s = h4.w; \
        cb4_##s = h2.x; cb5_##s = h2.y; }
    S4_LIST(HOIST)
    {
        const float4 p0 = *reinterpret_cast<const float4*>(&probT[0][qb]);
        const float4 p1 = *reinterpret_cast<const float4*>(&probT[1][qb]);
        const float4 p2 = *reinterpret_cast<const float4*>(&probT[2][qb]);
        const float4 p3 = *reinterpret_cast<const float4*>(&probT[3][qb]);
        cq0_0 = p0.x; cq0_1 = p0.y; cq0_2 = p0.z; cq0_3 = p0.w;
        cq1_0 = p1.x; cq1_1 = p1.y; cq1_2 = p1.z; cq1_3 = p1.w;
        cq2_0 = p2.x; cq2_1 = p2.y; cq2_2 = p2.z; cq2_3 = p2.w;
        cq3_0 = p3.x; cq3_1 = p3.y; cq3_2 = p3.z; cq3_3 = p3.w;
    }

    // ---- Phase 2a: row reduction — u[i] = min_j cost(i,j), argmin ----
    // Each wave computes the partial argmin of ITS 256-col slice for all
    // rows (no barriers inside), then one sync + per-row 4-way combine.
    for (int k = 0; k < n; ++k) {
        const float4 g4 = gb4[k];
        const float2 g2 = gb2[k];
        const int lb = lab[k];
        float lmin = FLT_MAX; int lj = NQ + 2;
#define RSCAN(s) { \
        float l1 = fabsf(cb0_##s - g4.x) + fabsf(cb1_##s - g4.y) \
                 + fabsf(cb2_##s - g4.z) + fabsf(cb3_##s - g4.w) \
                 + fabsf(cb4_##s - g2.x) + fabsf(cb5_##s - g2.y); \
        float pr = (lb == 0) ? cq0_##s : ((lb == 1) ? cq1_##s \
                 : ((lb == 2) ? cq2_##s : cq3_##s)); \
        float c = 5.0f * l1 - pr; \
        if (lv && c < lmin) { lmin = c; lj = qb + (s); } }
        S4_LIST(RSCAN)
        float mv; int mj;
        wave_argmin_f(lmin, lj, mv, mj);
        if (lane == 0) { rpart_v[wv][k] = mv; rpart_j[wv][k] = mj; }
    }
    __syncthreads();
    if (tid < n) {
        float bv = rpart_v[0][tid]; int bj = rpart_j[0][tid];
        #pragma unroll
        for (int w = 1; w < 4; ++w) {
            float vw = rpart_v[w][tid]; int jw = rpart_j[w][tid];
            if (vw < bv || (vw == bv && jw < bj)) { bv = vw; bj = jw; }
        }
        rowmin_s[tid] = bv; rowarg_s[tid] = bj;
    }
    __syncthreads();

    // ---- Phase 2b: greedy claim (dual-feasible partial assignment) ----
    if (tid < n) atomicMin(&claim[rowarg_s[tid]], tid);
    for (int k = tid; k < n; k += THREADS) upot[k + 1] = rowmin_s[k];
    if (tid == 0) upot[0] = 0.f;
    __syncthreads();
    if (tid < n) {
        int a = rowarg_s[tid];
        if (claim[a] == tid) pcol[a + 1] = tid + 1;   // unique winner
    }
    if (tid < 64) {
        int un = (lane < n) && (claim[rowarg_s[lane]] != lane);
        unsigned long long bal = __ballot(un);
        if (un) ua_s[(int)__popcll(bal & ((1ull << lane) - 1ull))] = lane;
        if (lane == 0) nua_s = (int)__popcll(bal);
    }
    __syncthreads();

    // ---- Phase 2c: shortest augmenting path, block-cooperative ----
    {
        float minv_0, minv_1, minv_2, minv_3;
        float vpot_0 = 0.f, vpot_1 = 0.f, vpot_2 = 0.f, vpot_3 = 0.f;
        const int nua = nua_s;

        for (int t = 0; t < nua; ++t) {
            const int i = ua_s[t] + 1;
            minv_0 = FLT_MAX; minv_1 = FLT_MAX;
            minv_2 = FLT_MAX; minv_3 = FLT_MAX;
            unsigned int usedm = 0;
            int intree = 0;
            if (tid == 0) pcol[0] = i;
            int j0 = 0, i0 = i, bj = 0;
            __syncthreads();   // pcol[0] + prior augment visible
            while (true) {
                // mark used[j0] (owner thread), add row i0 to the tree
                if (j0 > 0 && ((j0 - 1) >> 2) == tid)
                    usedm |= 1u << ((j0 - 1) & 3);
                if (tid == i0 - 1) intree = 1;
                // row i0's data: uniform LDS broadcast reads
                const float base = upot[i0];
                const float4 g4 = gb4[i0 - 1];
                const float2 g2 = gb2[i0 - 1];
                const int lb = lab[i0 - 1];
                float lmin = FLT_MAX; int lj = NQ + 2;
#define SSCAN(s) { \
                float l1 = fabsf(cb0_##s - g4.x) + fabsf(cb1_##s - g4.y) \
                         + fabsf(cb2_##s - g4.z) + fabsf(cb3_##s - g4.w) \
                         + fabsf(cb4_##s - g2.x) + fabsf(cb5_##s - g2.y); \
                float pr = (lb == 0) ? cq0_##s : ((lb == 1) ? cq1_##s \
                         : ((lb == 2) ? cq2_##s : cq3_##s)); \
                float cost = 5.0f * l1 - pr; \
                float cur = cost - base - vpot_##s; \
                if (lv && !((usedm >> (s)) & 1u)) { \
                    if (cur < minv_##s) { minv_##s = cur; \
                                          way_lds[qb + (s) + 1] = j0; } \
                    if (minv_##s < lmin) { lmin = minv_##s; \
                                           lj = qb + (s) + 1; } } }
                S4_LIST(SSCAN)
                float pv; int pj;
                wave_argmin_f(lmin, lj, pv, pj);
                if (lane == 0) { redv[wv] = pv; redj[wv] = pj; }
                __syncthreads();   // B1: partials + way_lds visible
                // redundant 4-way combine on every thread (no broadcast RT)
                const float4 rv4 = *reinterpret_cast<const float4*>(redv);
                const int4   rj4 = *reinterpret_cast<const int4*>(redj);
                float dv = rv4.x; int dj = rj4.x;
                if (rv4.y < dv || (rv4.y == dv && rj4.y < dj)) { dv = rv4.y; dj = rj4.y; }
                if (rv4.z < dv || (rv4.z == dv && rj4.z < dj)) { dv = rv4.z; dj = rj4.z; }
                if (rv4.w < dv || (rv4.w == dv && rj4.w < dj)) { dv = rv4.w; dj = rj4.w; }
                const float delta = dv;
                bj = dj;
                const int nr = pcol[bj];
                // v[used] -= delta ; minv[unused] -= delta (local registers)
#define UPDATE(s) { if ((usedm >> (s)) & 1u) vpot_##s -= delta; \
                    else                     minv_##s -= delta; }
                S4_LIST(UPDATE)
                // u[rows in tree] += delta (owner-exclusive LDS update)
                if (intree) upot[tid + 1] += delta;
                __syncthreads();   // B2: upot visible for next scan
                if (nr == 0) break;     // bj is a free column
                j0 = bj; i0 = nr;
            }
            // augment along the alternating path (thread 0, LDS chase)
            if (tid == 0) {
                int jcur = bj;
                while (jcur != 0) {
                    int jp = way_lds[jcur];
                    pcol[jcur] = pcol[jp];
                    jcur = jp;
                }
            }
        }
    }
    __syncthreads();

    // ---- Phase 3: losses over matched pairs (all 256 threads) ----
    // (summation structure unchanged from the verified kernel)
    for (int j = 1 + tid; j <= NQ; j += THREADS) {
        int r = pcol[j];
        if (r > 0) row2col[r - 1] = j - 1;
    }
    __syncthreads();
    float cs = 0.f, bs = 0.f;
    for (int k = tid; k < n; k += THREADS) {
        int q = row2col[k];
        int lb = lab[k];
        cs += -logf(probT[lb][q]);
        float4 p4 = pbx4[q]; float2 p2 = pbx2[q];
        float4 g4 = gb4[k];  float2 g2 = gb2[k];
        bs += fabsf(p4.x - g4.x) + fabsf(p4.y - g4.y) + fabsf(p4.z - g4.z)
            + fabsf(p4.w - g4.w) + fabsf(p2.x - g2.x) + fabsf(p2.y - g2.y);
    }
    for (int off = 32; off > 0; off >>= 1) {
        cs += __shfl_down(cs, off);
        bs += __shfl_down(bs, off);
    }
    {
        int wave = tid >> 6;
        if ((tid & 63) == 0) { redc[wave] = cs; redb[wave] = bs; }
    }
    __syncthreads();
    if (tid == 0) {
        cls_part[b] = redc[0] + redc[1] + redc[2] + redc[3];
        box_part[b] = redb[0] + redb[1] + redb[2] + redb[3];
        cnt_part[b] = n;
    }
}

__global__ void finalize_kernel(const float* __restrict__ cls_part,
                                const float* __restrict__ box_part,
                                const int* __restrict__ cnt_part,
                                float* __restrict__ out) {
    if (threadIdx.x == 0 && blockIdx.x == 0) {
        float c = 0.f, bx = 0.f;
        int nn = 0;
        for (int b = 0; b < NB; ++b) {
            c += cls_part[b]; bx += box_part[b]; nn += cnt_part[b];
        }
        float denom = (nn > 0) ? (float)nn : 1.0f;
        float cl = c / denom;
        float bl = bx / (6.0f * denom);
        out[0] = cl;
        out[1] = bl;
        out[2] = cl + 5.0f * bl;
    }
}

extern "C" void kernel_launch(void* const* d_in, const int* in_sizes, int n_in,
                              void* d_out, int out_size, void* d_ws, size_t ws_size,
                              hipStream_t stream) {
    const float* pred_boxes   = (const float*)d_in[0];
    const float* pred_classes = (const float*)d_in[1];
    const float* gt_boxes     = (const float*)d_in[2];
    const unsigned int*  labels_w = (const unsigned int*)d_in[3];
    const unsigned int*  mask_w   = (const unsigned int*)d_in[4];
    const unsigned char* mask_b   = (const unsigned char*)d_in[4];

    char* ws = (char*)d_ws;
    float* cls_part = (float*)(ws + 16);
    float* box_part = (float*)(ws + 16 + 4 * NB);
    int*   cnt_part = (int*)(ws + 16 + 8 * NB);
    float* out = (float*)d_out;

    match_kernel<<<NB, THREADS, 0, stream>>>(pred_boxes, pred_classes, gt_boxes,
                                             labels_w, mask_w, mask_b,
                                             cls_part, box_part, cnt_part);
    finalize_kernel<<<1, 64, 0, stream>>>(cls_part, box_part, cnt_part, out);
}

// Round 7
// 39.733 us; speedup vs baseline: 4.3256x; 1.0182x over previous
//
#include <hip/hip_runtime.h>
#include <cfloat>
#include <cmath>

#define NB 64
#define NQ 900
#define NM 64
#define NC 4
#define THREADS 256
#define NCT 225   // col-threads: thread t (t<225) owns cols [4t, 4t+4)

// Apply X to the 4 per-thread column slots
#define S4_LIST(X) X(0) X(1) X(2) X(3)

__device__ __forceinline__ unsigned int uminu(unsigned int a, unsigned int b) {
    return a < b ? a : b;
}

// Wave-64 min reduction on the VALU pipe: 4x DPP row_shr + readlane of the
// 4 row minima + scalar mins. Result is wave-uniform.
__device__ __forceinline__ unsigned int wave_redmin_u32(unsigned int x) {
    int t;
    t = __builtin_amdgcn_update_dpp(-1, (int)x, 0x111, 0xF, 0xF, false); // shr:1
    x = uminu(x, (unsigned)t);
    t = __builtin_amdgcn_update_dpp(-1, (int)x, 0x112, 0xF, 0xF, false); // shr:2
    x = uminu(x, (unsigned)t);
    t = __builtin_amdgcn_update_dpp(-1, (int)x, 0x114, 0xF, 0xF, false); // shr:4
    x = uminu(x, (unsigned)t);
    t = __builtin_amdgcn_update_dpp(-1, (int)x, 0x118, 0xF, 0xF, false); // shr:8
    x = uminu(x, (unsigned)t);
    unsigned a = (unsigned)__builtin_amdgcn_readlane((int)x, 15);
    unsigned b = (unsigned)__builtin_amdgcn_readlane((int)x, 31);
    unsigned c = (unsigned)__builtin_amdgcn_readlane((int)x, 47);
    unsigned d = (unsigned)__builtin_amdgcn_readlane((int)x, 63);
    return uminu(uminu(a, b), uminu(c, d));
}

// Per-wave argmin with np.argmin (lowest index on ties) semantics.
// Thread-major col ownership: lane order == col order within the wave.
__device__ __forceinline__ void wave_argmin_f(float lmin, int lj,
                                              float& mv, int& mj) {
    unsigned u = __float_as_uint(lmin);
    unsigned key = (u & 0x80000000u) ? ~u : (u | 0x80000000u);
    unsigned mk = wave_redmin_u32(key);
    unsigned long long bal = __ballot(key == mk);
    int fl = (int)__builtin_ctzll(bal);
    mj = __builtin_amdgcn_readlane(lj, fl);
    unsigned mu = (mk & 0x80000000u) ? (mk & 0x7FFFFFFFu) : ~mk;
    mv = __uint_as_float(mu);
}

__global__ __launch_bounds__(THREADS, 1) void match_kernel(
    const float* __restrict__ pred_boxes,    // [NB,NQ,6]
    const float* __restrict__ pred_classes,  // [NB,NQ,NC]
    const float* __restrict__ gt_boxes,      // [NB,NM,6]
    const unsigned int* __restrict__ labels_w,
    const unsigned int* __restrict__ mask_w,
    const unsigned char* __restrict__ mask_b,
    float* __restrict__ cls_part, float* __restrict__ box_part,
    int* __restrict__ cnt_part)
{
    __shared__ float4 pbx4[NQ];          // pred box dims 0..3 (phase-3 use)
    __shared__ float2 pbx2[NQ];          // pred box dims 4..5
    __shared__ float  probT[NC][NQ];     // transposed softmax probs
    __shared__ int    pcol[NQ + 1];      // col -> matched row (1-based), 0=free
    __shared__ int    claim[NQ];         // greedy contention: min row claiming col
    __shared__ int    way_lds[NQ + 1];   // Dijkstra predecessor col
    __shared__ float  upot[NM + 1];      // row potentials (1-based)
    __shared__ float4 gb4[NM];
    __shared__ float2 gb2[NM];
    __shared__ int    lab[NM];
    __shared__ int    vpos_s[NM];
    __shared__ int    row2col[NM];
    __shared__ float  rowmin_s[NM];
    __shared__ int    rowarg_s[NM];
    __shared__ float  rpart_v[4][NM];    // per-wave row-reduction partials
    __shared__ int    rpart_j[4][NM];
    __shared__ int    ua_s[NM];          // unassigned rows after greedy
    __shared__ int    nua_s;
    __shared__ int    m_sh;
    __shared__ int    f_lab_odd, f_m_not01, f_m_odd;
    __shared__ __align__(16) float redv[2][4];   // double-buffered partials
    __shared__ __align__(16) int   redj[2][4];
    __shared__ float  redc[4], redb[4];

    const int b = blockIdx.x;
    const int tid = threadIdx.x;
    const int lane = tid & 63;
    const int wv = tid >> 6;

    if (tid == 0) { f_lab_odd = 0; f_m_not01 = 0; f_m_odd = 0; }
    __syncthreads();

    // ---- Phase 1a: dtype detection (first 4KB of each buffer) + LDS init ----
    for (int w = tid; w < 1024; w += THREADS) {
        unsigned int lw = labels_w[w];
        if ((w & 1) && lw != 0u) f_lab_odd = 1;   // benign race: all write 1
        unsigned int mw = mask_w[w];
        if (mw > 1u) f_m_not01 = 1;
        if ((w & 1) && mw != 0u) f_m_odd = 1;
    }
    for (int j = tid; j <= NQ; j += THREADS) { pcol[j] = 0; way_lds[j] = 0; }
    for (int j = tid; j < NQ; j += THREADS) claim[j] = 0x7FFFFFFF;
    __syncthreads();

    const int lmode = f_lab_odd ? 0 : 1;                 // 0=int32, 1=int64
    const int mmode = f_m_not01 ? 2 : (f_m_odd ? 0 : 1); // 2=bytes,0=i32,1=i64

    // ---- Phase 1c: stage OWN 4 columns straight into registers + LDS copy ----
    // Thread t owns cols [4t, 4t+4). Coalesced: 64B (classes) + 96B (boxes)
    // per thread, contiguous across threads. Registers filled directly (no
    // LDS round-trip); LDS copies kept only for phase 3.
    const bool lv = (tid < NCT);
    const int qb = tid << 2;
#define DECL_COL(s) float cb0_##s = 0.f, cb1_##s = 0.f, cb2_##s = 0.f, \
                          cb3_##s = 0.f, cb4_##s = 0.f, cb5_##s = 0.f, \
                          cq0_##s = 0.f, cq1_##s = 0.f, cq2_##s = 0.f, \
                          cq3_##s = 0.f;
    S4_LIST(DECL_COL)
    if (lv) {
        const float* cp = pred_classes + ((size_t)b * NQ + qb) * NC;
        const float4 lg0 = *reinterpret_cast<const float4*>(cp + 0);
        const float4 lg1 = *reinterpret_cast<const float4*>(cp + 4);
        const float4 lg2 = *reinterpret_cast<const float4*>(cp + 8);
        const float4 lg3 = *reinterpret_cast<const float4*>(cp + 12);
#define SOFTM(s, LG) { \
        float mx = fmaxf(fmaxf(LG.x, LG.y), fmaxf(LG.z, LG.w)); \
        float e0 = expf(LG.x - mx), e1 = expf(LG.y - mx); \
        float e2 = expf(LG.z - mx), e3 = expf(LG.w - mx); \
        float inv = 1.0f / (e0 + e1 + e2 + e3); \
        cq0_##s = e0 * inv; cq1_##s = e1 * inv; \
        cq2_##s = e2 * inv; cq3_##s = e3 * inv; \
        probT[0][qb + (s)] = cq0_##s; probT[1][qb + (s)] = cq1_##s; \
        probT[2][qb + (s)] = cq2_##s; probT[3][qb + (s)] = cq3_##s; }
        SOFTM(0, lg0) SOFTM(1, lg1) SOFTM(2, lg2) SOFTM(3, lg3)
        const float* bp = pred_boxes + ((size_t)b * NQ + qb) * 6;
        const float4 b0 = *reinterpret_cast<const float4*>(bp + 0);
        const float4 b1 = *reinterpret_cast<const float4*>(bp + 4);
        const float4 b2 = *reinterpret_cast<const float4*>(bp + 8);
        const float4 b3 = *reinterpret_cast<const float4*>(bp + 12);
        const float4 b4 = *reinterpret_cast<const float4*>(bp + 16);
        const float4 b5 = *reinterpret_cast<const float4*>(bp + 20);
        cb0_0 = b0.x; cb1_0 = b0.y; cb2_0 = b0.z; cb3_0 = b0.w;
        cb4_0 = b1.x; cb5_0 = b1.y;
        cb0_1 = b1.z; cb1_1 = b1.w; cb2_1 = b2.x; cb3_1 = b2.y;
        cb4_1 = b2.z; cb5_1 = b2.w;
        cb0_2 = b3.x; cb1_2 = b3.y; cb2_2 = b3.z; cb3_2 = b3.w;
        cb4_2 = b4.x; cb5_2 = b4.y;
        cb0_3 = b4.z; cb1_3 = b4.w; cb2_3 = b5.x; cb3_3 = b5.y;
        cb4_3 = b5.z; cb5_3 = b5.w;
#define STORE_PBX(s) { pbx4[qb + (s)] = make_float4(cb0_##s, cb1_##s, \
                           cb2_##s, cb3_##s); \
                       pbx2[qb + (s)] = make_float2(cb4_##s, cb5_##s); }
        S4_LIST(STORE_PBX)
    }

    // ---- Phase 1b: mask compaction + gt staging (wave 0 only) ----
    if (tid < 64) {
        int vv;
        if (mmode == 2)      vv = (mask_b[b * NM + lane] != 0);
        else if (mmode == 1) vv = (mask_w[(b * NM + lane) * 2] != 0u);
        else                 vv = (mask_w[b * NM + lane] != 0u);
        unsigned long long bal = __ballot(vv);
        if (vv) {
            int pos = (int)__popcll(bal & ((1ull << lane) - 1ull));
            vpos_s[pos] = lane;
        }
        if (lane == 0) m_sh = (int)__popcll(bal);
        __builtin_amdgcn_wave_barrier();
        int nw = (int)__popcll(bal);
        if (lane < nw) {
            int g = vpos_s[lane];
            lab[lane] = (int)(lmode ? labels_w[(size_t)(b * NM + g) * 2]
                                    : labels_w[b * NM + g]);
            const float* gp = gt_boxes + ((size_t)b * NM + g) * 6;
            gb4[lane] = make_float4(gp[0], gp[1], gp[2], gp[3]);
            gb2[lane] = make_float2(gp[4], gp[5]);
        }
    }
    __syncthreads();
    const int n = m_sh;

    // ---- Phase 2a: row reduction, unrolled by 2 to overlap DPP chains ----
#define RSCANX(s, G4, G2, LB, LMIN, LJ) { \
        float l1 = fabsf(cb0_##s - G4.x) + fabsf(cb1_##s - G4.y) \
                 + fabsf(cb2_##s - G4.z) + fabsf(cb3_##s - G4.w) \
                 + fabsf(cb4_##s - G2.x) + fabsf(cb5_##s - G2.y); \
        float pr = ((LB) == 0) ? cq0_##s : (((LB) == 1) ? cq1_##s \
                 : (((LB) == 2) ? cq2_##s : cq3_##s)); \
        float c = 5.0f * l1 - pr; \
        if (lv && c < (LMIN)) { (LMIN) = c; (LJ) = qb + (s); } }
    {
        int k = 0;
        for (; k + 1 < n; k += 2) {
            const float4 g4a = gb4[k];     const float2 g2a = gb2[k];
            const int lba = lab[k];
            const float4 g4b = gb4[k + 1]; const float2 g2b = gb2[k + 1];
            const int lbb = lab[k + 1];
            float lmina = FLT_MAX; int lja = NQ + 2;
            float lminb = FLT_MAX; int ljb = NQ + 2;
#define RSA(s) RSCANX(s, g4a, g2a, lba, lmina, lja)
#define RSB(s) RSCANX(s, g4b, g2b, lbb, lminb, ljb)
            S4_LIST(RSA) S4_LIST(RSB)
            float mva, mvb; int mja, mjb;
            wave_argmin_f(lmina, lja, mva, mja);
            wave_argmin_f(lminb, ljb, mvb, mjb);
            if (lane == 0) {
                rpart_v[wv][k] = mva;     rpart_j[wv][k] = mja;
                rpart_v[wv][k + 1] = mvb; rpart_j[wv][k + 1] = mjb;
            }
        }
        if (k < n) {
            const float4 g4a = gb4[k]; const float2 g2a = gb2[k];
            const int lba = lab[k];
            float lmina = FLT_MAX; int lja = NQ + 2;
            S4_LIST(RSA)
            float mva; int mja;
            wave_argmin_f(lmina, lja, mva, mja);
            if (lane == 0) { rpart_v[wv][k] = mva; rpart_j[wv][k] = mja; }
        }
    }
    __syncthreads();
    if (tid < n) {
        float bv = rpart_v[0][tid]; int bj = rpart_j[0][tid];
        #pragma unroll
        for (int w = 1; w < 4; ++w) {
            float vw = rpart_v[w][tid]; int jw = rpart_j[w][tid];
            if (vw < bv || (vw == bv && jw < bj)) { bv = vw; bj = jw; }
        }
        rowmin_s[tid] = bv; rowarg_s[tid] = bj;
    }
    __syncthreads();

    // ---- Phase 2b: greedy claim (dual-feasible partial assignment) ----
    if (tid < n) atomicMin(&claim[rowarg_s[tid]], tid);
    for (int k = tid; k < n; k += THREADS) upot[k + 1] = rowmin_s[k];
    if (tid == 0) upot[0] = 0.f;
    __syncthreads();
    if (tid < n) {
        int a = rowarg_s[tid];
        if (claim[a] == tid) pcol[a + 1] = tid + 1;   // unique winner
    }
    if (tid < 64) {
        int un = (lane < n) && (claim[rowarg_s[lane]] != lane);
        unsigned long long bal = __ballot(un);
        if (un) ua_s[(int)__popcll(bal & ((1ull << lane) - 1ull))] = lane;
        if (lane == 0) nua_s = (int)__popcll(bal);
    }
    __syncthreads();

    // ---- Phase 2c: shortest augmenting path, 1 barrier per iteration ----
    // redv/redj double-buffered by parity; next row's data prefetched right
    // after the combine (row nr is provably not yet in the tree, so no
    // upot[nr] write races); augment protected by a per-stage exit barrier.
    {
        float minv_0, minv_1, minv_2, minv_3;
        float vpot_0 = 0.f, vpot_1 = 0.f, vpot_2 = 0.f, vpot_3 = 0.f;
        const int nua = nua_s;

        for (int t = 0; t < nua; ++t) {
            const int i = ua_s[t] + 1;
            minv_0 = FLT_MAX; minv_1 = FLT_MAX;
            minv_2 = FLT_MAX; minv_3 = FLT_MAX;
            unsigned int usedm = 0;
            int intree = 0;
            if (tid == 0) pcol[0] = i;
            __syncthreads();   // stage start: prior augment/upot stable
            // prefetch start row's data
            float base = upot[i];
            float4 g4 = gb4[i - 1];
            float2 g2 = gb2[i - 1];
            int lb = lab[i - 1];
            int j0 = 0, i0 = i, bj = 0, par = 0;
            while (true) {
                // mark used[j0] (owner thread), add row i0 to the tree
                if (j0 > 0 && ((j0 - 1) >> 2) == tid)
                    usedm |= 1u << ((j0 - 1) & 3);
                if (tid == i0 - 1) intree = 1;
                float lmin = FLT_MAX; int lj = NQ + 2;
#define SSCAN(s) { \
                float l1 = fabsf(cb0_##s - g4.x) + fabsf(cb1_##s - g4.y) \
                         + fabsf(cb2_##s - g4.z) + fabsf(cb3_##s - g4.w) \
                         + fabsf(cb4_##s - g2.x) + fabsf(cb5_##s - g2.y); \
                float pr = (lb == 0) ? cq0_##s : ((lb == 1) ? cq1_##s \
                         : ((lb == 2) ? cq2_##s : cq3_##s)); \
                float cost = 5.0f * l1 - pr; \
                float cur = cost - base - vpot_##s; \
                if (lv && !((usedm >> (s)) & 1u)) { \
                    if (cur < minv_##s) { minv_##s = cur; \
                                          way_lds[qb + (s) + 1] = j0; } \
                    if (minv_##s < lmin) { lmin = minv_##s; \
                                           lj = qb + (s) + 1; } } }
                S4_LIST(SSCAN)
                float pv; int pj;
                wave_argmin_f(lmin, lj, pv, pj);
                if (lane == 0) { redv[par][wv] = pv; redj[par][wv] = pj; }
                __syncthreads();   // B1: partials + way_lds visible
                // redundant 4-way combine on every thread
                const float4 rv4 = *reinterpret_cast<const float4*>(redv[par]);
                const int4   rj4 = *reinterpret_cast<const int4*>(redj[par]);
                float dv = rv4.x; int dj = rj4.x;
                if (rv4.y < dv || (rv4.y == dv && rj4.y < dj)) { dv = rv4.y; dj = rj4.y; }
                if (rv4.z < dv || (rv4.z == dv && rj4.z < dj)) { dv = rv4.z; dj = rj4.z; }
                if (rv4.w < dv || (rv4.w == dv && rj4.w < dj)) { dv = rv4.w; dj = rj4.w; }
                const float delta = dv;
                bj = dj;
                const int nr = pcol[bj];
                // v[used] -= delta ; minv[unused] -= delta (local registers)
#define UPDATE(s) { if ((usedm >> (s)) & 1u) vpot_##s -= delta; \
                    else                     minv_##s -= delta; }
                S4_LIST(UPDATE)
                // u[rows in tree] += delta (owner-exclusive LDS update)
                if (intree) upot[tid + 1] += delta;
                if (nr == 0) break;     // bj is a free column
                // prefetch next row's data (nr not in tree: no write races)
                base = upot[nr];
                g4 = gb4[nr - 1];
                g2 = gb2[nr - 1];
                lb = lab[nr - 1];
                j0 = bj; i0 = nr; par ^= 1;
            }
            __syncthreads();   // stage exit: pcol/upot reads done everywhere
            // augment along the alternating path (thread 0, LDS chase)
            if (tid == 0) {
                int jcur = bj;
                while (jcur != 0) {
                    int jp = way_lds[jcur];
                    pcol[jcur] = pcol[jp];
                    jcur = jp;
                }
            }
        }
    }
    __syncthreads();

    // ---- Phase 3: losses over matched pairs (all 256 threads) ----
    // (summation structure unchanged from the verified kernel)
    for (int j = 1 + tid; j <= NQ; j += THREADS) {
        int r = pcol[j];
        if (r > 0) row2col[r - 1] = j - 1;
    }
    __syncthreads();
    float cs = 0.f, bs = 0.f;
    for (int k = tid; k < n; k += THREADS) {
        int q = row2col[k];
        int lb = lab[k];
        cs += -logf(probT[lb][q]);
        float4 p4 = pbx4[q]; float2 p2 = pbx2[q];
        float4 g4 = gb4[k];  float2 g2 = gb2[k];
        bs += fabsf(p4.x - g4.x) + fabsf(p4.y - g4.y) + fabsf(p4.z - g4.z)
            + fabsf(p4.w - g4.w) + fabsf(p2.x - g2.x) + fabsf(p2.y - g2.y);
    }
    for (int off = 32; off > 0; off >>= 1) {
        cs += __shfl_down(cs, off);
        bs += __shfl_down(bs, off);
    }
    {
        int wave = tid >> 6;
        if ((tid & 63) == 0) { redc[wave] = cs; redb[wave] = bs; }
    }
    __syncthreads();
    if (tid == 0) {
        cls_part[b] = redc[0] + redc[1] + redc[2] + redc[3];
        box_part[b] = redb[0] + redb[1] + redb[2] + redb[3];
        cnt_part[b] = n;
    }
}

__global__ void finalize_kernel(const float* __restrict__ cls_part,
                                const float* __restrict__ box_part,
                                const int* __restrict__ cnt_part,
                                float* __restrict__ out) {
    if (threadIdx.x == 0 && blockIdx.x == 0) {
        float c = 0.f, bx = 0.f;
        int nn = 0;
        for (int b = 0; b < NB; ++b) {
            c += cls_part[b]; bx += box_part[b]; nn += cnt_part[b];
        }
        float denom = (nn > 0) ? (float)nn : 1.0f;
        float cl = c / denom;
        float bl = bx / (6.0f * denom);
        out[0] = cl;
        out[1] = bl;
        out[2] = cl + 5.0f * bl;
    }
}

extern "C" void kernel_launch(void* const* d_in, const int* in_sizes, int n_in,
                              void* d_out, int out_size, void* d_ws, size_t ws_size,
                              hipStream_t stream) {
    const float* pred_boxes   = (const float*)d_in[0];
    const float* pred_classes = (const float*)d_in[1];
    const float* gt_boxes     = (const float*)d_in[2];
    const unsigned int*  labels_w = (const unsigned int*)d_in[3];
    const unsigned int*  mask_w   = (const unsigned int*)d_in[4];
    const unsigned char* mask_b   = (const unsigned char*)d_in[4];

    char* ws = (char*)d_ws;
    float* cls_part = (float*)(ws + 16);
    float* box_part = (float*)(ws + 16 + 4 * NB);
    int*   cnt_part = (int*)(ws + 16 + 8 * NB);
    float* out = (float*)d_out;

    match_kernel<<<NB, THREADS, 0, stream>>>(pred_boxes, pred_classes, gt_boxes,
                                             labels_w, mask_w, mask_b,
                                             cls_part, box_part, cnt_part);
    finalize_kernel<<<1, 64, 0, stream>>>(cls_part, box_part, cnt_part, out);
}

// Round 8
// 39.227 us; speedup vs baseline: 4.3815x; 1.0129x over previous
//
#include <hip/hip_runtime.h>
#include <cfloat>
#include <cmath>

#define NB 64
#define NQ 900
#define NM 64
#define NC 4
#define THREADS 256
#define NCT 225   // col-threads: thread t (t<225) owns cols [4t, 4t+4)

// Apply X to the 4 per-thread column slots
#define S4_LIST(X) X(0) X(1) X(2) X(3)

__device__ __forceinline__ unsigned int uminu(unsigned int a, unsigned int b) {
    return a < b ? a : b;
}

// Wave-64 min reduction on the VALU pipe: 4x DPP row_shr + readlane of the
// 4 row minima + scalar mins. Result is wave-uniform.
__device__ __forceinline__ unsigned int wave_redmin_u32(unsigned int x) {
    int t;
    t = __builtin_amdgcn_update_dpp(-1, (int)x, 0x111, 0xF, 0xF, false); // shr:1
    x = uminu(x, (unsigned)t);
    t = __builtin_amdgcn_update_dpp(-1, (int)x, 0x112, 0xF, 0xF, false); // shr:2
    x = uminu(x, (unsigned)t);
    t = __builtin_amdgcn_update_dpp(-1, (int)x, 0x114, 0xF, 0xF, false); // shr:4
    x = uminu(x, (unsigned)t);
    t = __builtin_amdgcn_update_dpp(-1, (int)x, 0x118, 0xF, 0xF, false); // shr:8
    x = uminu(x, (unsigned)t);
    unsigned a = (unsigned)__builtin_amdgcn_readlane((int)x, 15);
    unsigned b = (unsigned)__builtin_amdgcn_readlane((int)x, 31);
    unsigned c = (unsigned)__builtin_amdgcn_readlane((int)x, 47);
    unsigned d = (unsigned)__builtin_amdgcn_readlane((int)x, 63);
    return uminu(uminu(a, b), uminu(c, d));
}

// Per-wave argmin with np.argmin (lowest index on ties) semantics.
__device__ __forceinline__ void wave_argmin_f(float lmin, int lj,
                                              float& mv, int& mj) {
    unsigned u = __float_as_uint(lmin);
    unsigned key = (u & 0x80000000u) ? ~u : (u | 0x80000000u);
    unsigned mk = wave_redmin_u32(key);
    unsigned long long bal = __ballot(key == mk);
    int fl = (int)__builtin_ctzll(bal);
    mj = __builtin_amdgcn_readlane(lj, fl);
    unsigned mu = (mk & 0x80000000u) ? (mk & 0x7FFFFFFFu) : ~mk;
    mv = __uint_as_float(mu);
}

// Same, with a second payload (the winning column's cached pcol value).
__device__ __forceinline__ void wave_argmin_f2(float lmin, int lj, int lpc,
                                               float& mv, int& mj, int& mpc) {
    unsigned u = __float_as_uint(lmin);
    unsigned key = (u & 0x80000000u) ? ~u : (u | 0x80000000u);
    unsigned mk = wave_redmin_u32(key);
    unsigned long long bal = __ballot(key == mk);
    int fl = (int)__builtin_ctzll(bal);
    mj = __builtin_amdgcn_readlane(lj, fl);
    mpc = __builtin_amdgcn_readlane(lpc, fl);
    unsigned mu = (mk & 0x80000000u) ? (mk & 0x7FFFFFFFu) : ~mk;
    mv = __uint_as_float(mu);
}

__global__ __launch_bounds__(THREADS, 1) void match_kernel(
    const float* __restrict__ pred_boxes,    // [NB,NQ,6]
    const float* __restrict__ pred_classes,  // [NB,NQ,NC]
    const float* __restrict__ gt_boxes,      // [NB,NM,6]
    const unsigned int* __restrict__ labels_w,
    const unsigned int* __restrict__ mask_w,
    const unsigned char* __restrict__ mask_b,
    float* __restrict__ cls_part, float* __restrict__ box_part,
    int* __restrict__ cnt_part)
{
    __shared__ float4 pbx4[NQ];          // pred box dims 0..3 (phase-3 use)
    __shared__ float2 pbx2[NQ];          // pred box dims 4..5
    __shared__ float  probT[NC][NQ];     // transposed softmax probs
    __shared__ int    pcol[NQ + 1];      // col -> matched row (1-based), 0=free
    __shared__ int    claim[NQ];         // greedy contention: min row claiming col
    __shared__ int    way_lds[NQ + 1];   // Dijkstra predecessor col
    __shared__ float  upot[NM + 1];      // row potentials (1-based)
    __shared__ float4 gb4[NM];
    __shared__ float2 gb2[NM];
    __shared__ int    lab[NM];
    __shared__ int    vpos_s[NM];
    __shared__ int    row2col[NM];
    __shared__ float  rowmin_s[NM];
    __shared__ int    rowarg_s[NM];
    __shared__ float  rpart_v[4][NM];    // per-wave row-reduction partials
    __shared__ int    rpart_j[4][NM];
    __shared__ int    ua_s[NM];          // unassigned rows after greedy
    __shared__ int    nua_s;
    __shared__ int    m_sh;
    __shared__ int    f_lab_odd, f_m_not01, f_m_odd;
    __shared__ __align__(16) float redv[2][4];   // double-buffered partials
    __shared__ __align__(16) int   redj[2][4];
    __shared__ __align__(16) int   redp[2][4];   // pcol payload
    __shared__ float  redc[4], redb[4];

    const int b = blockIdx.x;
    const int tid = threadIdx.x;
    const int lane = tid & 63;
    const int wv = tid >> 6;

    if (tid == 0) { f_lab_odd = 0; f_m_not01 = 0; f_m_odd = 0; }
    __syncthreads();

    // ---- Phase 1a: dtype detection (first 4KB of each buffer, one uint4
    //      per thread per buffer) + LDS init ----
    {
        const uint4 lw4 = reinterpret_cast<const uint4*>(labels_w)[tid];
        if ((lw4.y | lw4.w) != 0u) f_lab_odd = 1;      // odd words nonzero
        const uint4 mw4 = reinterpret_cast<const uint4*>(mask_w)[tid];
        if (mw4.x > 1u || mw4.y > 1u || mw4.z > 1u || mw4.w > 1u)
            f_m_not01 = 1;
        if ((mw4.y | mw4.w) != 0u) f_m_odd = 1;
    }
    for (int j = tid; j <= NQ; j += THREADS) { pcol[j] = 0; way_lds[j] = 0; }
    for (int j = tid; j < NQ; j += THREADS) claim[j] = 0x7FFFFFFF;
    __syncthreads();

    const int lmode = f_lab_odd ? 0 : 1;                 // 0=int32, 1=int64
    const int mmode = f_m_not01 ? 2 : (f_m_odd ? 0 : 1); // 2=bytes,0=i32,1=i64

    // ---- Phase 1c: stage OWN 4 columns straight into registers + LDS copy ----
    const bool lv = (tid < NCT);
    const int qb = tid << 2;
#define DECL_COL(s) float cb0_##s = 0.f, cb1_##s = 0.f, cb2_##s = 0.f, \
                          cb3_##s = 0.f, cb4_##s = 0.f, cb5_##s = 0.f, \
                          cq0_##s = 0.f, cq1_##s = 0.f, cq2_##s = 0.f, \
                          cq3_##s = 0.f;
    S4_LIST(DECL_COL)
    if (lv) {
        const float* cp = pred_classes + ((size_t)b * NQ + qb) * NC;
        const float4 lg0 = *reinterpret_cast<const float4*>(cp + 0);
        const float4 lg1 = *reinterpret_cast<const float4*>(cp + 4);
        const float4 lg2 = *reinterpret_cast<const float4*>(cp + 8);
        const float4 lg3 = *reinterpret_cast<const float4*>(cp + 12);
#define SOFTM(s, LG) { \
        float mx = fmaxf(fmaxf(LG.x, LG.y), fmaxf(LG.z, LG.w)); \
        float e0 = expf(LG.x - mx), e1 = expf(LG.y - mx); \
        float e2 = expf(LG.z - mx), e3 = expf(LG.w - mx); \
        float inv = 1.0f / (e0 + e1 + e2 + e3); \
        cq0_##s = e0 * inv; cq1_##s = e1 * inv; \
        cq2_##s = e2 * inv; cq3_##s = e3 * inv; \
        probT[0][qb + (s)] = cq0_##s; probT[1][qb + (s)] = cq1_##s; \
        probT[2][qb + (s)] = cq2_##s; probT[3][qb + (s)] = cq3_##s; }
        SOFTM(0, lg0) SOFTM(1, lg1) SOFTM(2, lg2) SOFTM(3, lg3)
        const float* bp = pred_boxes + ((size_t)b * NQ + qb) * 6;
        const float4 b0 = *reinterpret_cast<const float4*>(bp + 0);
        const float4 b1 = *reinterpret_cast<const float4*>(bp + 4);
        const float4 b2 = *reinterpret_cast<const float4*>(bp + 8);
        const float4 b3 = *reinterpret_cast<const float4*>(bp + 12);
        const float4 b4 = *reinterpret_cast<const float4*>(bp + 16);
        const float4 b5 = *reinterpret_cast<const float4*>(bp + 20);
        cb0_0 = b0.x; cb1_0 = b0.y; cb2_0 = b0.z; cb3_0 = b0.w;
        cb4_0 = b1.x; cb5_0 = b1.y;
        cb0_1 = b1.z; cb1_1 = b1.w; cb2_1 = b2.x; cb3_1 = b2.y;
        cb4_1 = b2.z; cb5_1 = b2.w;
        cb0_2 = b3.x; cb1_2 = b3.y; cb2_2 = b3.z; cb3_2 = b3.w;
        cb4_2 = b4.x; cb5_2 = b4.y;
        cb0_3 = b4.z; cb1_3 = b4.w; cb2_3 = b5.x; cb3_3 = b5.y;
        cb4_3 = b5.z; cb5_3 = b5.w;
#define STORE_PBX(s) { pbx4[qb + (s)] = make_float4(cb0_##s, cb1_##s, \
                           cb2_##s, cb3_##s); \
                       pbx2[qb + (s)] = make_float2(cb4_##s, cb5_##s); }
        S4_LIST(STORE_PBX)
    }

    // ---- Phase 1b: mask compaction + gt staging (wave 0 only) ----
    if (tid < 64) {
        int vv;
        if (mmode == 2)      vv = (mask_b[b * NM + lane] != 0);
        else if (mmode == 1) vv = (mask_w[(b * NM + lane) * 2] != 0u);
        else                 vv = (mask_w[b * NM + lane] != 0u);
        unsigned long long bal = __ballot(vv);
        if (vv) {
            int pos = (int)__popcll(bal & ((1ull << lane) - 1ull));
            vpos_s[pos] = lane;
        }
        if (lane == 0) m_sh = (int)__popcll(bal);
        __builtin_amdgcn_wave_barrier();
        int nw = (int)__popcll(bal);
        if (lane < nw) {
            int g = vpos_s[lane];
            lab[lane] = (int)(lmode ? labels_w[(size_t)(b * NM + g) * 2]
                                    : labels_w[b * NM + g]);
            const float* gp = gt_boxes + ((size_t)b * NM + g) * 6;
            gb4[lane] = make_float4(gp[0], gp[1], gp[2], gp[3]);
            gb2[lane] = make_float2(gp[4], gp[5]);
        }
    }
    __syncthreads();
    const int n = m_sh;

    // ---- Phase 2a: row reduction, unrolled by 2 to overlap DPP chains ----
#define RSCANX(s, G4, G2, LB, LMIN, LJ) { \
        float l1 = fabsf(cb0_##s - G4.x) + fabsf(cb1_##s - G4.y) \
                 + fabsf(cb2_##s - G4.z) + fabsf(cb3_##s - G4.w) \
                 + fabsf(cb4_##s - G2.x) + fabsf(cb5_##s - G2.y); \
        float pr = ((LB) == 0) ? cq0_##s : (((LB) == 1) ? cq1_##s \
                 : (((LB) == 2) ? cq2_##s : cq3_##s)); \
        float c = 5.0f * l1 - pr; \
        if (lv && c < (LMIN)) { (LMIN) = c; (LJ) = qb + (s); } }
    {
        int k = 0;
        for (; k + 1 < n; k += 2) {
            const float4 g4a = gb4[k];     const float2 g2a = gb2[k];
            const int lba = lab[k];
            const float4 g4b = gb4[k + 1]; const float2 g2b = gb2[k + 1];
            const int lbb = lab[k + 1];
            float lmina = FLT_MAX; int lja = NQ + 2;
            float lminb = FLT_MAX; int ljb = NQ + 2;
#define RSA(s) RSCANX(s, g4a, g2a, lba, lmina, lja)
#define RSB(s) RSCANX(s, g4b, g2b, lbb, lminb, ljb)
            S4_LIST(RSA) S4_LIST(RSB)
            float mva, mvb; int mja, mjb;
            wave_argmin_f(lmina, lja, mva, mja);
            wave_argmin_f(lminb, ljb, mvb, mjb);
            if (lane == 0) {
                rpart_v[wv][k] = mva;     rpart_j[wv][k] = mja;
                rpart_v[wv][k + 1] = mvb; rpart_j[wv][k + 1] = mjb;
            }
        }
        if (k < n) {
            const float4 g4a = gb4[k]; const float2 g2a = gb2[k];
            const int lba = lab[k];
            float lmina = FLT_MAX; int lja = NQ + 2;
            S4_LIST(RSA)
            float mva; int mja;
            wave_argmin_f(lmina, lja, mva, mja);
            if (lane == 0) { rpart_v[wv][k] = mva; rpart_j[wv][k] = mja; }
        }
    }
    __syncthreads();
    if (tid < n) {
        float bv = rpart_v[0][tid]; int bj = rpart_j[0][tid];
        #pragma unroll
        for (int w = 1; w < 4; ++w) {
            float vw = rpart_v[w][tid]; int jw = rpart_j[w][tid];
            if (vw < bv || (vw == bv && jw < bj)) { bv = vw; bj = jw; }
        }
        rowmin_s[tid] = bv; rowarg_s[tid] = bj;
    }
    __syncthreads();

    // ---- Phase 2b: greedy claim (dual-feasible partial assignment) ----
    if (tid < n) atomicMin(&claim[rowarg_s[tid]], tid);
    for (int k = tid; k < n; k += THREADS) upot[k + 1] = rowmin_s[k];
    if (tid == 0) upot[0] = 0.f;
    __syncthreads();
    if (tid < n) {
        int a = rowarg_s[tid];
        if (claim[a] == tid) pcol[a + 1] = tid + 1;   // unique winner
    }
    if (tid < 64) {
        int un = (lane < n) && (claim[rowarg_s[lane]] != lane);
        unsigned long long bal = __ballot(un);
        if (un) ua_s[(int)__popcll(bal & ((1ull << lane) - 1ull))] = lane;
        if (lane == 0) nua_s = (int)__popcll(bal);
    }
    __syncthreads();

    // ---- Phase 2c: shortest augmenting path, 1 barrier per iteration.
    // pcol is stage-constant: cached in registers per slot at stage start
    // and carried through the argmin payload, so the dependent pcol[bj]
    // LDS read is off the iteration critical path entirely.
    {
        float minv_0, minv_1, minv_2, minv_3;
        float vpot_0 = 0.f, vpot_1 = 0.f, vpot_2 = 0.f, vpot_3 = 0.f;
        const int nua = nua_s;

        for (int t = 0; t < nua; ++t) {
            const int i = ua_s[t] + 1;
            minv_0 = FLT_MAX; minv_1 = FLT_MAX;
            minv_2 = FLT_MAX; minv_3 = FLT_MAX;
            unsigned int usedm = 0;
            int intree = 0;
            if (tid == 0) pcol[0] = i;   // col 0 is virtual: never a payload
            __syncthreads();   // stage start: prior augment/upot stable
            // cache this stage's pcol for own slots (stage-constant)
            int pc_0 = 0, pc_1 = 0, pc_2 = 0, pc_3 = 0;
            if (lv) {
                pc_0 = pcol[qb + 1]; pc_1 = pcol[qb + 2];
                pc_2 = pcol[qb + 3]; pc_3 = pcol[qb + 4];
            }
            // prefetch start row's data
            float base = upot[i];
            float4 g4 = gb4[i - 1];
            float2 g2 = gb2[i - 1];
            int lb = lab[i - 1];
            int j0 = 0, i0 = i, bj = 0, par = 0;
            while (true) {
                // mark used[j0] (owner thread), add row i0 to the tree
                if (j0 > 0 && ((j0 - 1) >> 2) == tid)
                    usedm |= 1u << ((j0 - 1) & 3);
                if (tid == i0 - 1) intree = 1;
                float lmin = FLT_MAX; int lj = NQ + 2; int lpc = 0;
#define SSCAN(s) { \
                float l1 = fabsf(cb0_##s - g4.x) + fabsf(cb1_##s - g4.y) \
                         + fabsf(cb2_##s - g4.z) + fabsf(cb3_##s - g4.w) \
                         + fabsf(cb4_##s - g2.x) + fabsf(cb5_##s - g2.y); \
                float pr = (lb == 0) ? cq0_##s : ((lb == 1) ? cq1_##s \
                         : ((lb == 2) ? cq2_##s : cq3_##s)); \
                float cost = 5.0f * l1 - pr; \
                float cur = cost - base - vpot_##s; \
                if (lv && !((usedm >> (s)) & 1u)) { \
                    if (cur < minv_##s) { minv_##s = cur; \
                                          way_lds[qb + (s) + 1] = j0; } \
                    if (minv_##s < lmin) { lmin = minv_##s; \
                                           lj = qb + (s) + 1; \
                                           lpc = pc_##s; } } }
                S4_LIST(SSCAN)
                float pv; int pj, pp;
                wave_argmin_f2(lmin, lj, lpc, pv, pj, pp);
                if (lane == 0) {
                    redv[par][wv] = pv; redj[par][wv] = pj; redp[par][wv] = pp;
                }
                __syncthreads();   // B1: partials + way_lds visible
                // redundant 4-way combine on every thread
                const float4 rv4 = *reinterpret_cast<const float4*>(redv[par]);
                const int4   rj4 = *reinterpret_cast<const int4*>(redj[par]);
                const int4   rp4 = *reinterpret_cast<const int4*>(redp[par]);
                float dv = rv4.x; int dj = rj4.x; int dp = rp4.x;
                if (rv4.y < dv || (rv4.y == dv && rj4.y < dj)) {
                    dv = rv4.y; dj = rj4.y; dp = rp4.y; }
                if (rv4.z < dv || (rv4.z == dv && rj4.z < dj)) {
                    dv = rv4.z; dj = rj4.z; dp = rp4.z; }
                if (rv4.w < dv || (rv4.w == dv && rj4.w < dj)) {
                    dv = rv4.w; dj = rj4.w; dp = rp4.w; }
                const float delta = dv;
                bj = dj;
                const int nr = dp;      // pcol[bj] via payload (no LDS read)
                // prefetch next row's data early (nr not in tree: no races)
                if (nr != 0) {
                    base = upot[nr];
                    g4 = gb4[nr - 1];
                    g2 = gb2[nr - 1];
                    lb = lab[nr - 1];
                }
                // v[used] -= delta ; minv[unused] -= delta (local registers)
#define UPDATE(s) { if ((usedm >> (s)) & 1u) vpot_##s -= delta; \
                    else                     minv_##s -= delta; }
                S4_LIST(UPDATE)
                // u[rows in tree] += delta (owner-exclusive LDS update)
                if (intree) upot[tid + 1] += delta;
                if (nr == 0) break;     // bj is a free column
                j0 = bj; i0 = nr; par ^= 1;
            }
            __syncthreads();   // stage exit: upot writes done everywhere
            // augment along the alternating path (thread 0, LDS chase)
            if (tid == 0) {
                int jcur = bj;
                while (jcur != 0) {
                    int jp = way_lds[jcur];
                    pcol[jcur] = pcol[jp];
                    jcur = jp;
                }
            }
        }
    }
    __syncthreads();

    // ---- Phase 3: losses over matched pairs (all 256 threads) ----
    // (summation structure unchanged from the verified kernel)
    for (int j = 1 + tid; j <= NQ; j += THREADS) {
        int r = pcol[j];
        if (r > 0) row2col[r - 1] = j - 1;
    }
    __syncthreads();
    float cs = 0.f, bs = 0.f;
    for (int k = tid; k < n; k += THREADS) {
        int q = row2col[k];
        int lb = lab[k];
        cs += -logf(probT[lb][q]);
        float4 p4 = pbx4[q]; float2 p2 = pbx2[q];
        float4 g4 = gb4[k];  float2 g2 = gb2[k];
        bs += fabsf(p4.x - g4.x) + fabsf(p4.y - g4.y) + fabsf(p4.z - g4.z)
            + fabsf(p4.w - g4.w) + fabsf(p2.x - g2.x) + fabsf(p2.y - g2.y);
    }
    for (int off = 32; off > 0; off >>= 1) {
        cs += __shfl_down(cs, off);
        bs += __shfl_down(bs, off);
    }
    {
        int wave = tid >> 6;
        if ((tid & 63) == 0) { redc[wave] = cs; redb[wave] = bs; }
    }
    __syncthreads();
    if (tid == 0) {
        cls_part[b] = redc[0] + redc[1] + redc[2] + redc[3];
        box_part[b] = redb[0] + redb[1] + redb[2] + redb[3];
        cnt_part[b] = n;
    }
}

__global__ void finalize_kernel(const float* __restrict__ cls_part,
                                const float* __restrict__ box_part,
                                const int* __restrict__ cnt_part,
                                float* __restrict__ out) {
    if (threadIdx.x == 0 && blockIdx.x == 0) {
        float c = 0.f, bx = 0.f;
        int nn = 0;
        for (int b = 0; b < NB; ++b) {
            c += cls_part[b]; bx += box_part[b]; nn += cnt_part[b];
        }
        float denom = (nn > 0) ? (float)nn : 1.0f;
        float cl = c / denom;
        float bl = bx / (6.0f * denom);
        out[0] = cl;
        out[1] = bl;
        out[2] = cl + 5.0f * bl;
    }
}

extern "C" void kernel_launch(void* const* d_in, const int* in_sizes, int n_in,
                              void* d_out, int out_size, void* d_ws, size_t ws_size,
                              hipStream_t stream) {
    const float* pred_boxes   = (const float*)d_in[0];
    const float* pred_classes = (const float*)d_in[1];
    const float* gt_boxes     = (const float*)d_in[2];
    const unsigned int*  labels_w = (const unsigned int*)d_in[3];
    const unsigned int*  mask_w   = (const unsigned int*)d_in[4];
    const unsigned char* mask_b   = (const unsigned char*)d_in[4];

    char* ws = (char*)d_ws;
    float* cls_part = (float*)(ws + 16);
    float* box_part = (float*)(ws + 16 + 4 * NB);
    int*   cnt_part = (int*)(ws + 16 + 8 * NB);
    float* out = (float*)d_out;

    match_kernel<<<NB, THREADS, 0, stream>>>(pred_boxes, pred_classes, gt_boxes,
                                             labels_w, mask_w, mask_b,
                                             cls_part, box_part, cnt_part);
    finalize_kernel<<<1, 64, 0, stream>>>(cls_part, box_part, cnt_part, out);
}

// Round 9
// 35.214 us; speedup vs baseline: 4.8808x; 1.1140x over previous
//
#include <hip/hip_runtime.h>
#include <cfloat>
#include <cmath>

#define NB 64
#define NQ 900
#define NM 64
#define NC 4
#define THREADS 256
#define NCT 225   // col-threads: thread t (t<225) owns cols [4t, 4t+4)
#define MAGIC 0x5A17C0DEu

// Apply X to the 4 per-thread column slots
#define S4_LIST(X) X(0) X(1) X(2) X(3)

__device__ __forceinline__ unsigned int uminu(unsigned int a, unsigned int b) {
    return a < b ? a : b;
}

__device__ __forceinline__ float readlane_f(float v, int l) {
    return __uint_as_float(
        (unsigned)__builtin_amdgcn_readlane(__float_as_int(v), l));
}

// Wave-64 min reduction on the VALU pipe: 4x DPP row_shr + readlane of the
// 4 row minima + scalar mins. Result is wave-uniform.
__device__ __forceinline__ unsigned int wave_redmin_u32(unsigned int x) {
    int t;
    t = __builtin_amdgcn_update_dpp(-1, (int)x, 0x111, 0xF, 0xF, false); // shr:1
    x = uminu(x, (unsigned)t);
    t = __builtin_amdgcn_update_dpp(-1, (int)x, 0x112, 0xF, 0xF, false); // shr:2
    x = uminu(x, (unsigned)t);
    t = __builtin_amdgcn_update_dpp(-1, (int)x, 0x114, 0xF, 0xF, false); // shr:4
    x = uminu(x, (unsigned)t);
    t = __builtin_amdgcn_update_dpp(-1, (int)x, 0x118, 0xF, 0xF, false); // shr:8
    x = uminu(x, (unsigned)t);
    unsigned a = (unsigned)__builtin_amdgcn_readlane((int)x, 15);
    unsigned b = (unsigned)__builtin_amdgcn_readlane((int)x, 31);
    unsigned c = (unsigned)__builtin_amdgcn_readlane((int)x, 47);
    unsigned d = (unsigned)__builtin_amdgcn_readlane((int)x, 63);
    return uminu(uminu(a, b), uminu(c, d));
}

// Per-wave argmin with np.argmin (lowest index on ties) semantics.
__device__ __forceinline__ void wave_argmin_f(float lmin, int lj,
                                              float& mv, int& mj) {
    unsigned u = __float_as_uint(lmin);
    unsigned key = (u & 0x80000000u) ? ~u : (u | 0x80000000u);
    unsigned mk = wave_redmin_u32(key);
    unsigned long long bal = __ballot(key == mk);
    int fl = (int)__builtin_ctzll(bal);
    mj = __builtin_amdgcn_readlane(lj, fl);
    unsigned mu = (mk & 0x80000000u) ? (mk & 0x7FFFFFFFu) : ~mk;
    mv = __uint_as_float(mu);
}

// Same, with a second payload (the winning column's cached pcol value).
__device__ __forceinline__ void wave_argmin_f2(float lmin, int lj, int lpc,
                                               float& mv, int& mj, int& mpc) {
    unsigned u = __float_as_uint(lmin);
    unsigned key = (u & 0x80000000u) ? ~u : (u | 0x80000000u);
    unsigned mk = wave_redmin_u32(key);
    unsigned long long bal = __ballot(key == mk);
    int fl = (int)__builtin_ctzll(bal);
    mj = __builtin_amdgcn_readlane(lj, fl);
    mpc = __builtin_amdgcn_readlane(lpc, fl);
    unsigned mu = (mk & 0x80000000u) ? (mk & 0x7FFFFFFFu) : ~mk;
    mv = __uint_as_float(mu);
}

__global__ __launch_bounds__(THREADS, 1) void match_kernel(
    const float* __restrict__ pred_boxes,    // [NB,NQ,6]
    const float* __restrict__ pred_classes,  // [NB,NQ,NC]
    const float* __restrict__ gt_boxes,      // [NB,NM,6]
    const unsigned int* __restrict__ labels_w,
    const unsigned int* __restrict__ mask_w,
    const unsigned char* __restrict__ mask_b,
    unsigned int* __restrict__ res,          // ws: 64 slots x 4 words
    float* __restrict__ out)
{
    __shared__ float4 pbx4[NQ];          // pred box dims 0..3 (phase-3 use)
    __shared__ float2 pbx2[NQ];          // pred box dims 4..5
    __shared__ float  probT[NC][NQ];     // transposed softmax probs
    __shared__ int    pcol[NQ + 1];      // col -> matched row (1-based), 0=free
    __shared__ int    claim[NQ];         // greedy contention: min row claiming col
    __shared__ int    way_lds[NQ + 1];   // Dijkstra predecessor col
    __shared__ float  upot[NM + 1];      // row potentials (1-based)
    __shared__ float4 gb4[NM];
    __shared__ float2 gb2[NM];
    __shared__ int    lab[NM];
    __shared__ int    vpos_s[NM];
    __shared__ int    row2col[NM];
    __shared__ float  rowmin_s[NM];
    __shared__ int    rowarg_s[NM];
    __shared__ float  rpart_v[4][NM];    // per-wave row-reduction partials
    __shared__ int    rpart_j[4][NM];
    __shared__ int    ua_s[NM];          // unassigned rows after greedy
    __shared__ int    nua_s;
    __shared__ int    m_sh;
    __shared__ int    f_lab_odd, f_m_not01, f_m_odd;
    __shared__ __align__(16) float redv[2][4];   // double-buffered partials
    __shared__ __align__(16) int   redj[2][4];
    __shared__ __align__(16) int   redp[2][4];   // pcol payload
    __shared__ float  redc[4], redb[4];

    const int b = blockIdx.x;
    const int tid = threadIdx.x;
    const int lane = tid & 63;
    const int wv = tid >> 6;

    if (tid == 0) { f_lab_odd = 0; f_m_not01 = 0; f_m_odd = 0; }
    __syncthreads();

    // ---- Phase 1a: dtype detection (first 4KB of each buffer, one uint4
    //      per thread per buffer) + LDS init ----
    {
        const uint4 lw4 = reinterpret_cast<const uint4*>(labels_w)[tid];
        if ((lw4.y | lw4.w) != 0u) f_lab_odd = 1;      // odd words nonzero
        const uint4 mw4 = reinterpret_cast<const uint4*>(mask_w)[tid];
        if (mw4.x > 1u || mw4.y > 1u || mw4.z > 1u || mw4.w > 1u)
            f_m_not01 = 1;
        if ((mw4.y | mw4.w) != 0u) f_m_odd = 1;
    }
    for (int j = tid; j <= NQ; j += THREADS) { pcol[j] = 0; way_lds[j] = 0; }
    for (int j = tid; j < NQ; j += THREADS) claim[j] = 0x7FFFFFFF;
    __syncthreads();

    const int lmode = f_lab_odd ? 0 : 1;                 // 0=int32, 1=int64
    const int mmode = f_m_not01 ? 2 : (f_m_odd ? 0 : 1); // 2=bytes,0=i32,1=i64

    // ---- Phase 1c: stage OWN 4 columns straight into registers + LDS copy ----
    const bool lv = (tid < NCT);
    const int qb = tid << 2;
#define DECL_COL(s) float cb0_##s = 0.f, cb1_##s = 0.f, cb2_##s = 0.f, \
                          cb3_##s = 0.f, cb4_##s = 0.f, cb5_##s = 0.f, \
                          cq0_##s = 0.f, cq1_##s = 0.f, cq2_##s = 0.f, \
                          cq3_##s = 0.f;
    S4_LIST(DECL_COL)
    if (lv) {
        const float* cp = pred_classes + ((size_t)b * NQ + qb) * NC;
        const float4 lg0 = *reinterpret_cast<const float4*>(cp + 0);
        const float4 lg1 = *reinterpret_cast<const float4*>(cp + 4);
        const float4 lg2 = *reinterpret_cast<const float4*>(cp + 8);
        const float4 lg3 = *reinterpret_cast<const float4*>(cp + 12);
#define SOFTM(s, LG) { \
        float mx = fmaxf(fmaxf(LG.x, LG.y), fmaxf(LG.z, LG.w)); \
        float e0 = expf(LG.x - mx), e1 = expf(LG.y - mx); \
        float e2 = expf(LG.z - mx), e3 = expf(LG.w - mx); \
        float inv = 1.0f / (e0 + e1 + e2 + e3); \
        cq0_##s = e0 * inv; cq1_##s = e1 * inv; \
        cq2_##s = e2 * inv; cq3_##s = e3 * inv; \
        probT[0][qb + (s)] = cq0_##s; probT[1][qb + (s)] = cq1_##s; \
        probT[2][qb + (s)] = cq2_##s; probT[3][qb + (s)] = cq3_##s; }
        SOFTM(0, lg0) SOFTM(1, lg1) SOFTM(2, lg2) SOFTM(3, lg3)
        const float* bp = pred_boxes + ((size_t)b * NQ + qb) * 6;
        const float4 b0 = *reinterpret_cast<const float4*>(bp + 0);
        const float4 b1 = *reinterpret_cast<const float4*>(bp + 4);
        const float4 b2 = *reinterpret_cast<const float4*>(bp + 8);
        const float4 b3 = *reinterpret_cast<const float4*>(bp + 12);
        const float4 b4 = *reinterpret_cast<const float4*>(bp + 16);
        const float4 b5 = *reinterpret_cast<const float4*>(bp + 20);
        cb0_0 = b0.x; cb1_0 = b0.y; cb2_0 = b0.z; cb3_0 = b0.w;
        cb4_0 = b1.x; cb5_0 = b1.y;
        cb0_1 = b1.z; cb1_1 = b1.w; cb2_1 = b2.x; cb3_1 = b2.y;
        cb4_1 = b2.z; cb5_1 = b2.w;
        cb0_2 = b3.x; cb1_2 = b3.y; cb2_2 = b3.z; cb3_2 = b3.w;
        cb4_2 = b4.x; cb5_2 = b4.y;
        cb0_3 = b4.z; cb1_3 = b4.w; cb2_3 = b5.x; cb3_3 = b5.y;
        cb4_3 = b5.z; cb5_3 = b5.w;
#define STORE_PBX(s) { pbx4[qb + (s)] = make_float4(cb0_##s, cb1_##s, \
                           cb2_##s, cb3_##s); \
                       pbx2[qb + (s)] = make_float2(cb4_##s, cb5_##s); }
        S4_LIST(STORE_PBX)
    }

    // ---- Phase 1b: mask compaction + gt staging (wave 0 only) ----
    if (tid < 64) {
        int vv;
        if (mmode == 2)      vv = (mask_b[b * NM + lane] != 0);
        else if (mmode == 1) vv = (mask_w[(b * NM + lane) * 2] != 0u);
        else                 vv = (mask_w[b * NM + lane] != 0u);
        unsigned long long bal = __ballot(vv);
        if (vv) {
            int pos = (int)__popcll(bal & ((1ull << lane) - 1ull));
            vpos_s[pos] = lane;
        }
        if (lane == 0) m_sh = (int)__popcll(bal);
        __builtin_amdgcn_wave_barrier();
        int nw = (int)__popcll(bal);
        if (lane < nw) {
            int g = vpos_s[lane];
            lab[lane] = (int)(lmode ? labels_w[(size_t)(b * NM + g) * 2]
                                    : labels_w[b * NM + g]);
            const float* gp = gt_boxes + ((size_t)b * NM + g) * 6;
            gb4[lane] = make_float4(gp[0], gp[1], gp[2], gp[3]);
            gb2[lane] = make_float2(gp[4], gp[5]);
        }
    }
    __syncthreads();
    const int n = m_sh;

    // ---- Phase 2a: row reduction, unrolled by 4 to overlap DPP chains ----
#define RSCANX(s, G4, G2, LB, LMIN, LJ) { \
        float l1 = fabsf(cb0_##s - G4.x) + fabsf(cb1_##s - G4.y) \
                 + fabsf(cb2_##s - G4.z) + fabsf(cb3_##s - G4.w) \
                 + fabsf(cb4_##s - G2.x) + fabsf(cb5_##s - G2.y); \
        float pr = ((LB) == 0) ? cq0_##s : (((LB) == 1) ? cq1_##s \
                 : (((LB) == 2) ? cq2_##s : cq3_##s)); \
        float c = 5.0f * l1 - pr; \
        if (lv && c < (LMIN)) { (LMIN) = c; (LJ) = qb + (s); } }
#define RSA(s) RSCANX(s, g4a, g2a, lba, lmina, lja)
#define RSB(s) RSCANX(s, g4b, g2b, lbb, lminb, ljb)
#define RSC(s) RSCANX(s, g4c, g2c, lbc, lminc, ljc)
#define RSD(s) RSCANX(s, g4d, g2d, lbd, lmind, ljd)
    {
        int k = 0;
        for (; k + 3 < n; k += 4) {
            const float4 g4a = gb4[k];     const float2 g2a = gb2[k];
            const int lba = lab[k];
            const float4 g4b = gb4[k + 1]; const float2 g2b = gb2[k + 1];
            const int lbb = lab[k + 1];
            const float4 g4c = gb4[k + 2]; const float2 g2c = gb2[k + 2];
            const int lbc = lab[k + 2];
            const float4 g4d = gb4[k + 3]; const float2 g2d = gb2[k + 3];
            const int lbd = lab[k + 3];
            float lmina = FLT_MAX, lminb = FLT_MAX;
            float lminc = FLT_MAX, lmind = FLT_MAX;
            int lja = NQ + 2, ljb = NQ + 2, ljc = NQ + 2, ljd = NQ + 2;
            S4_LIST(RSA) S4_LIST(RSB) S4_LIST(RSC) S4_LIST(RSD)
            float mva, mvb, mvc, mvd; int mja, mjb, mjc, mjd;
            wave_argmin_f(lmina, lja, mva, mja);
            wave_argmin_f(lminb, ljb, mvb, mjb);
            wave_argmin_f(lminc, ljc, mvc, mjc);
            wave_argmin_f(lmind, ljd, mvd, mjd);
            if (lane == 0) {
                rpart_v[wv][k] = mva;     rpart_j[wv][k] = mja;
                rpart_v[wv][k + 1] = mvb; rpart_j[wv][k + 1] = mjb;
                rpart_v[wv][k + 2] = mvc; rpart_j[wv][k + 2] = mjc;
                rpart_v[wv][k + 3] = mvd; rpart_j[wv][k + 3] = mjd;
            }
        }
        for (; k < n; ++k) {
            const float4 g4a = gb4[k]; const float2 g2a = gb2[k];
            const int lba = lab[k];
            float lmina = FLT_MAX; int lja = NQ + 2;
            S4_LIST(RSA)
            float mva; int mja;
            wave_argmin_f(lmina, lja, mva, mja);
            if (lane == 0) { rpart_v[wv][k] = mva; rpart_j[wv][k] = mja; }
        }
    }
    __syncthreads();
    if (tid < n) {
        float bv = rpart_v[0][tid]; int bj = rpart_j[0][tid];
        #pragma unroll
        for (int w = 1; w < 4; ++w) {
            float vw = rpart_v[w][tid]; int jw = rpart_j[w][tid];
            if (vw < bv || (vw == bv && jw < bj)) { bv = vw; bj = jw; }
        }
        rowmin_s[tid] = bv; rowarg_s[tid] = bj;
    }
    __syncthreads();

    // ---- Phase 2b: greedy claim (dual-feasible partial assignment) ----
    if (tid < n) atomicMin(&claim[rowarg_s[tid]], tid);
    for (int k = tid; k < n; k += THREADS) upot[k + 1] = rowmin_s[k];
    if (tid == 0) upot[0] = 0.f;
    __syncthreads();
    if (tid < n) {
        int a = rowarg_s[tid];
        if (claim[a] == tid) pcol[a + 1] = tid + 1;   // unique winner
    }
    if (tid < 64) {
        int un = (lane < n) && (claim[rowarg_s[lane]] != lane);
        unsigned long long bal = __ballot(un);
        if (un) ua_s[(int)__popcll(bal & ((1ull << lane) - 1ull))] = lane;
        if (lane == 0) nua_s = (int)__popcll(bal);
    }
    __syncthreads();

    // ---- Phase 2c: shortest augmenting path, 1 barrier per iteration.
    // pcol is stage-constant: cached in registers per slot at stage start
    // and carried through the argmin payload.
    {
        float minv_0, minv_1, minv_2, minv_3;
        float vpot_0 = 0.f, vpot_1 = 0.f, vpot_2 = 0.f, vpot_3 = 0.f;
        const int nua = nua_s;

        for (int t = 0; t < nua; ++t) {
            const int i = ua_s[t] + 1;
            minv_0 = FLT_MAX; minv_1 = FLT_MAX;
            minv_2 = FLT_MAX; minv_3 = FLT_MAX;
            unsigned int usedm = 0;
            int intree = 0;
            if (tid == 0) pcol[0] = i;   // col 0 is virtual: never a payload
            __syncthreads();   // stage start: prior augment/upot stable
            // cache this stage's pcol for own slots (stage-constant)
            int pc_0 = 0, pc_1 = 0, pc_2 = 0, pc_3 = 0;
            if (lv) {
                pc_0 = pcol[qb + 1]; pc_1 = pcol[qb + 2];
                pc_2 = pcol[qb + 3]; pc_3 = pcol[qb + 4];
            }
            // prefetch start row's data
            float base = upot[i];
            float4 g4 = gb4[i - 1];
            float2 g2 = gb2[i - 1];
            int lb = lab[i - 1];
            int j0 = 0, i0 = i, bj = 0, par = 0;
            while (true) {
                // mark used[j0] (owner thread), add row i0 to the tree
                if (j0 > 0 && ((j0 - 1) >> 2) == tid)
                    usedm |= 1u << ((j0 - 1) & 3);
                if (tid == i0 - 1) intree = 1;
                float lmin = FLT_MAX; int lj = NQ + 2; int lpc = 0;
#define SSCAN(s) { \
                float l1 = fabsf(cb0_##s - g4.x) + fabsf(cb1_##s - g4.y) \
                         + fabsf(cb2_##s - g4.z) + fabsf(cb3_##s - g4.w) \
                         + fabsf(cb4_##s - g2.x) + fabsf(cb5_##s - g2.y); \
                float pr = (lb == 0) ? cq0_##s : ((lb == 1) ? cq1_##s \
                         : ((lb == 2) ? cq2_##s : cq3_##s)); \
                float cost = 5.0f * l1 - pr; \
                float cur = cost - base - vpot_##s; \
                if (lv && !((usedm >> (s)) & 1u)) { \
                    if (cur < minv_##s) { minv_##s = cur; \
                                          way_lds[qb + (s) + 1] = j0; } \
                    if (minv_##s < lmin) { lmin = minv_##s; \
                                           lj = qb + (s) + 1; \
                                           lpc = pc_##s; } } }
                S4_LIST(SSCAN)
                float pv; int pj, pp;
                wave_argmin_f2(lmin, lj, lpc, pv, pj, pp);
                if (lane == 0) {
                    redv[par][wv] = pv; redj[par][wv] = pj; redp[par][wv] = pp;
                }
                __syncthreads();   // B1: partials + way_lds visible
                // redundant 4-way combine on every thread
                const float4 rv4 = *reinterpret_cast<const float4*>(redv[par]);
                const int4   rj4 = *reinterpret_cast<const int4*>(redj[par]);
                const int4   rp4 = *reinterpret_cast<const int4*>(redp[par]);
                float dv = rv4.x; int dj = rj4.x; int dp = rp4.x;
                if (rv4.y < dv || (rv4.y == dv && rj4.y < dj)) {
                    dv = rv4.y; dj = rj4.y; dp = rp4.y; }
                if (rv4.z < dv || (rv4.z == dv && rj4.z < dj)) {
                    dv = rv4.z; dj = rj4.z; dp = rp4.z; }
                if (rv4.w < dv || (rv4.w == dv && rj4.w < dj)) {
                    dv = rv4.w; dj = rj4.w; dp = rp4.w; }
                const float delta = dv;
                bj = dj;
                const int nr = dp;      // pcol[bj] via payload (no LDS read)
                // prefetch next row's data early (nr not in tree: no races)
                if (nr != 0) {
                    base = upot[nr];
                    g4 = gb4[nr - 1];
                    g2 = gb2[nr - 1];
                    lb = lab[nr - 1];
                }
                // v[used] -= delta ; minv[unused] -= delta (local registers)
#define UPDATE(s) { if ((usedm >> (s)) & 1u) vpot_##s -= delta; \
                    else                     minv_##s -= delta; }
                S4_LIST(UPDATE)
                // u[rows in tree] += delta (owner-exclusive LDS update)
                if (intree) upot[tid + 1] += delta;
                if (nr == 0) break;     // bj is a free column
                j0 = bj; i0 = nr; par ^= 1;
            }
            __syncthreads();   // stage exit: upot writes done everywhere
            // augment along the alternating path (thread 0, LDS chase)
            if (tid == 0) {
                int jcur = bj;
                while (jcur != 0) {
                    int jp = way_lds[jcur];
                    pcol[jcur] = pcol[jp];
                    jcur = jp;
                }
            }
        }
    }
    __syncthreads();

    // ---- Phase 3: losses over matched pairs (all 256 threads) ----
    // (summation structure unchanged from the verified kernel)
    for (int j = 1 + tid; j <= NQ; j += THREADS) {
        int r = pcol[j];
        if (r > 0) row2col[r - 1] = j - 1;
    }
    __syncthreads();
    float cs = 0.f, bs = 0.f;
    for (int k = tid; k < n; k += THREADS) {
        int q = row2col[k];
        int lb = lab[k];
        cs += -logf(probT[lb][q]);
        float4 p4 = pbx4[q]; float2 p2 = pbx2[q];
        float4 g4 = gb4[k];  float2 g2 = gb2[k];
        bs += fabsf(p4.x - g4.x) + fabsf(p4.y - g4.y) + fabsf(p4.z - g4.z)
            + fabsf(p4.w - g4.w) + fabsf(p2.x - g2.x) + fabsf(p2.y - g2.y);
    }
    for (int off = 32; off > 0; off >>= 1) {
        cs += __shfl_down(cs, off);
        bs += __shfl_down(bs, off);
    }
    {
        int wave = tid >> 6;
        if ((tid & 63) == 0) { redc[wave] = cs; redb[wave] = bs; }
    }
    __syncthreads();

    // ---- Phase 4: publish per-block result; block 0 reduces in-kernel ----
    // (replaces the separate finalize_kernel: saves a launch + gap)
    if (tid == 0) {
        float cls = redc[0] + redc[1] + redc[2] + redc[3];
        float box = redb[0] + redb[1] + redb[2] + redb[3];
        unsigned* slot = res + b * 4;
        __hip_atomic_store(&slot[0], __float_as_uint(cls),
                           __ATOMIC_RELAXED, __HIP_MEMORY_SCOPE_AGENT);
        __hip_atomic_store(&slot[1], __float_as_uint(box),
                           __ATOMIC_RELAXED, __HIP_MEMORY_SCOPE_AGENT);
        __hip_atomic_store(&slot[2], (unsigned)n,
                           __ATOMIC_RELAXED, __HIP_MEMORY_SCOPE_AGENT);
        __hip_atomic_store(&slot[3], MAGIC,
                           __ATOMIC_RELEASE, __HIP_MEMORY_SCOPE_AGENT);
    }
    if (b == 0 && tid < 64) {
        // all 64 blocks are co-resident (64 blocks <= 256 CUs): spin is safe
        unsigned* slot = res + lane * 4;
        while (__hip_atomic_load(&slot[3], __ATOMIC_ACQUIRE,
                                 __HIP_MEMORY_SCOPE_AGENT) != MAGIC) {
            __builtin_amdgcn_s_sleep(1);
        }
        float clsv = __uint_as_float(__hip_atomic_load(
            &slot[0], __ATOMIC_RELAXED, __HIP_MEMORY_SCOPE_AGENT));
        float boxv = __uint_as_float(__hip_atomic_load(
            &slot[1], __ATOMIC_RELAXED, __HIP_MEMORY_SCOPE_AGENT));
        int cntv = (int)__hip_atomic_load(
            &slot[2], __ATOMIC_RELAXED, __HIP_MEMORY_SCOPE_AGENT);
        if (lane == 0) {
            // serial b=0..63 order via readlane: bitwise-identical to the
            // old finalize_kernel loop
            float c = 0.f, bx = 0.f;
            int nn = 0;
            for (int bb = 0; bb < 64; ++bb) {
                c += readlane_f(clsv, bb);
                bx += readlane_f(boxv, bb);
                nn += __builtin_amdgcn_readlane(cntv, bb);
            }
            float denom = (nn > 0) ? (float)nn : 1.0f;
            float cl = c / denom;
            float bl = bx / (6.0f * denom);
            out[0] = cl;
            out[1] = bl;
            out[2] = cl + 5.0f * bl;
        }
    }
}

extern "C" void kernel_launch(void* const* d_in, const int* in_sizes, int n_in,
                              void* d_out, int out_size, void* d_ws, size_t ws_size,
                              hipStream_t stream) {
    const float* pred_boxes   = (const float*)d_in[0];
    const float* pred_classes = (const float*)d_in[1];
    const float* gt_boxes     = (const float*)d_in[2];
    const unsigned int*  labels_w = (const unsigned int*)d_in[3];
    const unsigned int*  mask_w   = (const unsigned int*)d_in[4];
    const unsigned char* mask_b   = (const unsigned char*)d_in[4];

    char* ws = (char*)d_ws;
    unsigned* res = (unsigned*)(ws + 16);   // 64 slots x 16B
    float* out = (float*)d_out;

    match_kernel<<<NB, THREADS, 0, stream>>>(pred_boxes, pred_classes, gt_boxes,
                                             labels_w, mask_w, mask_b,
                                             res, out);
}

// Round 10
// 34.999 us; speedup vs baseline: 4.9108x; 1.0061x over previous
//
#include <hip/hip_runtime.h>
#include <cfloat>
#include <cmath>

#define NB 64
#define NQ 900
#define NM 64
#define NC 4
#define THREADS 256
#define NCT 225   // col-threads: thread t (t<225) owns cols [4t, 4t+4)
#define MAGIC 0x5A17C0DEu

// Apply X to the 4 per-thread column slots
#define S4_LIST(X) X(0) X(1) X(2) X(3)

__device__ __forceinline__ unsigned int uminu(unsigned int a, unsigned int b) {
    return a < b ? a : b;
}

__device__ __forceinline__ float readlane_f(float v, int l) {
    return __uint_as_float(
        (unsigned)__builtin_amdgcn_readlane(__float_as_int(v), l));
}

// Wave-64 min reduction on the VALU pipe: 4x DPP row_shr + readlane of the
// 4 row minima + scalar mins. Result is wave-uniform.
__device__ __forceinline__ unsigned int wave_redmin_u32(unsigned int x) {
    int t;
    t = __builtin_amdgcn_update_dpp(-1, (int)x, 0x111, 0xF, 0xF, false); // shr:1
    x = uminu(x, (unsigned)t);
    t = __builtin_amdgcn_update_dpp(-1, (int)x, 0x112, 0xF, 0xF, false); // shr:2
    x = uminu(x, (unsigned)t);
    t = __builtin_amdgcn_update_dpp(-1, (int)x, 0x114, 0xF, 0xF, false); // shr:4
    x = uminu(x, (unsigned)t);
    t = __builtin_amdgcn_update_dpp(-1, (int)x, 0x118, 0xF, 0xF, false); // shr:8
    x = uminu(x, (unsigned)t);
    unsigned a = (unsigned)__builtin_amdgcn_readlane((int)x, 15);
    unsigned b = (unsigned)__builtin_amdgcn_readlane((int)x, 31);
    unsigned c = (unsigned)__builtin_amdgcn_readlane((int)x, 47);
    unsigned d = (unsigned)__builtin_amdgcn_readlane((int)x, 63);
    return uminu(uminu(a, b), uminu(c, d));
}

// Per-wave argmin with np.argmin (lowest index on ties) semantics.
__device__ __forceinline__ void wave_argmin_f(float lmin, int lj,
                                              float& mv, int& mj) {
    unsigned u = __float_as_uint(lmin);
    unsigned key = (u & 0x80000000u) ? ~u : (u | 0x80000000u);
    unsigned mk = wave_redmin_u32(key);
    unsigned long long bal = __ballot(key == mk);
    int fl = (int)__builtin_ctzll(bal);
    mj = __builtin_amdgcn_readlane(lj, fl);
    unsigned mu = (mk & 0x80000000u) ? (mk & 0x7FFFFFFFu) : ~mk;
    mv = __uint_as_float(mu);
}

// Same, with a second payload (the winning column's cached pcol value).
__device__ __forceinline__ void wave_argmin_f2(float lmin, int lj, int lpc,
                                               float& mv, int& mj, int& mpc) {
    unsigned u = __float_as_uint(lmin);
    unsigned key = (u & 0x80000000u) ? ~u : (u | 0x80000000u);
    unsigned mk = wave_redmin_u32(key);
    unsigned long long bal = __ballot(key == mk);
    int fl = (int)__builtin_ctzll(bal);
    mj = __builtin_amdgcn_readlane(lj, fl);
    mpc = __builtin_amdgcn_readlane(lpc, fl);
    unsigned mu = (mk & 0x80000000u) ? (mk & 0x7FFFFFFFu) : ~mk;
    mv = __uint_as_float(mu);
}

__global__ __launch_bounds__(THREADS, 1) void match_kernel(
    const float* __restrict__ pred_boxes,    // [NB,NQ,6]
    const float* __restrict__ pred_classes,  // [NB,NQ,NC]
    const float* __restrict__ gt_boxes,      // [NB,NM,6]
    const unsigned int* __restrict__ labels_w,
    const unsigned int* __restrict__ mask_w,
    const unsigned char* __restrict__ mask_b,
    unsigned int* __restrict__ res,          // ws: 64 slots x 4 words
    float* __restrict__ out)
{
    __shared__ float4 pbx4[NQ];          // pred box dims 0..3 (phase-3 use)
    __shared__ float2 pbx2[NQ];          // pred box dims 4..5
    __shared__ float  probT[NC][NQ];     // transposed softmax probs
    __shared__ int    pcol[NQ + 1];      // col -> matched row (1-based), 0=free
    __shared__ int    claim[NQ];         // greedy contention: min row claiming col
    __shared__ int    way_lds[NQ + 1];   // Dijkstra predecessor col
    __shared__ float  upot[NM + 1];      // row potentials (1-based)
    __shared__ float4 gb4[NM];
    __shared__ float2 gb2[NM];
    __shared__ int    lab[NM];
    __shared__ int    vpos_s[NM];
    __shared__ int    row2col[NM];
    __shared__ float  rowmin_s[NM];
    __shared__ int    rowarg_s[NM];
    __shared__ float  rpart_v[4][NM];    // per-wave row-reduction partials
    __shared__ int    rpart_j[4][NM];
    __shared__ int    ua_s[NM];          // unassigned rows after greedy
    __shared__ int    nua_s;
    __shared__ int    m_sh;
    __shared__ __align__(16) float redv[2][4];   // double-buffered partials
    __shared__ __align__(16) int   redj[2][4];
    __shared__ __align__(16) int   redp[2][4];   // pcol payload
    __shared__ float  redc[4], redb[4];

    const int b = blockIdx.x;
    const int tid = threadIdx.x;
    const int lane = tid & 63;
    const int wv = tid >> 6;

    // ---- Phase 1 (fully overlapped, single barrier at the end):
    //   all col-threads: stage own 4 columns global->registers (+LDS copy)
    //   waves 0-2:       LDS init (pcol/way/claim)
    //   wave 3:          dtype detect (wave-local flags, no block barrier)
    //                    -> mask compaction -> gt/label gather
    const bool lv = (tid < NCT);
    const int qb = tid << 2;
#define DECL_COL(s) float cb0_##s = 0.f, cb1_##s = 0.f, cb2_##s = 0.f, \
                          cb3_##s = 0.f, cb4_##s = 0.f, cb5_##s = 0.f, \
                          cq0_##s = 0.f, cq1_##s = 0.f, cq2_##s = 0.f, \
                          cq3_##s = 0.f;
    S4_LIST(DECL_COL)
    if (lv) {
        const float* cp = pred_classes + ((size_t)b * NQ + qb) * NC;
        const float4 lg0 = *reinterpret_cast<const float4*>(cp + 0);
        const float4 lg1 = *reinterpret_cast<const float4*>(cp + 4);
        const float4 lg2 = *reinterpret_cast<const float4*>(cp + 8);
        const float4 lg3 = *reinterpret_cast<const float4*>(cp + 12);
#define SOFTM(s, LG) { \
        float mx = fmaxf(fmaxf(LG.x, LG.y), fmaxf(LG.z, LG.w)); \
        float e0 = expf(LG.x - mx), e1 = expf(LG.y - mx); \
        float e2 = expf(LG.z - mx), e3 = expf(LG.w - mx); \
        float inv = 1.0f / (e0 + e1 + e2 + e3); \
        cq0_##s = e0 * inv; cq1_##s = e1 * inv; \
        cq2_##s = e2 * inv; cq3_##s = e3 * inv; }
        SOFTM(0, lg0) SOFTM(1, lg1) SOFTM(2, lg2) SOFTM(3, lg3)
        // vectorized probT stores (4x dwordx4 instead of 16x dword)
        *reinterpret_cast<float4*>(&probT[0][qb]) =
            make_float4(cq0_0, cq0_1, cq0_2, cq0_3);
        *reinterpret_cast<float4*>(&probT[1][qb]) =
            make_float4(cq1_0, cq1_1, cq1_2, cq1_3);
        *reinterpret_cast<float4*>(&probT[2][qb]) =
            make_float4(cq2_0, cq2_1, cq2_2, cq2_3);
        *reinterpret_cast<float4*>(&probT[3][qb]) =
            make_float4(cq3_0, cq3_1, cq3_2, cq3_3);
        const float* bp = pred_boxes + ((size_t)b * NQ + qb) * 6;
        const float4 b0 = *reinterpret_cast<const float4*>(bp + 0);
        const float4 b1 = *reinterpret_cast<const float4*>(bp + 4);
        const float4 b2 = *reinterpret_cast<const float4*>(bp + 8);
        const float4 b3 = *reinterpret_cast<const float4*>(bp + 12);
        const float4 b4 = *reinterpret_cast<const float4*>(bp + 16);
        const float4 b5 = *reinterpret_cast<const float4*>(bp + 20);
        cb0_0 = b0.x; cb1_0 = b0.y; cb2_0 = b0.z; cb3_0 = b0.w;
        cb4_0 = b1.x; cb5_0 = b1.y;
        cb0_1 = b1.z; cb1_1 = b1.w; cb2_1 = b2.x; cb3_1 = b2.y;
        cb4_1 = b2.z; cb5_1 = b2.w;
        cb0_2 = b3.x; cb1_2 = b3.y; cb2_2 = b3.z; cb3_2 = b3.w;
        cb4_2 = b4.x; cb5_2 = b4.y;
        cb0_3 = b4.z; cb1_3 = b4.w; cb2_3 = b5.x; cb3_3 = b5.y;
        cb4_3 = b5.z; cb5_3 = b5.w;
#define STORE_PBX(s) { pbx4[qb + (s)] = make_float4(cb0_##s, cb1_##s, \
                           cb2_##s, cb3_##s); \
                       pbx2[qb + (s)] = make_float2(cb4_##s, cb5_##s); }
        S4_LIST(STORE_PBX)
    }
    if (tid < 192) {
        for (int j = tid; j <= NQ; j += 192) { pcol[j] = 0; way_lds[j] = 0; }
        for (int j = tid; j < NQ; j += 192) claim[j] = 0x7FFFFFFF;
    } else {
        // ---- wave 3 (its lanes 33-63 own no columns): matching prep ----
        // (executed by ALL 64 lanes of wave 3? no: tid>=192 is exactly wave 3
        //  lanes 0..63 minus the 33 col-thread lanes... careful: tids 192-224
        //  ARE col-threads and took the lv branch above; they still reach
        //  here? No: if/else. So only tids 225-255 enter. That's 31 lanes —
        //  not enough for the 64-slot ballot. Prep must run on the FULL wave,
        //  after the else. Handled below.)
    }
    int lmode_r = 0, mmode_r = 0;
    if (wv == 3) {
        const int l3 = lane;    // 0..63 within wave 3
        // dtype detect: this wave reads all 1024 words of each buffer
        unsigned labodd = 0u, mgt1 = 0u, modd = 0u;
        #pragma unroll
        for (int k = 0; k < 4; ++k) {
            const uint4 lw4 =
                reinterpret_cast<const uint4*>(labels_w)[l3 * 4 + k];
            labodd |= (lw4.y | lw4.w);
            const uint4 mw4 =
                reinterpret_cast<const uint4*>(mask_w)[l3 * 4 + k];
            mgt1 |= (mw4.x > 1u) | (mw4.y > 1u) | (mw4.z > 1u) | (mw4.w > 1u);
            modd |= (mw4.y | mw4.w);
        }
        const int lmode = __any(labodd != 0u) ? 0 : 1;       // 0=i32,1=i64
        const int mmode = __any(mgt1 != 0u) ? 2
                         : (__any(modd != 0u) ? 0 : 1);      // 2=bytes
        lmode_r = lmode; mmode_r = mmode;
        // mask compaction (wave-local ballot over the 64 gt slots)
        int vv;
        if (mmode == 2)      vv = (mask_b[b * NM + l3] != 0);
        else if (mmode == 1) vv = (mask_w[(b * NM + l3) * 2] != 0u);
        else                 vv = (mask_w[b * NM + l3] != 0u);
        unsigned long long bal = __ballot(vv);
        if (vv) {
            int pos = (int)__popcll(bal & ((1ull << l3) - 1ull));
            vpos_s[pos] = l3;
        }
        if (l3 == 0) m_sh = (int)__popcll(bal);
        __builtin_amdgcn_wave_barrier();
        int nw = (int)__popcll(bal);
        if (l3 < nw) {
            int g = vpos_s[l3];
            lab[l3] = (int)(lmode ? labels_w[(size_t)(b * NM + g) * 2]
                                  : labels_w[b * NM + g]);
            const float* gp = gt_boxes + ((size_t)b * NM + g) * 6;
            gb4[l3] = make_float4(gp[0], gp[1], gp[2], gp[3]);
            gb2[l3] = make_float2(gp[4], gp[5]);
        }
    }
    (void)lmode_r; (void)mmode_r;
    __syncthreads();   // staging + LDS init + matching prep all complete
    const int n = m_sh;

    // ---- Phase 2a: row reduction, unrolled by 4 to overlap DPP chains ----
#define RSCANX(s, G4, G2, LB, LMIN, LJ) { \
        float l1 = fabsf(cb0_##s - G4.x) + fabsf(cb1_##s - G4.y) \
                 + fabsf(cb2_##s - G4.z) + fabsf(cb3_##s - G4.w) \
                 + fabsf(cb4_##s - G2.x) + fabsf(cb5_##s - G2.y); \
        float pr = ((LB) == 0) ? cq0_##s : (((LB) == 1) ? cq1_##s \
                 : (((LB) == 2) ? cq2_##s : cq3_##s)); \
        float c = 5.0f * l1 - pr; \
        if (lv && c < (LMIN)) { (LMIN) = c; (LJ) = qb + (s); } }
#define RSA(s) RSCANX(s, g4a, g2a, lba, lmina, lja)
#define RSB(s) RSCANX(s, g4b, g2b, lbb, lminb, ljb)
#define RSC(s) RSCANX(s, g4c, g2c, lbc, lminc, ljc)
#define RSD(s) RSCANX(s, g4d, g2d, lbd, lmind, ljd)
    {
        int k = 0;
        for (; k + 3 < n; k += 4) {
            const float4 g4a = gb4[k];     const float2 g2a = gb2[k];
            const int lba = lab[k];
            const float4 g4b = gb4[k + 1]; const float2 g2b = gb2[k + 1];
            const int lbb = lab[k + 1];
            const float4 g4c = gb4[k + 2]; const float2 g2c = gb2[k + 2];
            const int lbc = lab[k + 2];
            const float4 g4d = gb4[k + 3]; const float2 g2d = gb2[k + 3];
            const int lbd = lab[k + 3];
            float lmina = FLT_MAX, lminb = FLT_MAX;
            float lminc = FLT_MAX, lmind = FLT_MAX;
            int lja = NQ + 2, ljb = NQ + 2, ljc = NQ + 2, ljd = NQ + 2;
            S4_LIST(RSA) S4_LIST(RSB) S4_LIST(RSC) S4_LIST(RSD)
            float mva, mvb, mvc, mvd; int mja, mjb, mjc, mjd;
            wave_argmin_f(lmina, lja, mva, mja);
            wave_argmin_f(lminb, ljb, mvb, mjb);
            wave_argmin_f(lminc, ljc, mvc, mjc);
            wave_argmin_f(lmind, ljd, mvd, mjd);
            if (lane == 0) {
                rpart_v[wv][k] = mva;     rpart_j[wv][k] = mja;
                rpart_v[wv][k + 1] = mvb; rpart_j[wv][k + 1] = mjb;
                rpart_v[wv][k + 2] = mvc; rpart_j[wv][k + 2] = mjc;
                rpart_v[wv][k + 3] = mvd; rpart_j[wv][k + 3] = mjd;
            }
        }
        for (; k < n; ++k) {
            const float4 g4a = gb4[k]; const float2 g2a = gb2[k];
            const int lba = lab[k];
            float lmina = FLT_MAX; int lja = NQ + 2;
            S4_LIST(RSA)
            float mva; int mja;
            wave_argmin_f(lmina, lja, mva, mja);
            if (lane == 0) { rpart_v[wv][k] = mva; rpart_j[wv][k] = mja; }
        }
    }
    __syncthreads();
    if (tid < n) {
        float bv = rpart_v[0][tid]; int bj = rpart_j[0][tid];
        #pragma unroll
        for (int w = 1; w < 4; ++w) {
            float vw = rpart_v[w][tid]; int jw = rpart_j[w][tid];
            if (vw < bv || (vw == bv && jw < bj)) { bv = vw; bj = jw; }
        }
        rowmin_s[tid] = bv; rowarg_s[tid] = bj;
    }
    __syncthreads();

    // ---- Phase 2b: greedy claim (dual-feasible partial assignment) ----
    if (tid < n) atomicMin(&claim[rowarg_s[tid]], tid);
    for (int k = tid; k < n; k += THREADS) upot[k + 1] = rowmin_s[k];
    if (tid == 0) upot[0] = 0.f;
    __syncthreads();
    if (tid < n) {
        int a = rowarg_s[tid];
        if (claim[a] == tid) pcol[a + 1] = tid + 1;   // unique winner
    }
    if (tid < 64) {
        int un = (lane < n) && (claim[rowarg_s[lane]] != lane);
        unsigned long long bal = __ballot(un);
        if (un) ua_s[(int)__popcll(bal & ((1ull << lane) - 1ull))] = lane;
        if (lane == 0) nua_s = (int)__popcll(bal);
    }
    __syncthreads();

    // ---- Phase 2c: shortest augmenting path, 1 barrier per iteration.
    // pcol is stage-constant: cached in registers per slot at stage start
    // and carried through the argmin payload.
    {
        float minv_0, minv_1, minv_2, minv_3;
        float vpot_0 = 0.f, vpot_1 = 0.f, vpot_2 = 0.f, vpot_3 = 0.f;
        const int nua = nua_s;

        for (int t = 0; t < nua; ++t) {
            const int i = ua_s[t] + 1;
            minv_0 = FLT_MAX; minv_1 = FLT_MAX;
            minv_2 = FLT_MAX; minv_3 = FLT_MAX;
            unsigned int usedm = 0;
            int intree = 0;
            if (tid == 0) pcol[0] = i;   // col 0 is virtual: never a payload
            __syncthreads();   // stage start: prior augment/upot stable
            // cache this stage's pcol for own slots (stage-constant)
            int pc_0 = 0, pc_1 = 0, pc_2 = 0, pc_3 = 0;
            if (lv) {
                pc_0 = pcol[qb + 1]; pc_1 = pcol[qb + 2];
                pc_2 = pcol[qb + 3]; pc_3 = pcol[qb + 4];
            }
            // prefetch start row's data
            float base = upot[i];
            float4 g4 = gb4[i - 1];
            float2 g2 = gb2[i - 1];
            int lb = lab[i - 1];
            int j0 = 0, i0 = i, bj = 0, par = 0;
            while (true) {
                // mark used[j0] (owner thread), add row i0 to the tree
                if (j0 > 0 && ((j0 - 1) >> 2) == tid)
                    usedm |= 1u << ((j0 - 1) & 3);
                if (tid == i0 - 1) intree = 1;
                float lmin = FLT_MAX; int lj = NQ + 2; int lpc = 0;
#define SSCAN(s) { \
                float l1 = fabsf(cb0_##s - g4.x) + fabsf(cb1_##s - g4.y) \
                         + fabsf(cb2_##s - g4.z) + fabsf(cb3_##s - g4.w) \
                         + fabsf(cb4_##s - g2.x) + fabsf(cb5_##s - g2.y); \
                float pr = (lb == 0) ? cq0_##s : ((lb == 1) ? cq1_##s \
                         : ((lb == 2) ? cq2_##s : cq3_##s)); \
                float cost = 5.0f * l1 - pr; \
                float cur = cost - base - vpot_##s; \
                if (lv && !((usedm >> (s)) & 1u)) { \
                    if (cur < minv_##s) { minv_##s = cur; \
                                          way_lds[qb + (s) + 1] = j0; } \
                    if (minv_##s < lmin) { lmin = minv_##s; \
                                           lj = qb + (s) + 1; \
                                           lpc = pc_##s; } } }
                S4_LIST(SSCAN)
                float pv; int pj, pp;
                wave_argmin_f2(lmin, lj, lpc, pv, pj, pp);
                if (lane == 0) {
                    redv[par][wv] = pv; redj[par][wv] = pj; redp[par][wv] = pp;
                }
                __syncthreads();   // B1: partials + way_lds visible
                // redundant 4-way combine on every thread
                const float4 rv4 = *reinterpret_cast<const float4*>(redv[par]);
                const int4   rj4 = *reinterpret_cast<const int4*>(redj[par]);
                const int4   rp4 = *reinterpret_cast<const int4*>(redp[par]);
                float dv = rv4.x; int dj = rj4.x; int dp = rp4.x;
                if (rv4.y < dv || (rv4.y == dv && rj4.y < dj)) {
                    dv = rv4.y; dj = rj4.y; dp = rp4.y; }
                if (rv4.z < dv || (rv4.z == dv && rj4.z < dj)) {
                    dv = rv4.z; dj = rj4.z; dp = rp4.z; }
                if (rv4.w < dv || (rv4.w == dv && rj4.w < dj)) {
                    dv = rv4.w; dj = rj4.w; dp = rp4.w; }
                const float delta = dv;
                bj = dj;
                const int nr = dp;      // pcol[bj] via payload (no LDS read)
                // prefetch next row's data early (nr not in tree: no races)
                if (nr != 0) {
                    base = upot[nr];
                    g4 = gb4[nr - 1];
                    g2 = gb2[nr - 1];
                    lb = lab[nr - 1];
                }
                // v[used] -= delta ; minv[unused] -= delta (local registers)
#define UPDATE(s) { if ((usedm >> (s)) & 1u) vpot_##s -= delta; \
                    else                     minv_##s -= delta; }
                S4_LIST(UPDATE)
                // u[rows in tree] += delta (owner-exclusive LDS update)
                if (intree) upot[tid + 1] += delta;
                if (nr == 0) break;     // bj is a free column
                j0 = bj; i0 = nr; par ^= 1;
            }
            __syncthreads();   // stage exit: upot writes done everywhere
            // augment along the alternating path (thread 0, LDS chase)
            if (tid == 0) {
                int jcur = bj;
                while (jcur != 0) {
                    int jp = way_lds[jcur];
                    pcol[jcur] = pcol[jp];
                    jcur = jp;
                }
            }
        }
    }
    __syncthreads();

    // ---- Phase 3: losses over matched pairs (all 256 threads) ----
    // (summation structure unchanged from the verified kernel)
    for (int j = 1 + tid; j <= NQ; j += THREADS) {
        int r = pcol[j];
        if (r > 0) row2col[r - 1] = j - 1;
    }
    __syncthreads();
    float cs = 0.f, bs = 0.f;
    for (int k = tid; k < n; k += THREADS) {
        int q = row2col[k];
        int lb = lab[k];
        cs += -logf(probT[lb][q]);
        float4 p4 = pbx4[q]; float2 p2 = pbx2[q];
        float4 g4 = gb4[k];  float2 g2 = gb2[k];
        bs += fabsf(p4.x - g4.x) + fabsf(p4.y - g4.y) + fabsf(p4.z - g4.z)
            + fabsf(p4.w - g4.w) + fabsf(p2.x - g2.x) + fabsf(p2.y - g2.y);
    }
    for (int off = 32; off > 0; off >>= 1) {
        cs += __shfl_down(cs, off);
        bs += __shfl_down(bs, off);
    }
    {
        int wave = tid >> 6;
        if ((tid & 63) == 0) { redc[wave] = cs; redb[wave] = bs; }
    }
    __syncthreads();

    // ---- Phase 4: publish per-block result; block 0 reduces in-kernel ----
    if (tid == 0) {
        float cls = redc[0] + redc[1] + redc[2] + redc[3];
        float box = redb[0] + redb[1] + redb[2] + redb[3];
        unsigned* slot = res + b * 4;
        __hip_atomic_store(&slot[0], __float_as_uint(cls),
                           __ATOMIC_RELAXED, __HIP_MEMORY_SCOPE_AGENT);
        __hip_atomic_store(&slot[1], __float_as_uint(box),
                           __ATOMIC_RELAXED, __HIP_MEMORY_SCOPE_AGENT);
        __hip_atomic_store(&slot[2], (unsigned)n,
                           __ATOMIC_RELAXED, __HIP_MEMORY_SCOPE_AGENT);
        __hip_atomic_store(&slot[3], MAGIC,
                           __ATOMIC_RELEASE, __HIP_MEMORY_SCOPE_AGENT);
    }
    if (b == 0 && tid < 64) {
        // all 64 blocks are co-resident (64 blocks <= 256 CUs): spin is safe
        unsigned* slot = res + lane * 4;
        while (__hip_atomic_load(&slot[3], __ATOMIC_ACQUIRE,
                                 __HIP_MEMORY_SCOPE_AGENT) != MAGIC) {
            __builtin_amdgcn_s_sleep(1);
        }
        float clsv = __uint_as_float(__hip_atomic_load(
            &slot[0], __ATOMIC_RELAXED, __HIP_MEMORY_SCOPE_AGENT));
        float boxv = __uint_as_float(__hip_atomic_load(
            &slot[1], __ATOMIC_RELAXED, __HIP_MEMORY_SCOPE_AGENT));
        int cntv = (int)__hip_atomic_load(
            &slot[2], __ATOMIC_RELAXED, __HIP_MEMORY_SCOPE_AGENT);
        if (lane == 0) {
            // serial b=0..63 order via readlane: bitwise-identical to the
            // original finalize loop
            float c = 0.f, bx = 0.f;
            int nn = 0;
            for (int bb = 0; bb < 64; ++bb) {
                c += readlane_f(clsv, bb);
                bx += readlane_f(boxv, bb);
                nn += __builtin_amdgcn_readlane(cntv, bb);
            }
            float denom = (nn > 0) ? (float)nn : 1.0f;
            float cl = c / denom;
            float bl = bx / (6.0f * denom);
            out[0] = cl;
            out[1] = bl;
            out[2] = cl + 5.0f * bl;
        }
    }
}

extern "C" void kernel_launch(void* const* d_in, const int* in_sizes, int n_in,
                              void* d_out, int out_size, void* d_ws, size_t ws_size,
                              hipStream_t stream) {
    const float* pred_boxes   = (const float*)d_in[0];
    const float* pred_classes = (const float*)d_in[1];
    const float* gt_boxes     = (const float*)d_in[2];
    const unsigned int*  labels_w = (const unsigned int*)d_in[3];
    const unsigned int*  mask_w   = (const unsigned int*)d_in[4];
    const unsigned char* mask_b   = (const unsigned char*)d_in[4];

    char* ws = (char*)d_ws;
    unsigned* res = (unsigned*)(ws + 16);   // 64 slots x 16B
    float* out = (float*)d_out;

    match_kernel<<<NB, THREADS, 0, stream>>>(pred_boxes, pred_classes, gt_boxes,
                                             labels_w, mask_w, mask_b,
                                             res, out);
}

// Round 11
// 34.096 us; speedup vs baseline: 5.0408x; 1.0265x over previous
//
#include <hip/hip_runtime.h>
#include <cfloat>
#include <cmath>

#define NB 64
#define NQ 900
#define NM 64
#define NC 4
#define THREADS 256
#define NCT 225   // col-threads: thread t (t<225) owns cols [4t, 4t+4)
#define MAGIC 0x5A17C0DEu

// Apply X to the 4 per-thread column slots
#define S4_LIST(X) X(0) X(1) X(2) X(3)

__device__ __forceinline__ unsigned int uminu(unsigned int a, unsigned int b) {
    return a < b ? a : b;
}

__device__ __forceinline__ float readlane_f(float v, int l) {
    return __uint_as_float(
        (unsigned)__builtin_amdgcn_readlane(__float_as_int(v), l));
}

// Wave-64 min reduction on the VALU pipe: 4x DPP row_shr + readlane of the
// 4 row minima + scalar mins. Result is wave-uniform.
__device__ __forceinline__ unsigned int wave_redmin_u32(unsigned int x) {
    int t;
    t = __builtin_amdgcn_update_dpp(-1, (int)x, 0x111, 0xF, 0xF, false); // shr:1
    x = uminu(x, (unsigned)t);
    t = __builtin_amdgcn_update_dpp(-1, (int)x, 0x112, 0xF, 0xF, false); // shr:2
    x = uminu(x, (unsigned)t);
    t = __builtin_amdgcn_update_dpp(-1, (int)x, 0x114, 0xF, 0xF, false); // shr:4
    x = uminu(x, (unsigned)t);
    t = __builtin_amdgcn_update_dpp(-1, (int)x, 0x118, 0xF, 0xF, false); // shr:8
    x = uminu(x, (unsigned)t);
    unsigned a = (unsigned)__builtin_amdgcn_readlane((int)x, 15);
    unsigned b = (unsigned)__builtin_amdgcn_readlane((int)x, 31);
    unsigned c = (unsigned)__builtin_amdgcn_readlane((int)x, 47);
    unsigned d = (unsigned)__builtin_amdgcn_readlane((int)x, 63);
    return uminu(uminu(a, b), uminu(c, d));
}

// Per-wave argmin with np.argmin (lowest index on ties) semantics.
__device__ __forceinline__ void wave_argmin_f(float lmin, int lj,
                                              float& mv, int& mj) {
    unsigned u = __float_as_uint(lmin);
    unsigned key = (u & 0x80000000u) ? ~u : (u | 0x80000000u);
    unsigned mk = wave_redmin_u32(key);
    unsigned long long bal = __ballot(key == mk);
    int fl = (int)__builtin_ctzll(bal);
    mj = __builtin_amdgcn_readlane(lj, fl);
    unsigned mu = (mk & 0x80000000u) ? (mk & 0x7FFFFFFFu) : ~mk;
    mv = __uint_as_float(mu);
}

// Same, with a second payload (the winning column's cached pcol value).
__device__ __forceinline__ void wave_argmin_f2(float lmin, int lj, int lpc,
                                               float& mv, int& mj, int& mpc) {
    unsigned u = __float_as_uint(lmin);
    unsigned key = (u & 0x80000000u) ? ~u : (u | 0x80000000u);
    unsigned mk = wave_redmin_u32(key);
    unsigned long long bal = __ballot(key == mk);
    int fl = (int)__builtin_ctzll(bal);
    mj = __builtin_amdgcn_readlane(lj, fl);
    mpc = __builtin_amdgcn_readlane(lpc, fl);
    unsigned mu = (mk & 0x80000000u) ? (mk & 0x7FFFFFFFu) : ~mk;
    mv = __uint_as_float(mu);
}

__global__ __launch_bounds__(THREADS, 1) void match_kernel(
    const float* __restrict__ pred_boxes,    // [NB,NQ,6]
    const float* __restrict__ pred_classes,  // [NB,NQ,NC]
    const float* __restrict__ gt_boxes,      // [NB,NM,6]
    const unsigned int* __restrict__ labels_w,
    const unsigned int* __restrict__ mask_w,
    const unsigned char* __restrict__ mask_b,
    unsigned int* __restrict__ res,          // ws: 64 slots x 4 words
    float* __restrict__ out)
{
    __shared__ float4 pbx4[NQ];          // pred box dims 0..3 (phase-3 use)
    __shared__ float2 pbx2[NQ];          // pred box dims 4..5
    __shared__ float  probT[NC][NQ];     // transposed softmax probs
    __shared__ int    pcol[NQ + 1];      // col -> matched row (1-based), 0=free
    __shared__ int    claim[NQ];         // greedy contention: min row claiming col
    __shared__ int    way_lds[NQ + 1];   // Dijkstra predecessor (no init needed:
                                         // read only for argmin winners, which
                                         // always had a minv-improving write)
    __shared__ float  upot[NM + 1];      // row potentials (1-based)
    __shared__ float4 gb4[NM];
    __shared__ float2 gb2[NM];
    __shared__ int    lab[NM];
    __shared__ int    vpos_s[NM];
    __shared__ int    row2col[NM];
    __shared__ int    rowarg_s[NM];
    __shared__ float  rpart_v[4][NM];    // per-wave row-reduction partials
    __shared__ int    rpart_j[4][NM];
    __shared__ int    ua_s[NM];          // unassigned rows after greedy
    __shared__ int    nua_s;
    __shared__ int    m_sh;
    __shared__ __align__(16) float redv[2][4];   // double-buffered partials
    __shared__ __align__(16) int   redj[2][4];
    __shared__ __align__(16) int   redp[2][4];   // pcol payload
    __shared__ float  redc[4], redb[4];

    const int b = blockIdx.x;
    const int tid = threadIdx.x;
    const int lane = tid & 63;
    const int wv = tid >> 6;

    // ---- Phase 1 (fully overlapped, single barrier at the end):
    //   col-threads: stage own 4 columns global->registers (+LDS copies)
    //   waves 0-2:   LDS init (pcol/claim)
    //   wave 3:      dtype detect -> mask compaction -> gt/label gather
    const bool lv = (tid < NCT);
    const int qb = tid << 2;
    const int qbc = lv ? qb : 0;        // clamped base for LDS reads
#define DECL_COL(s) float cb0_##s = 0.f, cb1_##s = 0.f, cb2_##s = 0.f, \
                          cb3_##s = 0.f, cb4_##s = 0.f, cb5_##s = 0.f;
    S4_LIST(DECL_COL)
    if (lv) {
        const float* cp = pred_classes + ((size_t)b * NQ + qb) * NC;
        const float4 lg0 = *reinterpret_cast<const float4*>(cp + 0);
        const float4 lg1 = *reinterpret_cast<const float4*>(cp + 4);
        const float4 lg2 = *reinterpret_cast<const float4*>(cp + 8);
        const float4 lg3 = *reinterpret_cast<const float4*>(cp + 12);
        float4 r0, r1, r2, r3;           // class-major prob rows for 4 cols
#define SOFTM(LG, C0, C1, C2, C3) { \
        float mx = fmaxf(fmaxf(LG.x, LG.y), fmaxf(LG.z, LG.w)); \
        float e0 = expf(LG.x - mx), e1 = expf(LG.y - mx); \
        float e2 = expf(LG.z - mx), e3 = expf(LG.w - mx); \
        float inv = 1.0f / (e0 + e1 + e2 + e3); \
        C0 = e0 * inv; C1 = e1 * inv; C2 = e2 * inv; C3 = e3 * inv; }
        SOFTM(lg0, r0.x, r1.x, r2.x, r3.x)
        SOFTM(lg1, r0.y, r1.y, r2.y, r3.y)
        SOFTM(lg2, r0.z, r1.z, r2.z, r3.z)
        SOFTM(lg3, r0.w, r1.w, r2.w, r3.w)
        *reinterpret_cast<float4*>(&probT[0][qb]) = r0;
        *reinterpret_cast<float4*>(&probT[1][qb]) = r1;
        *reinterpret_cast<float4*>(&probT[2][qb]) = r2;
        *reinterpret_cast<float4*>(&probT[3][qb]) = r3;
        const float* bp = pred_boxes + ((size_t)b * NQ + qb) * 6;
        const float4 b0 = *reinterpret_cast<const float4*>(bp + 0);
        const float4 b1 = *reinterpret_cast<const float4*>(bp + 4);
        const float4 b2 = *reinterpret_cast<const float4*>(bp + 8);
        const float4 b3 = *reinterpret_cast<const float4*>(bp + 12);
        const float4 b4 = *reinterpret_cast<const float4*>(bp + 16);
        const float4 b5 = *reinterpret_cast<const float4*>(bp + 20);
        cb0_0 = b0.x; cb1_0 = b0.y; cb2_0 = b0.z; cb3_0 = b0.w;
        cb4_0 = b1.x; cb5_0 = b1.y;
        cb0_1 = b1.z; cb1_1 = b1.w; cb2_1 = b2.x; cb3_1 = b2.y;
        cb4_1 = b2.z; cb5_1 = b2.w;
        cb0_2 = b3.x; cb1_2 = b3.y; cb2_2 = b3.z; cb3_2 = b3.w;
        cb4_2 = b4.x; cb5_2 = b4.y;
        cb0_3 = b4.z; cb1_3 = b4.w; cb2_3 = b5.x; cb3_3 = b5.y;
        cb4_3 = b5.z; cb5_3 = b5.w;
#define STORE_PBX(s) { pbx4[qb + (s)] = make_float4(cb0_##s, cb1_##s, \
                           cb2_##s, cb3_##s); \
                       pbx2[qb + (s)] = make_float2(cb4_##s, cb5_##s); }
        S4_LIST(STORE_PBX)
    }
    if (tid < 192) {
        for (int j = tid; j <= NQ; j += 192) pcol[j] = 0;
        for (int j = tid; j < NQ; j += 192) claim[j] = 0x7FFFFFFF;
    }
    if (wv == 3) {
        const int l3 = lane;
        // dtype detect: this wave reads all 1024 words of each buffer
        unsigned labodd = 0u, mgt1 = 0u, modd = 0u;
        #pragma unroll
        for (int k = 0; k < 4; ++k) {
            const uint4 lw4 =
                reinterpret_cast<const uint4*>(labels_w)[l3 * 4 + k];
            labodd |= (lw4.y | lw4.w);
            const uint4 mw4 =
                reinterpret_cast<const uint4*>(mask_w)[l3 * 4 + k];
            mgt1 |= (mw4.x > 1u) | (mw4.y > 1u) | (mw4.z > 1u) | (mw4.w > 1u);
            modd |= (mw4.y | mw4.w);
        }
        const int lmode = __any(labodd != 0u) ? 0 : 1;       // 0=i32,1=i64
        const int mmode = __any(mgt1 != 0u) ? 2
                         : (__any(modd != 0u) ? 0 : 1);      // 2=bytes
        // mask compaction (wave-local ballot over the 64 gt slots)
        int vv;
        if (mmode == 2)      vv = (mask_b[b * NM + l3] != 0);
        else if (mmode == 1) vv = (mask_w[(b * NM + l3) * 2] != 0u);
        else                 vv = (mask_w[b * NM + l3] != 0u);
        unsigned long long bal = __ballot(vv);
        if (vv) {
            int pos = (int)__popcll(bal & ((1ull << l3) - 1ull));
            vpos_s[pos] = l3;
        }
        if (l3 == 0) m_sh = (int)__popcll(bal);
        __builtin_amdgcn_wave_barrier();
        int nw = (int)__popcll(bal);
        if (l3 < nw) {
            int g = vpos_s[l3];
            lab[l3] = (int)(lmode ? labels_w[(size_t)(b * NM + g) * 2]
                                  : labels_w[b * NM + g]);
            const float* gp = gt_boxes + ((size_t)b * NM + g) * 6;
            gb4[l3] = make_float4(gp[0], gp[1], gp[2], gp[3]);
            gb2[l3] = make_float2(gp[4], gp[5]);
        }
    }
    __syncthreads();   // staging + LDS init + matching prep all complete
    const int n = m_sh;

    // cost of slot s vs row data (G4,G2) with prob PRc: bitwise-identical
    // expression to all prior rounds
#define COSTS(s, G4, G2, PRc) \
    (5.0f * (fabsf(cb0_##s - (G4).x) + fabsf(cb1_##s - (G4).y) \
           + fabsf(cb2_##s - (G4).z) + fabsf(cb3_##s - (G4).w) \
           + fabsf(cb4_##s - (G2).x) + fabsf(cb5_##s - (G2).y)) - (PRc))

    // ---- Phase 2a: row reduction, unrolled by 4 to overlap DPP chains ----
    // min3-style slot min + first-equal-slot recovery == sequential
    // strict-< first-min (lowest index on ties).
#define ROWMIN(G4, G2, PR4, MV, MJ) { \
    float c0 = COSTS(0, G4, G2, (PR4).x); \
    float c1 = COSTS(1, G4, G2, (PR4).y); \
    float c2 = COSTS(2, G4, G2, (PR4).z); \
    float c3 = COSTS(3, G4, G2, (PR4).w); \
    float lm = FLT_MAX; int ljj = NQ + 2; \
    if (lv) { \
        lm = fminf(fminf(c0, c1), fminf(c2, c3)); \
        ljj = (c0 == lm) ? qb : ((c1 == lm) ? qb + 1 \
              : ((c2 == lm) ? qb + 2 : qb + 3)); \
    } \
    wave_argmin_f(lm, ljj, MV, MJ); }
    {
        int k = 0;
        for (; k + 3 < n; k += 4) {
            const int lba = lab[k],     lbb = lab[k + 1];
            const int lbc = lab[k + 2], lbd = lab[k + 3];
            const float4 g4a = gb4[k];     const float2 g2a = gb2[k];
            const float4 g4b = gb4[k + 1]; const float2 g2b = gb2[k + 1];
            const float4 g4c = gb4[k + 2]; const float2 g2c = gb2[k + 2];
            const float4 g4d = gb4[k + 3]; const float2 g2d = gb2[k + 3];
            const float4 pra = *reinterpret_cast<const float4*>(&probT[lba][qbc]);
            const float4 prb = *reinterpret_cast<const float4*>(&probT[lbb][qbc]);
            const float4 prc = *reinterpret_cast<const float4*>(&probT[lbc][qbc]);
            const float4 prd = *reinterpret_cast<const float4*>(&probT[lbd][qbc]);
            float mva, mvb, mvc, mvd; int mja, mjb, mjc, mjd;
            ROWMIN(g4a, g2a, pra, mva, mja)
            ROWMIN(g4b, g2b, prb, mvb, mjb)
            ROWMIN(g4c, g2c, prc, mvc, mjc)
            ROWMIN(g4d, g2d, prd, mvd, mjd)
            if (lane == 0) {
                rpart_v[wv][k] = mva;     rpart_j[wv][k] = mja;
                rpart_v[wv][k + 1] = mvb; rpart_j[wv][k + 1] = mjb;
                rpart_v[wv][k + 2] = mvc; rpart_j[wv][k + 2] = mjc;
                rpart_v[wv][k + 3] = mvd; rpart_j[wv][k + 3] = mjd;
            }
        }
        for (; k < n; ++k) {
            const int lba = lab[k];
            const float4 g4a = gb4[k]; const float2 g2a = gb2[k];
            const float4 pra = *reinterpret_cast<const float4*>(&probT[lba][qbc]);
            float mva; int mja;
            ROWMIN(g4a, g2a, pra, mva, mja)
            if (lane == 0) { rpart_v[wv][k] = mva; rpart_j[wv][k] = mja; }
        }
    }
    __syncthreads();

    // ---- Phase 2b: combine + duals + greedy claim (merged, 2 barriers) ----
    if (tid < n) {
        float bv = rpart_v[0][tid]; int bj2 = rpart_j[0][tid];
        #pragma unroll
        for (int w = 1; w < 4; ++w) {
            float vw = rpart_v[w][tid]; int jw = rpart_j[w][tid];
            if (vw < bv || (vw == bv && jw < bj2)) { bv = vw; bj2 = jw; }
        }
        rowarg_s[tid] = bj2;
        upot[tid + 1] = bv;                 // u[i] = row min (dual init)
        atomicMin(&claim[bj2], tid);        // greedy claim, lowest row wins
    }
    if (tid == 0) upot[0] = 0.f;
    __syncthreads();                        // claims + duals final
    if (tid < n) {
        int a = rowarg_s[tid];
        if (claim[a] == tid) pcol[a + 1] = tid + 1;   // unique winner
    }
    if (tid < 64) {
        int un = (lane < n) && (claim[rowarg_s[lane]] != lane);
        unsigned long long bal = __ballot(un);
        if (un) ua_s[(int)__popcll(bal & ((1ull << lane) - 1ull))] = lane;
        if (lane == 0) nua_s = (int)__popcll(bal);
    }
    __syncthreads();                        // pcol winners + ua list visible

    // ---- Phase 2c: shortest augmenting path, 1 barrier per iteration.
    // pcol is stage-constant (cached per slot, carried through the argmin
    // payload); row data + prob row prefetched off the critical path.
    {
        float minv_0, minv_1, minv_2, minv_3;
        float vpot_0 = 0.f, vpot_1 = 0.f, vpot_2 = 0.f, vpot_3 = 0.f;
        const int nua = nua_s;

        for (int t = 0; t < nua; ++t) {
            const int i = ua_s[t] + 1;
            minv_0 = FLT_MAX; minv_1 = FLT_MAX;
            minv_2 = FLT_MAX; minv_3 = FLT_MAX;
            unsigned int usedm = 0;
            int intree = 0;
            if (tid == 0) pcol[0] = i;   // col 0 is virtual: never a payload
            __syncthreads();   // stage start: prior augment/upot stable
            // cache this stage's pcol for own slots (stage-constant)
            int pc_0 = 0, pc_1 = 0, pc_2 = 0, pc_3 = 0;
            if (lv) {
                pc_0 = pcol[qb + 1]; pc_1 = pcol[qb + 2];
                pc_2 = pcol[qb + 3]; pc_3 = pcol[qb + 4];
            }
            // prefetch start row's data (incl. its prob row)
            int lb = lab[i - 1];
            float base = upot[i];
            float4 g4 = gb4[i - 1];
            float2 g2 = gb2[i - 1];
            float4 pf = *reinterpret_cast<const float4*>(&probT[lb][qbc]);
            int j0 = 0, i0 = i, bj = 0, par = 0;
            while (true) {
                // mark used[j0] (owner thread), add row i0 to the tree
                if (j0 > 0 && ((j0 - 1) >> 2) == tid)
                    usedm |= 1u << ((j0 - 1) & 3);
                if (tid == i0 - 1) intree = 1;
                float lmin = FLT_MAX; int lj = NQ + 2; int lpc = 0;
#define SSCAN(s, PRc) { \
                float cost = COSTS(s, g4, g2, PRc); \
                float cur = cost - base - vpot_##s; \
                if (lv && !((usedm >> (s)) & 1u)) { \
                    if (cur < minv_##s) { minv_##s = cur; \
                                          way_lds[qb + (s) + 1] = j0; } \
                    if (minv_##s < lmin) { lmin = minv_##s; \
                                           lj = qb + (s) + 1; \
                                           lpc = pc_##s; } } }
                SSCAN(0, pf.x) SSCAN(1, pf.y) SSCAN(2, pf.z) SSCAN(3, pf.w)
                float pv; int pj, pp;
                wave_argmin_f2(lmin, lj, lpc, pv, pj, pp);
                if (lane == 0) {
                    redv[par][wv] = pv; redj[par][wv] = pj; redp[par][wv] = pp;
                }
                __syncthreads();   // B1: partials + way_lds visible
                // redundant 4-way combine on every thread
                const float4 rv4 = *reinterpret_cast<const float4*>(redv[par]);
                const int4   rj4 = *reinterpret_cast<const int4*>(redj[par]);
                const int4   rp4 = *reinterpret_cast<const int4*>(redp[par]);
                float dv = rv4.x; int dj = rj4.x; int dp = rp4.x;
                if (rv4.y < dv || (rv4.y == dv && rj4.y < dj)) {
                    dv = rv4.y; dj = rj4.y; dp = rp4.y; }
                if (rv4.z < dv || (rv4.z == dv && rj4.z < dj)) {
                    dv = rv4.z; dj = rj4.z; dp = rp4.z; }
                if (rv4.w < dv || (rv4.w == dv && rj4.w < dj)) {
                    dv = rv4.w; dj = rj4.w; dp = rp4.w; }
                const float delta = dv;
                bj = dj;
                const int nr = dp;      // pcol[bj] via payload (no LDS read)
                // prefetch next row's data early (nr not in tree: no races)
                if (nr != 0) {
                    lb = lab[nr - 1];
                    base = upot[nr];
                    g4 = gb4[nr - 1];
                    g2 = gb2[nr - 1];
                    pf = *reinterpret_cast<const float4*>(&probT[lb][qbc]);
                }
                // v[used] -= delta ; minv[unused] -= delta (local registers)
#define UPDATE(s) { if ((usedm >> (s)) & 1u) vpot_##s -= delta; \
                    else                     minv_##s -= delta; }
                S4_LIST(UPDATE)
                // u[rows in tree] += delta (owner-exclusive LDS update)
                if (intree) upot[tid + 1] += delta;
                if (nr == 0) break;     // bj is a free column
                j0 = bj; i0 = nr; par ^= 1;
            }
            __syncthreads();   // stage exit: upot writes done everywhere
            // augment along the alternating path (thread 0, LDS chase)
            if (tid == 0) {
                int jcur = bj;
                while (jcur != 0) {
                    int jp = way_lds[jcur];
                    pcol[jcur] = pcol[jp];
                    jcur = jp;
                }
            }
        }
    }
    __syncthreads();

    // ---- Phase 3: losses over matched pairs (all 256 threads) ----
    // (summation structure unchanged from the verified kernel)
    for (int j = 1 + tid; j <= NQ; j += THREADS) {
        int r = pcol[j];
        if (r > 0) row2col[r - 1] = j - 1;
    }
    __syncthreads();
    float cs = 0.f, bs = 0.f;
    for (int k = tid; k < n; k += THREADS) {
        int q = row2col[k];
        int lb = lab[k];
        cs += -logf(probT[lb][q]);
        float4 p4 = pbx4[q]; float2 p2 = pbx2[q];
        float4 g4 = gb4[k];  float2 g2 = gb2[k];
        bs += fabsf(p4.x - g4.x) + fabsf(p4.y - g4.y) + fabsf(p4.z - g4.z)
            + fabsf(p4.w - g4.w) + fabsf(p2.x - g2.x) + fabsf(p2.y - g2.y);
    }
    for (int off = 32; off > 0; off >>= 1) {
        cs += __shfl_down(cs, off);
        bs += __shfl_down(bs, off);
    }
    {
        int wave = tid >> 6;
        if ((tid & 63) == 0) { redc[wave] = cs; redb[wave] = bs; }
    }
    __syncthreads();

    // ---- Phase 4: publish per-block result; block 0 reduces in-kernel ----
    if (tid == 0) {
        float cls = redc[0] + redc[1] + redc[2] + redc[3];
        float box = redb[0] + redb[1] + redb[2] + redb[3];
        unsigned* slot = res + b * 4;
        __hip_atomic_store(&slot[0], __float_as_uint(cls),
                           __ATOMIC_RELAXED, __HIP_MEMORY_SCOPE_AGENT);
        __hip_atomic_store(&slot[1], __float_as_uint(box),
                           __ATOMIC_RELAXED, __HIP_MEMORY_SCOPE_AGENT);
        __hip_atomic_store(&slot[2], (unsigned)n,
                           __ATOMIC_RELAXED, __HIP_MEMORY_SCOPE_AGENT);
        __hip_atomic_store(&slot[3], MAGIC,
                           __ATOMIC_RELEASE, __HIP_MEMORY_SCOPE_AGENT);
    }
    if (b == 0 && tid < 64) {
        // all 64 blocks are co-resident (64 blocks <= 256 CUs): spin is safe
        unsigned* slot = res + lane * 4;
        while (__hip_atomic_load(&slot[3], __ATOMIC_ACQUIRE,
                                 __HIP_MEMORY_SCOPE_AGENT) != MAGIC) {
            __builtin_amdgcn_s_sleep(1);
        }
        float clsv = __uint_as_float(__hip_atomic_load(
            &slot[0], __ATOMIC_RELAXED, __HIP_MEMORY_SCOPE_AGENT));
        float boxv = __uint_as_float(__hip_atomic_load(
            &slot[1], __ATOMIC_RELAXED, __HIP_MEMORY_SCOPE_AGENT));
        int cntv = (int)__hip_atomic_load(
            &slot[2], __ATOMIC_RELAXED, __HIP_MEMORY_SCOPE_AGENT);
        if (lane == 0) {
            // serial b=0..63 order via readlane: bitwise-identical to the
            // original finalize loop
            float c = 0.f, bx = 0.f;
            int nn = 0;
            for (int bb = 0; bb < 64; ++bb) {
                c += readlane_f(clsv, bb);
                bx += readlane_f(boxv, bb);
                nn += __builtin_amdgcn_readlane(cntv, bb);
            }
            float denom = (nn > 0) ? (float)nn : 1.0f;
            float cl = c / denom;
            float bl = bx / (6.0f * denom);
            out[0] = cl;
            out[1] = bl;
            out[2] = cl + 5.0f * bl;
        }
    }
}

extern "C" void kernel_launch(void* const* d_in, const int* in_sizes, int n_in,
                              void* d_out, int out_size, void* d_ws, size_t ws_size,
                              hipStream_t stream) {
    const float* pred_boxes   = (const float*)d_in[0];
    const float* pred_classes = (const float*)d_in[1];
    const float* gt_boxes     = (const float*)d_in[2];
    const unsigned int*  labels_w = (const unsigned int*)d_in[3];
    const unsigned int*  mask_w   = (const unsigned int*)d_in[4];
    const unsigned char* mask_b   = (const unsigned char*)d_in[4];

    char* ws = (char*)d_ws;
    unsigned* res = (unsigned*)(ws + 16);   // 64 slots x 16B
    float* out = (float*)d_out;

    match_kernel<<<NB, THREADS, 0, stream>>>(pred_boxes, pred_classes, gt_boxes,
                                             labels_w, mask_w, mask_b,
                                             res, out);
}